// Round 7
// baseline (4514.023 us; speedup 1.0000x reference)
//
#include <hip/hip_runtime.h>

// ---------------------------------------------------------------------------
// Problem constants
// ---------------------------------------------------------------------------
#define Bv 8
#define Sv 256
#define Hv 16
#define Dv 64
#define LR 0.1f
#define SCALE (2.0f / 8192.0f)   // dLoss/dpred scale: 2/(B*H*D)

using bf16x8 = __attribute__((ext_vector_type(8))) short;
using bf16x4 = __attribute__((ext_vector_type(4))) short;
using f32x4  = __attribute__((ext_vector_type(4))) float;
using u32x4  = __attribute__((ext_vector_type(4))) unsigned;
#define MFMA16(A, B, C) __builtin_amdgcn_mfma_f32_16x16x32_bf16(A, B, C, 0, 0, 0)

// ---------------------------------------------------------------------------
// LDS layout (ushort units for bf16 planes, float units for fp32 areas)
// Weight/row planes: pitch 136 ushort = 272 B (hi[64] | lo[64] | pad[8]).
// T arrays: pitch 16 ushort = 32 B (hi[8] | lo[8]).
// dz lives in its own buffer (F_GD region): o_s is written only by F2/F2fin
// (barrier-protected) and read only in B1' -> no intra-phase WAR race.
// ---------------------------------------------------------------------------
constexpr int U_W1T = 0;          // [f][d] planes, 64x136
constexpr int U_W2T = 8704;      // [d][f]
constexpr int U_W2R = 17408;     // [f][d]
constexpr int U_G   = 26112;     // [d][d']  (symmetric, static)
constexpr int U_LwR = 34816;     // [d][e]   (static)
constexpr int U_K   = 43520;     // [b pad16][d] 16x136
constexpr int U_H   = 45696;     // [b][f]
constexpr int U_Z   = 47872;     // (unused)
constexpr int U_TG  = 50048;     // [b pad16][e] target planes
constexpr int U_DO  = 52224;     // (unused)
constexpr int U_KT  = 54400;     // [d][b] 64x16
constexpr int U_HT  = 55424;     // [f][b]  (buffer 0)
constexpr int U_DOT = 56448;     // [d][b]
constexpr int U_DAT = 57472;     // [f][b]
constexpr int F_BASE = 29248;    // = 58496/2
constexpr int F_O   = F_BASE;        // o (F2 output), [8][68]
constexpr int F_XH  = F_BASE + 544;
constexpr int F_GD  = F_XH + 544;    // dz buffer, [8][68]
constexpr int F_TGL = F_GD + 544;    // (unused)
constexpr int F_B1  = F_TGL + 544;   // (unused)
constexpr int F_B2  = F_B1 + 64;
constexpr int F_LG  = F_B2 + 64;
constexpr int F_LB  = F_LG + 64;
constexpr int F_C1  = F_LB + 64;     // Lb @ Lw^T (static)
constexpr int F_TGm = F_C1 + 64;
constexpr int F_TBm = F_TGm + 64;
constexpr int F_RSTD = F_TBm + 64;   // (unused)
constexpr int U_KG  = (F_RSTD + 8) * 2;   // -LR*K*K^T, [16][hi8|lo8]
constexpr int U_HT2 = U_KG + 256;         // HT buffer 1
constexpr int LDS_BYTES = (U_HT2 + 1024) * 2;   // 130080 B

// ---------------------------------------------------------------------------
// Helpers
// ---------------------------------------------------------------------------
__device__ __forceinline__ short bf_rn(float v) {
    unsigned u = __float_as_uint(v);
    unsigned r = u + 0x7fffu + ((u >> 16) & 1u);   // round-to-nearest-even
    return (short)(r >> 16);
}
__device__ __forceinline__ void cvt1(float v, short &hi, short &lo) {
    hi = bf_rn(v);
    float hf = __uint_as_float(((unsigned)(unsigned short)hi) << 16);
    lo = bf_rn(v - hf);
}
__device__ __forceinline__ float bf2f(short u) {
    return __uint_as_float(((unsigned)(unsigned short)u) << 16);
}
// Packed bf16 pair conversion: 1 instruction converts 2 floats (RTNE).
__device__ __forceinline__ unsigned cvtpk(float a, float b) {
    unsigned r;
    asm("v_cvt_pk_bf16_f32 %0, %1, %2" : "=v"(r) : "v"(a), "v"(b));
    return r;                      // lo16 = bf16(a), hi16 = bf16(b)
}
// hi/lo split of a float pair: hw = packed hi-bf16s, lw = packed lo-bf16s.
__device__ __forceinline__ void cvt2(float a, float b, unsigned &hw,
                                     unsigned &lw) {
    hw = cvtpk(a, b);
    float ra = a - __uint_as_float(hw << 16);
    float rb = b - __uint_as_float(hw & 0xffff0000u);
    lw = cvtpk(ra, rb);
}
// DPP-based 32-lane sum (epilogue only).
template <int CTRL>
__device__ __forceinline__ float dpp_add(float v) {
    int s = __builtin_amdgcn_update_dpp(0, __float_as_int(v), CTRL, 0xF, 0xF,
                                        true);
    return v + __int_as_float(s);
}
__device__ __forceinline__ float red32(float v) {
    v = dpp_add<0xB1>(v);    // quad_perm [1,0,3,2]  (xor 1)
    v = dpp_add<0x4E>(v);    // quad_perm [2,3,0,1]  (xor 2)
    v = dpp_add<0x124>(v);   // row_ror:4
    v = dpp_add<0x128>(v);   // row_ror:8
    v += __shfl_xor(v, 16);  // merge the two 16-rows of the 32-group
    return v;
}
__device__ __forceinline__ float fast_tanh(float u) {
    u = fminf(fmaxf(u, -10.f), 10.f);
    float e = __expf(2.0f * u);
    return (e - 1.0f) / (e + 1.0f);
}
__device__ __forceinline__ void gelu_both(float x, float &g, float &dg) {
    const float C0 = 0.7978845608028654f, A0 = 0.044715f;
    float x2 = x * x;
    float u = C0 * x * (1.0f + A0 * x2);
    float t = fast_tanh(u);
    g = 0.5f * x * (1.0f + t);
    float du = C0 * (1.0f + 3.0f * A0 * x2);
    dg = 0.5f * (1.0f + t) + 0.5f * x * (1.0f - t * t) * du;
}
__device__ __forceinline__ float gelu_f(float x) {
    const float C0 = 0.7978845608028654f, A0 = 0.044715f;
    float u = C0 * x * (1.0f + A0 * x * x);
    return 0.5f * x * (1.0f + fast_tanh(u));
}

// C[16x16 tile w] = A(16x64, row planes) @ B(64x64 via n-major planes)
__device__ __forceinline__ f32x4 mm64(const unsigned short *Ap,
                                      const unsigned short *Bp,
                                      int w, int c, int q) {
    const unsigned short *ar = Ap + c * 136 + 8 * q;
    const unsigned short *br = Bp + (16 * w + c) * 136 + 8 * q;
    bf16x8 ah0 = *(const bf16x8 *)(ar);
    bf16x8 al0 = *(const bf16x8 *)(ar + 64);
    bf16x8 bh0 = *(const bf16x8 *)(br);
    bf16x8 bl0 = *(const bf16x8 *)(br + 64);
    bf16x8 ah1 = *(const bf16x8 *)(ar + 32);
    bf16x8 al1 = *(const bf16x8 *)(ar + 96);
    bf16x8 bh1 = *(const bf16x8 *)(br + 32);
    bf16x8 bl1 = *(const bf16x8 *)(br + 96);
    f32x4 x0 = {0.f, 0.f, 0.f, 0.f}, x1 = {0.f, 0.f, 0.f, 0.f};
    x0 = MFMA16(ah0, bh0, x0); x1 = MFMA16(ah1, bh1, x1);
    x0 = MFMA16(al0, bh0, x0); x1 = MFMA16(al1, bh1, x1);
    x0 = MFMA16(ah0, bl0, x0); x1 = MFMA16(ah1, bl1, x1);
    x0 = MFMA16(al0, bl0, x0); x1 = MFMA16(al1, bl1, x1);
    return x0 + x1;
}

// Same matmul with A-fragments supplied from registers (z / do paths).
__device__ __forceinline__ f32x4 mm64_regA(bf16x8 ah0, bf16x8 ah1,
                                           bf16x8 al0, bf16x8 al1,
                                           const unsigned short *Bp,
                                           int w, int c, int q) {
    const unsigned short *br = Bp + (16 * w + c) * 136 + 8 * q;
    bf16x8 bh0 = *(const bf16x8 *)(br);
    bf16x8 bl0 = *(const bf16x8 *)(br + 64);
    bf16x8 bh1 = *(const bf16x8 *)(br + 32);
    bf16x8 bl1 = *(const bf16x8 *)(br + 96);
    f32x4 x0 = {0.f, 0.f, 0.f, 0.f}, x1 = {0.f, 0.f, 0.f, 0.f};
    x0 = MFMA16(ah0, bh0, x0); x1 = MFMA16(ah1, bh1, x1);
    x0 = MFMA16(al0, bh0, x0); x1 = MFMA16(al1, bh1, x1);
    x0 = MFMA16(ah0, bl0, x0); x1 = MFMA16(ah1, bl1, x1);
    x0 = MFMA16(al0, bl0, x0); x1 = MFMA16(al1, bl1, x1);
    return x0 + x1;
}

// W update with f32 master weights in registers. Lane (c,q) owns W elements
// (row 16w+c, col 16mt+4q+r) == exactly this lane's gradient outputs.
// g = X^T@Y via packed-K MFMA; master -= LR*g; planes = cvt2(master).
__device__ __forceinline__ void updW3(const bf16x8 *a4, bf16x8 b,
                                      float (&m)[16], unsigned short *WT,
                                      int w, int c, int q) {
    f32x4 g[4];
#pragma unroll
    for (int mt = 0; mt < 4; ++mt) {
        f32x4 z = {0.f, 0.f, 0.f, 0.f};
        g[mt] = MFMA16(a4[mt], b, z);
    }
    unsigned short *p0 = &WT[(16 * w + c) * 136 + 4 * q];
#pragma unroll
    for (int mt = 0; mt < 4; ++mt) {
        m[mt * 4 + 0] -= LR * g[mt][0];
        m[mt * 4 + 1] -= LR * g[mt][1];
        m[mt * 4 + 2] -= LR * g[mt][2];
        m[mt * 4 + 3] -= LR * g[mt][3];
        unsigned nh0, nl0, nh1, nl1;
        cvt2(m[mt * 4 + 0], m[mt * 4 + 1], nh0, nl0);
        cvt2(m[mt * 4 + 2], m[mt * 4 + 3], nh1, nl1);
        uint2 nh, nl;
        nh.x = nh0; nh.y = nh1;
        nl.x = nl0; nl.y = nl1;
        *(uint2 *)(p0 + 16 * mt) = nh;
        *(uint2 *)(p0 + 16 * mt + 64) = nl;
    }
}

// ---------------------------------------------------------------------------
// TTT scan kernel: one block (256 thr = 4 waves) per head
// Phase plan per token (14 barriers):
//   F1o | 4x{ F2 | B1'(+LNf in A-frag distribution) | mega(+LNb) } | F2fin
// LN is computed in the mm64 A-fragment distribution: lane (c,q) owns row c
// elements {8q..8q+7, 8q+32..8q+39}; z and do become register A-fragments.
// ---------------------------------------------------------------------------
__global__ __launch_bounds__(256) void ttt_scan(
    const float *__restrict__ q_g, const float *__restrict__ k_g,
    const float *__restrict__ v_g, float *__restrict__ out_g,
    const float *__restrict__ fw_w1, const float *__restrict__ fw_b1,
    const float *__restrict__ fw_w2, const float *__restrict__ fw_b2,
    const float *__restrict__ fw_lng, const float *__restrict__ fw_lnb,
    const float *__restrict__ loss_w, const float *__restrict__ loss_bv,
    const float *__restrict__ ttt_gv, const float *__restrict__ ttt_bv) {
    extern __shared__ char smem[];
    unsigned short *us = (unsigned short *)smem;
    float *fs = (float *)smem;

    unsigned short *W1T = us + U_W1T, *W2T = us + U_W2T, *W2R = us + U_W2R;
    unsigned short *Gp = us + U_G, *LwR = us + U_LwR;
    unsigned short *Kp = us + U_K, *Hp = us + U_H, *Zp = us + U_Z;
    unsigned short *TGp = us + U_TG, *DOp = us + U_DO;
    unsigned short *KT = us + U_KT, *HT0 = us + U_HT;
    unsigned short *DOT = us + U_DOT, *DAT = us + U_DAT;
    unsigned short *KgT = us + U_KG, *HT1 = us + U_HT2;
    float *o_s = fs + F_O, *xh_s = fs + F_XH, *dz_s = fs + F_GD;
    float *b2_s = fs + F_B2, *lg_s = fs + F_LG;
    float *lb_s = fs + F_LB, *c1_s = fs + F_C1;
    float *tG_s = fs + F_TGm, *tB_s = fs + F_TBm;

    const int h = blockIdx.x, tid = threadIdx.x;
    const int w = tid >> 6, lane = tid & 63, c = lane & 15, q = lane >> 4;
    const int bb = tid >> 5, j0 = (tid & 31) * 2;

    // ---- init: split weights into bf16 hi/lo planes
    for (int i = tid; i < 4096; i += 256) {
        int r = i >> 6, cc = i & 63;
        short hi, lo;
        cvt1(fw_w1[h * 4096 + i], hi, lo);           // [d=r][f=cc]
        W1T[cc * 136 + r] = (unsigned short)hi;
        W1T[cc * 136 + 64 + r] = (unsigned short)lo;
        cvt1(fw_w2[h * 4096 + i], hi, lo);           // [f=r][d=cc]
        W2T[cc * 136 + r] = (unsigned short)hi;
        W2T[cc * 136 + 64 + r] = (unsigned short)lo;
        W2R[r * 136 + cc] = (unsigned short)hi;
        W2R[r * 136 + 64 + cc] = (unsigned short)lo;
        cvt1(loss_w[i], hi, lo);                     // [d=r][e=cc]
        LwR[r * 136 + cc] = (unsigned short)hi;
        LwR[r * 136 + 64 + cc] = (unsigned short)lo;
    }
    // zero pad rows 8..15 of the activation row-plane arrays
    for (int i = tid; i < 5 * 8 * 128; i += 256) {
        int a = i / 128, u = i % 128;
        int arr = a >> 3, row = 8 + (a & 7);
        unsigned short *base = (arr == 0) ? Kp : (arr == 1) ? Hp
                              : (arr == 2) ? Zp : (arr == 3) ? TGp : DOp;
        base[row * 136 + u] = 0;
    }
    // f32 master weights in registers: lane (c,q) of wave w owns elements
    // (plane-row 16w+c, plane-col 16mt+4q+r) of each of the 3 W planes.
    float w1m[16], w2m[16], w2rm[16];
#pragma unroll
    for (int mt = 0; mt < 4; ++mt) {
#pragma unroll
        for (int r = 0; r < 4; ++r) {
            int el = 16 * mt + 4 * q + r;
            int row = 16 * w + c;
            w1m[mt * 4 + r] = fw_w1[h * 4096 + el * 64 + row];
            w2m[mt * 4 + r] = fw_w2[h * 4096 + el * 64 + row];
            w2rm[mt * 4 + r] = fw_w2[h * 4096 + row * 64 + el];
        }
    }
    __syncthreads();
    // G = Lw @ Lw^T (static; fuses F3+B1 into one phase per step)
#pragma unroll 1
    for (int mt = 0; mt < 4; ++mt) {
        f32x4 g = mm64(LwR + 16 * 136 * mt, LwR, w, c, q);
#pragma unroll
        for (int r = 0; r < 4; ++r) {
            short hi, lo;
            cvt1(g[r], hi, lo);
            int dr = 16 * mt + 4 * q + r, dc = 16 * w + c;
            Gp[dr * 136 + dc] = (unsigned short)hi;
            Gp[dr * 136 + 64 + dc] = (unsigned short)lo;
        }
    }
    if (tid < 64) {
        b2_s[tid] = fw_b2[h * 64 + tid];
        lg_s[tid] = fw_lng[h * 64 + tid];
        lb_s[tid] = fw_lnb[h * 64 + tid];
        tG_s[tid] = ttt_gv[h * 64 + tid];
        tB_s[tid] = ttt_bv[h * 64 + tid];
        float c1 = 0.f;                      // c1[d] = sum_e Lb[e]*Lw[d,e]
        for (int e = 0; e < 64; ++e) c1 += loss_bv[e] * loss_w[tid * 64 + e];
        c1_s[tid] = c1;
    }

    // ---- stage token 0 (Kp/KT/TGp) and hold q(0) in registers
    float2 pk, pv, pq, q_cur;
    {
        int idx = ((bb * Sv + 0) * Hv + h) * Dv + j0;
        float2 k0 = *(const float2 *)&k_g[idx];
        float2 v0 = *(const float2 *)&v_g[idx];
        q_cur = *(const float2 *)&q_g[idx];
        unsigned khw, klw;
        cvt2(k0.x, k0.y, khw, klw);
        *(unsigned *)&Kp[bb * 136 + j0] = khw;
        *(unsigned *)&Kp[bb * 136 + 64 + j0] = klw;
        KT[j0 * 16 + bb] = (unsigned short)khw;
        KT[j0 * 16 + 8 + bb] = (unsigned short)klw;
        KT[(j0 + 1) * 16 + bb] = (unsigned short)(khw >> 16);
        KT[(j0 + 1) * 16 + 8 + bb] = (unsigned short)(klw >> 16);
        unsigned thw, tlw;
        cvt2(v0.x - k0.x, v0.y - k0.y, thw, tlw);
        *(unsigned *)&TGp[bb * 136 + j0] = thw;
        *(unsigned *)&TGp[bb * 136 + 64 + j0] = tlw;
    }
    float b1_r = (q < 2) ? fw_b1[h * 64 + 16 * w + c] : 0.f;
    __syncthreads();
    float c1_r = c1_s[16 * w + c];
    f32x4 gd_r = {0.f, 0.f, 0.f, 0.f};
    f32x4 tgl_r = {0.f, 0.f, 0.f, 0.f};

#pragma unroll 1
    for (int t = 0; t < Sv; ++t) {
        // issue prefetch for token t+1 (consumed at F2fin staging / epilogue)
        if (t + 1 < Sv) {
            int idx2 = ((bb * Sv + t + 1) * Hv + h) * Dv + j0;
            pk = *(const float2 *)&k_g[idx2];
            pv = *(const float2 *)&v_g[idx2];
            pq = *(const float2 *)&q_g[idx2];
        }

        // ---- F1o: acc1 = k@W1 (kept in regs all token); tgl_r; Kg; gelu
        f32x4 acc1 = mm64(Kp, W1T, w, c, q);
        {
            f32x4 a2 = mm64(TGp, LwR, w, c, q);
            if (q < 2) {
#pragma unroll
                for (int r = 0; r < 4; ++r) tgl_r[r] = a2[r] - c1_r;
            }
        }
        if (w == 0) {
            f32x4 kg = mm64(Kp, Kp, 0, c, q);
            if (q < 2) {
#pragma unroll
                for (int r = 0; r < 4; ++r) {
                    short hi, lo;
                    cvt1(-LR * kg[r], hi, lo);
                    KgT[c * 16 + 4 * q + r] = (unsigned short)hi;
                    KgT[c * 16 + 8 + 4 * q + r] = (unsigned short)lo;
                }
            }
        }
        if (q < 2) {
            int col = 16 * w + c;
            float gv[4];
#pragma unroll
            for (int r = 0; r < 4; ++r) {
                float g, dg;
                gelu_both(acc1[r] + b1_r, g, dg);
                gv[r] = g;
                gd_r[r] = dg;
            }
            unsigned h01, l01, h23, l23;
            cvt2(gv[0], gv[1], h01, l01);
            cvt2(gv[2], gv[3], h23, l23);
            Hp[(4 * q + 0) * 136 + col] = (unsigned short)h01;
            Hp[(4 * q + 1) * 136 + col] = (unsigned short)(h01 >> 16);
            Hp[(4 * q + 2) * 136 + col] = (unsigned short)h23;
            Hp[(4 * q + 3) * 136 + col] = (unsigned short)(h23 >> 16);
            Hp[(4 * q + 0) * 136 + 64 + col] = (unsigned short)l01;
            Hp[(4 * q + 1) * 136 + 64 + col] = (unsigned short)(l01 >> 16);
            Hp[(4 * q + 2) * 136 + 64 + col] = (unsigned short)l23;
            Hp[(4 * q + 3) * 136 + 64 + col] = (unsigned short)(l23 >> 16);
            uint2 hh, hl;
            hh.x = h01; hh.y = h23;
            hl.x = l01; hl.y = l23;
            *(uint2 *)&HT0[col * 16 + 4 * q] = hh;
            *(uint2 *)&HT0[col * 16 + 8 + 4 * q] = hl;
        }
        __syncthreads();

#pragma unroll 1
        for (int step = 0; step < 4; ++step) {
            const unsigned short *HTr = (step & 1) ? HT1 : HT0;
            unsigned short *HTw = (step & 1) ? HT0 : HT1;
            // ---- F2: o = h@W2 + b2
            f32x4 acc = mm64(Hp, W2T, w, c, q);
            if (q < 2) {
                float bias = b2_s[16 * w + c];
#pragma unroll
                for (int r = 0; r < 4; ++r)
                    o_s[(4 * q + r) * 68 + 16 * w + c] = acc[r] + bias;
            }
            __syncthreads();

            // ---- B1'+LNf: LN in A-frag distribution -> z reg-frags -> z@G
            // dz goes to dz_s (NOT o_s): o_s is still being read by other
            // waves' LN in this same phase (no intra-phase barrier).
            float xh0[8], xh1[8], lgr0[8], lgr1[8], rstd_r;
            {
                const bool rok = (c < 8);
                const float *orow = &o_s[c * 68 + 8 * q];
                float4 z4 = {0.f, 0.f, 0.f, 0.f};
                float4 a0 = rok ? *(const float4 *)(orow) : z4;
                float4 a1 = rok ? *(const float4 *)(orow + 4) : z4;
                float4 a2_ = rok ? *(const float4 *)(orow + 32) : z4;
                float4 a3 = rok ? *(const float4 *)(orow + 36) : z4;
                float o0[8] = {a0.x, a0.y, a0.z, a0.w, a1.x, a1.y, a1.z, a1.w};
                float o1[8] = {a2_.x, a2_.y, a2_.z, a2_.w,
                               a3.x, a3.y, a3.z, a3.w};
                float s = 0.f;
#pragma unroll
                for (int j = 0; j < 8; ++j) s += o0[j] + o1[j];
                s += __shfl_xor(s, 16);
                s += __shfl_xor(s, 32);
                float mu = s * (1.f / 64.f);
                float sq = 0.f;
#pragma unroll
                for (int j = 0; j < 8; ++j) {
                    xh0[j] = o0[j] - mu;
                    xh1[j] = o1[j] - mu;
                    sq += xh0[j] * xh0[j] + xh1[j] * xh1[j];
                }
                sq += __shfl_xor(sq, 16);
                sq += __shfl_xor(sq, 32);
                rstd_r = rsqrtf(sq * (1.f / 64.f) + 1e-5f);
#pragma unroll
                for (int j = 0; j < 8; ++j) {
                    xh0[j] *= rstd_r;
                    xh1[j] *= rstd_r;
                }
                float4 g0 = *(const float4 *)&lg_s[8 * q];
                float4 g1 = *(const float4 *)&lg_s[8 * q + 4];
                float4 g2 = *(const float4 *)&lg_s[8 * q + 32];
                float4 g3 = *(const float4 *)&lg_s[8 * q + 36];
                lgr0[0] = g0.x; lgr0[1] = g0.y; lgr0[2] = g0.z; lgr0[3] = g0.w;
                lgr0[4] = g1.x; lgr0[5] = g1.y; lgr0[6] = g1.z; lgr0[7] = g1.w;
                lgr1[0] = g2.x; lgr1[1] = g2.y; lgr1[2] = g2.z; lgr1[3] = g2.w;
                lgr1[4] = g3.x; lgr1[5] = g3.y; lgr1[6] = g3.z; lgr1[7] = g3.w;
                float4 e0 = *(const float4 *)&lb_s[8 * q];
                float4 e1 = *(const float4 *)&lb_s[8 * q + 4];
                float4 e2 = *(const float4 *)&lb_s[8 * q + 32];
                float4 e3 = *(const float4 *)&lb_s[8 * q + 36];
                float lbr0[8] = {e0.x, e0.y, e0.z, e0.w,
                                 e1.x, e1.y, e1.z, e1.w};
                float lbr1[8] = {e2.x, e2.y, e2.z, e2.w,
                                 e3.x, e3.y, e3.z, e3.w};
                float zz0[8], zz1[8];
#pragma unroll
                for (int j = 0; j < 8; ++j) {
                    zz0[j] = xh0[j] * lgr0[j] + lbr0[j];
                    zz1[j] = xh1[j] * lgr1[j] + lbr1[j];
                }
                // persist xh for w3's dlg update (w0 writes; w3 reads after
                // the B1'-end barrier; all waves compute identical values)
                if (w == 0 && rok) {
                    float4 x4;
                    x4.x = xh0[0]; x4.y = xh0[1]; x4.z = xh0[2]; x4.w = xh0[3];
                    *(float4 *)&xh_s[c * 68 + 8 * q] = x4;
                    x4.x = xh0[4]; x4.y = xh0[5]; x4.z = xh0[6]; x4.w = xh0[7];
                    *(float4 *)&xh_s[c * 68 + 8 * q + 4] = x4;
                    x4.x = xh1[0]; x4.y = xh1[1]; x4.z = xh1[2]; x4.w = xh1[3];
                    *(float4 *)&xh_s[c * 68 + 8 * q + 32] = x4;
                    x4.x = xh1[4]; x4.y = xh1[5]; x4.z = xh1[6]; x4.w = xh1[7];
                    *(float4 *)&xh_s[c * 68 + 8 * q + 36] = x4;
                }
                u32x4 H0, L0, H1, L1;
#pragma unroll
                for (int p = 0; p < 4; ++p) {
                    unsigned hh, ll;
                    cvt2(zz0[2 * p], zz0[2 * p + 1], hh, ll);
                    H0[p] = rok ? hh : 0u;
                    L0[p] = rok ? ll : 0u;
                    cvt2(zz1[2 * p], zz1[2 * p + 1], hh, ll);
                    H1[p] = rok ? hh : 0u;
                    L1[p] = rok ? ll : 0u;
                }
                bf16x8 zh0 = __builtin_bit_cast(bf16x8, H0);
                bf16x8 zh1 = __builtin_bit_cast(bf16x8, H1);
                bf16x8 zl0 = __builtin_bit_cast(bf16x8, L0);
                bf16x8 zl1 = __builtin_bit_cast(bf16x8, L1);
                acc = mm64_regA(zh0, zh1, zl0, zl1, Gp, w, c, q);
                if (q < 2) {
                    int col = 16 * w + c;
#pragma unroll
                    for (int r = 0; r < 4; ++r)
                        dz_s[(4 * q + r) * 68 + col] =
                            (acc[r] - tgl_r[r]) * SCALE;
                }
            }
            __syncthreads();

            // ---- mega: LNb (A-frag distribution) -> do reg-frags -> B2 ->
            //      da/DAT -> 3x updW3 (f32 masters) -> accupd -> gelu
            {
                const bool rok = (c < 8);
                const float *drow = &dz_s[c * 68 + 8 * q];
                float4 z4 = {0.f, 0.f, 0.f, 0.f};
                float4 a0 = rok ? *(const float4 *)(drow) : z4;
                float4 a1 = rok ? *(const float4 *)(drow + 4) : z4;
                float4 a2_ = rok ? *(const float4 *)(drow + 32) : z4;
                float4 a3 = rok ? *(const float4 *)(drow + 36) : z4;
                float dz0[8] = {a0.x, a0.y, a0.z, a0.w,
                                a1.x, a1.y, a1.z, a1.w};
                float dz1[8] = {a2_.x, a2_.y, a2_.z, a2_.w,
                                a3.x, a3.y, a3.z, a3.w};
                float dxh0[8], dxh1[8];
                float s1 = 0.f, s2 = 0.f;
#pragma unroll
                for (int j = 0; j < 8; ++j) {
                    dxh0[j] = dz0[j] * lgr0[j];
                    dxh1[j] = dz1[j] * lgr1[j];
                    s1 += dxh0[j] + dxh1[j];
                    s2 += dxh0[j] * xh0[j] + dxh1[j] * xh1[j];
                }
                s1 += __shfl_xor(s1, 16);
                s2 += __shfl_xor(s2, 16);
                s1 += __shfl_xor(s1, 32);
                s2 += __shfl_xor(s2, 32);
                float S1 = s1 * (1.f / 64.f), S2 = s2 * (1.f / 64.f);
                float do0[8], do1[8];
#pragma unroll
                for (int j = 0; j < 8; ++j) {
                    do0[j] = rstd_r * (dxh0[j] - S1 - xh0[j] * S2);
                    do1[j] = rstd_r * (dxh1[j] - S1 - xh1[j] * S2);
                }
                u32x4 H0, L0, H1, L1;
#pragma unroll
                for (int p = 0; p < 4; ++p) {
                    unsigned hh, ll;
                    cvt2(do0[2 * p], do0[2 * p + 1], hh, ll);
                    H0[p] = rok ? hh : 0u;
                    L0[p] = rok ? ll : 0u;
                    cvt2(do1[2 * p], do1[2 * p + 1], hh, ll);
                    H1[p] = rok ? hh : 0u;
                    L1[p] = rok ? ll : 0u;
                }
                // DOT rebuild: every wave writes identical values (benign
                // race); same-wave ordering covers this wave's later reads.
                if (rok) {
#pragma unroll
                    for (int p = 0; p < 4; ++p) {
                        int d0 = 8 * q + 2 * p;
                        DOT[d0 * 16 + c] = (unsigned short)H0[p];
                        DOT[d0 * 16 + 8 + c] = (unsigned short)L0[p];
                        DOT[(d0 + 1) * 16 + c] = (unsigned short)(H0[p] >> 16);
                        DOT[(d0 + 1) * 16 + 8 + c] =
                            (unsigned short)(L0[p] >> 16);
                        int d1 = d0 + 32;
                        DOT[d1 * 16 + c] = (unsigned short)H1[p];
                        DOT[d1 * 16 + 8 + c] = (unsigned short)L1[p];
                        DOT[(d1 + 1) * 16 + c] = (unsigned short)(H1[p] >> 16);
                        DOT[(d1 + 1) * 16 + 8 + c] =
                            (unsigned short)(L1[p] >> 16);
                    }
                }
                bf16x8 dh0 = __builtin_bit_cast(bf16x8, H0);
                bf16x8 dh1 = __builtin_bit_cast(bf16x8, H1);
                bf16x8 dl0 = __builtin_bit_cast(bf16x8, L0);
                bf16x8 dl1 = __builtin_bit_cast(bf16x8, L1);
                acc = mm64_regA(dh0, dh1, dl0, dl1, W2R, w, c, q);

                float b1sum = 0.f;
                if (q < 2) {
                    int col = 16 * w + c;
                    float da0 = acc[0] * gd_r[0];
                    float da1 = acc[1] * gd_r[1];
                    float da2 = acc[2] * gd_r[2];
                    float da3 = acc[3] * gd_r[3];
                    b1sum = da0 + da1 + da2 + da3;
                    unsigned h01, l01, h23, l23;
                    cvt2(da0, da1, h01, l01);
                    cvt2(da2, da3, h23, l23);
                    uint2 th, tl;
                    th.x = h01; th.y = h23;
                    tl.x = l01; tl.y = l23;
                    *(uint2 *)&DAT[col * 16 + 4 * q] = th;
                    *(uint2 *)&DAT[col * 16 + 8 + 4 * q] = tl;
                }
                b1sum += __shfl_xor(b1sum, 16);

                bf16x8 zf8;
#pragma unroll
                for (int j = 0; j < 8; ++j) zf8[j] = 0;
                bf16x8 aK[4], aH[4], aD[4];
#pragma unroll
                for (int mt = 0; mt < 4; ++mt) {
                    aK[mt] = *(const bf16x8 *)
                        &KT[(16 * mt + c) * 16 + (q & 1) * 8];
                    aH[mt] = *(const bf16x8 *)
                        &HTr[(16 * mt + c) * 16 + (q & 1) * 8];
                    aD[mt] = *(const bf16x8 *)
                        &DOT[(16 * mt + c) * 16 + (q & 1) * 8];
                }
                bf16x8 bDO = zf8, bHT = zf8, bDA = zf8;
                if (q < 2) {
                    bDO = *(const bf16x8 *)&DOT[(16 * w + c) * 16];
                    bHT = *(const bf16x8 *)&HTr[(16 * w + c) * 16];
                    bDA = *(const bf16x8 *)&DAT[(16 * w + c) * 16];
                } else if (q == 2) {
                    bDO = *(const bf16x8 *)&DOT[(16 * w + c) * 16 + 8];
                    bHT = *(const bf16x8 *)&HTr[(16 * w + c) * 16 + 8];
                    bDA = *(const bf16x8 *)&DAT[(16 * w + c) * 16 + 8];
                }
                bf16x8 aKg = *(const bf16x8 *)&KgT[c * 16 + (q & 1) * 8];
                updW3(aK, bDA, w1m, W1T, w, c, q);
                updW3(aH, bDO, w2m, W2T, w, c, q);
                updW3(aD, bHT, w2rm, W2R, w, c, q);
                if (w == 2) {
                    bf16x8 oh_ = *(const bf16x8 *)&DOT[lane * 16];
                    bf16x8 ol_ = *(const bf16x8 *)&DOT[lane * 16 + 8];
                    float db2 = 0.f;
#pragma unroll
                    for (int j = 0; j < 8; ++j)
                        db2 += bf2f(oh_[j]) + bf2f(ol_[j]);
                    b2_s[lane] -= LR * db2;
                } else if (w == 3) {
                    float dlb = 0.f, dlg = 0.f;
#pragma unroll
                    for (int b = 0; b < 8; ++b) {
                        float dzv = dz_s[b * 68 + lane];
                        dlb += dzv;
                        dlg += dzv * xh_s[b * 68 + lane];
                    }
                    lb_s[lane] -= LR * dlb;
                    lg_s[lane] -= LR * dlg;
                }
                // F1': incremental pre-activation + activation for next step
                acc1 = MFMA16(aKg, bDA, acc1);
                b1_r -= LR * b1sum;
                if (q < 2) {
                    int col = 16 * w + c;
                    if (step < 3) {
                        float gv[4];
#pragma unroll
                        for (int r = 0; r < 4; ++r) {
                            float g, dg;
                            gelu_both(acc1[r] + b1_r, g, dg);
                            gv[r] = g;
                            gd_r[r] = dg;
                        }
                        unsigned h01, l01, h23, l23;
                        cvt2(gv[0], gv[1], h01, l01);
                        cvt2(gv[2], gv[3], h23, l23);
                        Hp[(4 * q + 0) * 136 + col] = (unsigned short)h01;
                        Hp[(4 * q + 1) * 136 + col] = (unsigned short)(h01 >> 16);
                        Hp[(4 * q + 2) * 136 + col] = (unsigned short)h23;
                        Hp[(4 * q + 3) * 136 + col] = (unsigned short)(h23 >> 16);
                        Hp[(4 * q + 0) * 136 + 64 + col] = (unsigned short)l01;
                        Hp[(4 * q + 1) * 136 + 64 + col] = (unsigned short)(l01 >> 16);
                        Hp[(4 * q + 2) * 136 + 64 + col] = (unsigned short)l23;
                        Hp[(4 * q + 3) * 136 + 64 + col] = (unsigned short)(l23 >> 16);
                        uint2 hh, hl;
                        hh.x = h01; hh.y = h23;
                        hl.x = l01; hl.y = l23;
                        *(uint2 *)&HTw[col * 16 + 4 * q] = hh;
                        *(uint2 *)&HTw[col * 16 + 8 + 4 * q] = hl;
                    } else {
                        float gv[4];
#pragma unroll
                        for (int r = 0; r < 4; ++r)
                            gv[r] = gelu_f(acc1[r] + b1_r);
                        unsigned h01, l01, h23, l23;
                        cvt2(gv[0], gv[1], h01, l01);
                        cvt2(gv[2], gv[3], h23, l23);
                        Hp[(4 * q + 0) * 136 + col] = (unsigned short)h01;
                        Hp[(4 * q + 1) * 136 + col] = (unsigned short)(h01 >> 16);
                        Hp[(4 * q + 2) * 136 + col] = (unsigned short)h23;
                        Hp[(4 * q + 3) * 136 + col] = (unsigned short)(h23 >> 16);
                        Hp[(4 * q + 0) * 136 + 64 + col] = (unsigned short)l01;
                        Hp[(4 * q + 1) * 136 + 64 + col] = (unsigned short)(l01 >> 16);
                        Hp[(4 * q + 2) * 136 + 64 + col] = (unsigned short)l23;
                        Hp[(4 * q + 3) * 136 + 64 + col] = (unsigned short)(l23 >> 16);
                    }
                }
            }
            __syncthreads();
        }

        // ---- F2fin: o = h_final@W2 + b2 ; stage token t+1 (Kp/KT/TGp)
        f32x4 acc = mm64(Hp, W2T, w, c, q);
        if (q < 2) {
            float bias = b2_s[16 * w + c];
#pragma unroll
            for (int r = 0; r < 4; ++r)
                o_s[(4 * q + r) * 68 + 16 * w + c] = acc[r] + bias;
        }
        if (t + 1 < Sv) {
            unsigned khw, klw;
            cvt2(pk.x, pk.y, khw, klw);
            *(unsigned *)&Kp[bb * 136 + j0] = khw;
            *(unsigned *)&Kp[bb * 136 + 64 + j0] = klw;
            KT[j0 * 16 + bb] = (unsigned short)khw;
            KT[j0 * 16 + 8 + bb] = (unsigned short)klw;
            KT[(j0 + 1) * 16 + bb] = (unsigned short)(khw >> 16);
            KT[(j0 + 1) * 16 + 8 + bb] = (unsigned short)(klw >> 16);
            unsigned thw, tlw;
            cvt2(pv.x - pk.x, pv.y - pk.y, thw, tlw);
            *(unsigned *)&TGp[bb * 136 + j0] = thw;
            *(unsigned *)&TGp[bb * 136 + 64 + j0] = tlw;
        }
        __syncthreads();
        // epilogue: LN(lg,lb) -> LN(ttt_g,ttt_b) -> out = q + z2
        // (no trailing barrier: F1o's end-barrier orders the o_s reuse)
        {
            float2 xv = *(const float2 *)&o_s[bb * 68 + j0];
            float mu = red32(xv.x + xv.y) * (1.f / 64.f);
            float d0 = xv.x - mu, d1 = xv.y - mu;
            float var = red32(d0 * d0 + d1 * d1) * (1.f / 64.f);
            float rs = rsqrtf(var + 1e-5f);
            float z0 = d0 * rs * lg_s[j0] + lb_s[j0];
            float z1 = d1 * rs * lg_s[j0 + 1] + lb_s[j0 + 1];
            float mu2 = red32(z0 + z1) * (1.f / 64.f);
            float e0 = z0 - mu2, e1 = z1 - mu2;
            float var2 = red32(e0 * e0 + e1 * e1) * (1.f / 64.f);
            float rs2 = rsqrtf(var2 + 1e-5f);
            float z20 = e0 * rs2 * tG_s[j0] + tB_s[j0];
            float z21 = e1 * rs2 * tG_s[j0 + 1] + tB_s[j0 + 1];
            int idx = ((bb * Sv + t) * Hv + h) * Dv + j0;
            float2 ov;
            ov.x = q_cur.x + z20;
            ov.y = q_cur.y + z21;
            *(float2 *)&out_g[idx] = ov;
            q_cur = pq;
        }
    }
}

// ---------------------------------------------------------------------------
// fp32 GEMM: C[M,N] = A[M,K] @ B[K,N]; mode 1: C = gelu(acc) * gate_ln
// ---------------------------------------------------------------------------
__global__ __launch_bounds__(256) void gemm_f32(
    const float *__restrict__ A, const float *__restrict__ B,
    float *__restrict__ C, const float *__restrict__ gate_ln,
    int M, int N, int K, int mode) {
    __shared__ float As[16][68];
    __shared__ float Bs[16][64];
    const int tid = threadIdx.x;
    const int tx = tid & 15, ty = tid >> 4;
    const int bm = blockIdx.y * 64, bn = blockIdx.x * 64;

    float acc[4][4] = {};
    for (int k0 = 0; k0 < K; k0 += 16) {
        {
            int r = tid >> 2, kk = (tid & 3) * 4;
            float4 av = *(const float4 *)(A + (long)(bm + r) * K + k0 + kk);
            As[kk + 0][r] = av.x;
            As[kk + 1][r] = av.y;
            As[kk + 2][r] = av.z;
            As[kk + 3][r] = av.w;
            int rr = tid >> 4, cc = (tid & 15) * 4;
            float4 bv = *(const float4 *)(B + (long)(k0 + rr) * N + bn + cc);
            *(float4 *)&Bs[rr][cc] = bv;
        }
        __syncthreads();
#pragma unroll
        for (int kk = 0; kk < 16; ++kk) {
            float4 a4 = *(float4 *)&As[kk][ty * 4];
            float4 b4 = *(float4 *)&Bs[kk][tx * 4];
            float a[4] = {a4.x, a4.y, a4.z, a4.w};
            float b[4] = {b4.x, b4.y, b4.z, b4.w};
#pragma unroll
            for (int i = 0; i < 4; ++i)
#pragma unroll
                for (int j = 0; j < 4; ++j) acc[i][j] += a[i] * b[j];
        }
        __syncthreads();
    }
#pragma unroll
    for (int i = 0; i < 4; ++i) {
        int row = bm + ty * 4 + i;
        float4 out;
        float v[4];
#pragma unroll
        for (int j = 0; j < 4; ++j) {
            float val = acc[i][j];
            if (mode == 1) {
                int col = bn + tx * 4 + j;
                val = gelu_f(val) * gate_ln[(long)row * N + col];
            }
            v[j] = val;
        }
        out.x = v[0]; out.y = v[1]; out.z = v[2]; out.w = v[3];
        *(float4 *)(C + (long)row * N + bn + tx * 4) = out;
    }
}

// ---------------------------------------------------------------------------
// Row LayerNorm over 1024 (post-scan, pn_g / pn_b)
// ---------------------------------------------------------------------------
__global__ __launch_bounds__(256) void row_ln(const float *__restrict__ in,
                                              float *__restrict__ out,
                                              const float *__restrict__ g,
                                              const float *__restrict__ b) {
    __shared__ float sred[4], s2red[4];
    const int row = blockIdx.x;
    const int tid = threadIdx.x;
    const float *x = in + (long)row * 1024;
    float4 v = *(const float4 *)(x + tid * 4);
    float s = v.x + v.y + v.z + v.w;
    float s2 = v.x * v.x + v.y * v.y + v.z * v.z + v.w * v.w;
#pragma unroll
    for (int m = 1; m <= 32; m <<= 1) {
        s += __shfl_xor(s, m);
        s2 += __shfl_xor(s2, m);
    }
    if ((tid & 63) == 0) {
        sred[tid >> 6] = s;
        s2red[tid >> 6] = s2;
    }
    __syncthreads();
    float S = sred[0] + sred[1] + sred[2] + sred[3];
    float S2 = s2red[0] + s2red[1] + s2red[2] + s2red[3];
    float mu = S * (1.f / 1024.f);
    float var = S2 * (1.f / 1024.f) - mu * mu;
    float rs = rsqrtf(var + 1e-5f);
    float o[4] = {v.x, v.y, v.z, v.w};
    float4 ov;
    float r[4];
#pragma unroll
    for (int i = 0; i < 4; ++i) {
        int col = tid * 4 + i;
        r[i] = (o[i] - mu) * rs * g[col] + b[col];
    }
    ov.x = r[0]; ov.y = r[1]; ov.z = r[2]; ov.w = r[3];
    *(float4 *)(out + (long)row * 1024 + tid * 4) = ov;
}

// ---------------------------------------------------------------------------
// Launch
// ---------------------------------------------------------------------------
extern "C" void kernel_launch(void *const *d_in, const int *in_sizes, int n_in,
                              void *d_out, int out_size, void *d_ws,
                              size_t ws_size, hipStream_t stream) {
    const float *x = (const float *)d_in[0];
    const float *wq = (const float *)d_in[1];
    const float *wk = (const float *)d_in[2];
    const float *wv = (const float *)d_in[3];
    const float *fw_w1 = (const float *)d_in[4];
    const float *fw_b1 = (const float *)d_in[5];
    const float *fw_w2 = (const float *)d_in[6];
    const float *fw_b2 = (const float *)d_in[7];
    const float *fw_lng = (const float *)d_in[8];
    const float *fw_lnb = (const float *)d_in[9];
    const float *loss_w = (const float *)d_in[10];
    const float *loss_b = (const float *)d_in[11];
    const float *ttt_g = (const float *)d_in[12];
    const float *ttt_b = (const float *)d_in[13];
    const float *wo = (const float *)d_in[14];
    const float *wg = (const float *)d_in[15];
    const float *pn_g = (const float *)d_in[16];
    const float *pn_b = (const float *)d_in[17];

    const long MAT = 2048L * 1024L;
    float *q_ws = (float *)d_ws;
    float *k_ws = q_ws + MAT;
    float *v_ws = k_ws + MAT;
    float *out_ws = v_ws + MAT;
    float *ln_ws = k_ws;       // reuse (k dead after scan)
    float *gated_ws = v_ws;    // reuse (v dead after scan)

    dim3 gg(1024 / 64, 2048 / 64), bt(256);
    hipLaunchKernelGGL(gemm_f32, gg, bt, 0, stream, x, wq, q_ws,
                       (const float *)nullptr, 2048, 1024, 1024, 0);
    hipLaunchKernelGGL(gemm_f32, gg, bt, 0, stream, x, wk, k_ws,
                       (const float *)nullptr, 2048, 1024, 1024, 0);
    hipLaunchKernelGGL(gemm_f32, gg, bt, 0, stream, x, wv, v_ws,
                       (const float *)nullptr, 2048, 1024, 1024, 0);

    (void)hipFuncSetAttribute((const void *)ttt_scan,
                              hipFuncAttributeMaxDynamicSharedMemorySize,
                              LDS_BYTES);
    hipLaunchKernelGGL(ttt_scan, dim3(16), dim3(256), LDS_BYTES, stream,
                       q_ws, k_ws, v_ws, out_ws, fw_w1, fw_b1, fw_w2, fw_b2,
                       fw_lng, fw_lnb, loss_w, loss_b, ttt_g, ttt_b);

    hipLaunchKernelGGL(row_ln, dim3(2048), dim3(256), 0, stream, out_ws, ln_ws,
                       pn_g, pn_b);
    hipLaunchKernelGGL(gemm_f32, gg, bt, 0, stream, x, wg, gated_ws, ln_ws,
                       2048, 1024, 1024, 1);
    hipLaunchKernelGGL(gemm_f32, gg, bt, 0, stream, gated_ws, wo,
                       (float *)d_out, (const float *)nullptr, 2048, 1024,
                       1024, 0);
}

// Round 8
// 3920.401 us; speedup vs baseline: 1.1514x; 1.1514x over previous
//
#include <hip/hip_runtime.h>

// ---------------------------------------------------------------------------
// Problem constants
// ---------------------------------------------------------------------------
#define Bv 8
#define Sv 256
#define Hv 16
#define Dv 64
#define LR 0.1f
#define SCALE (2.0f / 8192.0f)   // dLoss/dpred scale: 2/(B*H*D)

using bf16x8 = __attribute__((ext_vector_type(8))) short;
using bf16x4 = __attribute__((ext_vector_type(4))) short;
using f32x4  = __attribute__((ext_vector_type(4))) float;
using u32x4  = __attribute__((ext_vector_type(4))) unsigned;
#define MFMA16(A, B, C) __builtin_amdgcn_mfma_f32_16x16x32_bf16(A, B, C, 0, 0, 0)

// ---------------------------------------------------------------------------
// LDS layout (ushort units for bf16 planes, float units for fp32 areas)
// Weight/row planes: pitch 136 ushort = 272 B (hi[64] | lo[64] | pad[8]).
// T arrays: pitch 16 ushort = 32 B (hi[8] | lo[8]).
// ---------------------------------------------------------------------------
constexpr int U_W1T = 0;          // [f][d] planes, 64x136
constexpr int U_W2T = 8704;      // [d][f]
constexpr int U_W2R = 17408;     // [f][d]
constexpr int U_G   = 26112;     // [d][d']  (symmetric, static)
constexpr int U_LwR = 34816;     // [d][e]   (static)
constexpr int U_K   = 43520;     // [b pad16][d] 16x136
constexpr int U_H   = 45696;     // [b][f]
constexpr int U_Z   = 47872;     // [b][d]
constexpr int U_TG  = 50048;     // [b pad16][e] target planes
constexpr int U_DO  = 52224;     // [b][d]
constexpr int U_KT  = 54400;     // [d][b] 64x16
constexpr int U_HT  = 55424;     // [f][b]  (buffer 0)
constexpr int U_DOT = 56448;     // [d][b]
constexpr int U_DAT = 57472;     // (unused now - DAT lives in registers/shfl)
constexpr int F_BASE = 29248;    // = 58496/2
constexpr int F_O   = F_BASE;        // o / dz shared, [8][68]
constexpr int F_XH  = F_BASE + 544;
constexpr int F_GD  = F_XH + 544;    // (unused)
constexpr int F_TGL = F_GD + 544;    // (unused)
constexpr int F_B1  = F_TGL + 544;   // (unused)
constexpr int F_B2  = F_B1 + 64;
constexpr int F_LG  = F_B2 + 64;
constexpr int F_LB  = F_LG + 64;
constexpr int F_C1  = F_LB + 64;     // Lb @ Lw^T (static)
constexpr int F_TGm = F_C1 + 64;
constexpr int F_TBm = F_TGm + 64;
constexpr int F_RSTD = F_TBm + 64;
constexpr int U_KG  = (F_RSTD + 8) * 2;   // -LR*K*K^T, [16][hi8|lo8]
constexpr int U_HT2 = U_KG + 256;         // HT buffer 1
constexpr int LDS_BYTES = (U_HT2 + 1024) * 2;   // 130080 B

// ---------------------------------------------------------------------------
// Helpers
// ---------------------------------------------------------------------------
__device__ __forceinline__ short bf_rn(float v) {
    unsigned u = __float_as_uint(v);
    unsigned r = u + 0x7fffu + ((u >> 16) & 1u);   // round-to-nearest-even
    return (short)(r >> 16);
}
__device__ __forceinline__ void cvt1(float v, short &hi, short &lo) {
    hi = bf_rn(v);
    float hf = __uint_as_float(((unsigned)(unsigned short)hi) << 16);
    lo = bf_rn(v - hf);
}
__device__ __forceinline__ float bf2f(short u) {
    return __uint_as_float(((unsigned)(unsigned short)u) << 16);
}
// Packed bf16 pair conversion: 1 instruction converts 2 floats (RTNE).
__device__ __forceinline__ unsigned cvtpk(float a, float b) {
    unsigned r;
    asm("v_cvt_pk_bf16_f32 %0, %1, %2" : "=v"(r) : "v"(a), "v"(b));
    return r;                      // lo16 = bf16(a), hi16 = bf16(b)
}
// hi/lo split of a float pair: hw = packed hi-bf16s, lw = packed lo-bf16s.
__device__ __forceinline__ void cvt2(float a, float b, unsigned &hw,
                                     unsigned &lw) {
    hw = cvtpk(a, b);
    float ra = a - __uint_as_float(hw << 16);
    float rb = b - __uint_as_float(hw & 0xffff0000u);
    lw = cvtpk(ra, rb);
}
// DPP-based 32-lane sum.
template <int CTRL>
__device__ __forceinline__ float dpp_add(float v) {
    int s = __builtin_amdgcn_update_dpp(0, __float_as_int(v), CTRL, 0xF, 0xF,
                                        true);
    return v + __int_as_float(s);
}
__device__ __forceinline__ float red32(float v) {
    v = dpp_add<0xB1>(v);    // quad_perm [1,0,3,2]  (xor 1)
    v = dpp_add<0x4E>(v);    // quad_perm [2,3,0,1]  (xor 2)
    v = dpp_add<0x124>(v);   // row_ror:4
    v = dpp_add<0x128>(v);   // row_ror:8
    v += __shfl_xor(v, 16);  // merge the two 16-rows of the 32-group
    return v;
}
__device__ __forceinline__ float fast_tanh(float u) {
    u = fminf(fmaxf(u, -10.f), 10.f);
    float e = __expf(2.0f * u);
    return (e - 1.0f) / (e + 1.0f);
}
__device__ __forceinline__ void gelu_both(float x, float &g, float &dg) {
    const float C0 = 0.7978845608028654f, A0 = 0.044715f;
    float x2 = x * x;
    float u = C0 * x * (1.0f + A0 * x2);
    float t = fast_tanh(u);
    g = 0.5f * x * (1.0f + t);
    float du = C0 * (1.0f + 3.0f * A0 * x2);
    dg = 0.5f * (1.0f + t) + 0.5f * x * (1.0f - t * t) * du;
}
__device__ __forceinline__ float gelu_f(float x) {
    const float C0 = 0.7978845608028654f, A0 = 0.044715f;
    float u = C0 * x * (1.0f + A0 * x * x);
    return 0.5f * x * (1.0f + fast_tanh(u));
}

// C[16x16 tile w] = A(16x64, row planes) @ B(64x64 via n-major planes)
// 3-term split product (hh + lh + hl; the ll term is ~2^-17 relative and
// dropped — same packing precedent as updW since round 2).
__device__ __forceinline__ f32x4 mm64(const unsigned short *Ap,
                                      const unsigned short *Bp,
                                      int w, int c, int q) {
    const unsigned short *ar = Ap + c * 136 + 8 * q;
    const unsigned short *br = Bp + (16 * w + c) * 136 + 8 * q;
    bf16x8 ah0 = *(const bf16x8 *)(ar);
    bf16x8 al0 = *(const bf16x8 *)(ar + 64);
    bf16x8 bh0 = *(const bf16x8 *)(br);
    bf16x8 bl0 = *(const bf16x8 *)(br + 64);
    bf16x8 ah1 = *(const bf16x8 *)(ar + 32);
    bf16x8 al1 = *(const bf16x8 *)(ar + 96);
    bf16x8 bh1 = *(const bf16x8 *)(br + 32);
    bf16x8 bl1 = *(const bf16x8 *)(br + 96);
    f32x4 x0 = {0.f, 0.f, 0.f, 0.f}, x1 = {0.f, 0.f, 0.f, 0.f};
    x0 = MFMA16(ah0, bh0, x0); x1 = MFMA16(ah1, bh1, x1);
    x0 = MFMA16(al0, bh0, x0); x1 = MFMA16(al1, bh1, x1);
    x0 = MFMA16(ah0, bl0, x0); x1 = MFMA16(ah1, bl1, x1);
    return x0 + x1;
}

// W update with f32 master weights in registers (validated in round 7).
// Lane (c,q) owns W elements (row 16w+c, col 16mt+4q+r) == exactly this
// lane's gradient outputs. g = X^T@Y via packed-K MFMA; master -= LR*g;
// planes = cvt2(master). No W-plane reads.
__device__ __forceinline__ void updW3(const bf16x8 *a4, bf16x8 b,
                                      float (&m)[16], unsigned short *WT,
                                      int w, int c, int q) {
    f32x4 g[4];
#pragma unroll
    for (int mt = 0; mt < 4; ++mt) {
        f32x4 z = {0.f, 0.f, 0.f, 0.f};
        g[mt] = MFMA16(a4[mt], b, z);
    }
    unsigned short *p0 = &WT[(16 * w + c) * 136 + 4 * q];
#pragma unroll
    for (int mt = 0; mt < 4; ++mt) {
        m[mt * 4 + 0] -= LR * g[mt][0];
        m[mt * 4 + 1] -= LR * g[mt][1];
        m[mt * 4 + 2] -= LR * g[mt][2];
        m[mt * 4 + 3] -= LR * g[mt][3];
        unsigned nh0, nl0, nh1, nl1;
        cvt2(m[mt * 4 + 0], m[mt * 4 + 1], nh0, nl0);
        cvt2(m[mt * 4 + 2], m[mt * 4 + 3], nh1, nl1);
        uint2 nh, nl;
        nh.x = nh0; nh.y = nh1;
        nl.x = nl0; nl.y = nl1;
        *(uint2 *)(p0 + 16 * mt) = nh;
        *(uint2 *)(p0 + 16 * mt + 64) = nl;
    }
}

// ---------------------------------------------------------------------------
// TTT scan kernel: one block (256 thr = 4 waves) per head
// Phase plan per token (22 barriers):
//   F1o (acc1=k@W1, Kg, tgl_r, gelu) | 4x{ F2 | LNf | B1' | LNb | B2+upd+F1' }
//   | F2fin(+stage t+1) | epilogue(no barrier)
// Register-carried per lane: acc1, gd_r, tgl_r, b1_r, masters w1m/w2m/w2rm.
// da B-fragments are built by cross-lane shuffle (no DAT LDS round-trip).
// ---------------------------------------------------------------------------
__global__ __launch_bounds__(256) void ttt_scan(
    const float *__restrict__ q_g, const float *__restrict__ k_g,
    const float *__restrict__ v_g, float *__restrict__ out_g,
    const float *__restrict__ fw_w1, const float *__restrict__ fw_b1,
    const float *__restrict__ fw_w2, const float *__restrict__ fw_b2,
    const float *__restrict__ fw_lng, const float *__restrict__ fw_lnb,
    const float *__restrict__ loss_w, const float *__restrict__ loss_bv,
    const float *__restrict__ ttt_gv, const float *__restrict__ ttt_bv) {
    extern __shared__ char smem[];
    unsigned short *us = (unsigned short *)smem;
    float *fs = (float *)smem;

    unsigned short *W1T = us + U_W1T, *W2T = us + U_W2T, *W2R = us + U_W2R;
    unsigned short *Gp = us + U_G, *LwR = us + U_LwR;
    unsigned short *Kp = us + U_K, *Hp = us + U_H, *Zp = us + U_Z;
    unsigned short *TGp = us + U_TG, *DOp = us + U_DO;
    unsigned short *KT = us + U_KT, *HT0 = us + U_HT;
    unsigned short *DOT = us + U_DOT;
    unsigned short *KgT = us + U_KG, *HT1 = us + U_HT2;
    float *o_s = fs + F_O, *xh_s = fs + F_XH;
    float *b2_s = fs + F_B2, *lg_s = fs + F_LG;
    float *lb_s = fs + F_LB, *c1_s = fs + F_C1;
    float *tG_s = fs + F_TGm, *tB_s = fs + F_TBm, *rstd_s = fs + F_RSTD;

    const int h = blockIdx.x, tid = threadIdx.x;
    const int w = tid >> 6, lane = tid & 63, c = lane & 15, q = lane >> 4;
    const int bb = tid >> 5, j0 = (tid & 31) * 2;

    // ---- init: split weights into bf16 hi/lo planes
    for (int i = tid; i < 4096; i += 256) {
        int r = i >> 6, cc = i & 63;
        short hi, lo;
        cvt1(fw_w1[h * 4096 + i], hi, lo);           // [d=r][f=cc]
        W1T[cc * 136 + r] = (unsigned short)hi;
        W1T[cc * 136 + 64 + r] = (unsigned short)lo;
        cvt1(fw_w2[h * 4096 + i], hi, lo);           // [f=r][d=cc]
        W2T[cc * 136 + r] = (unsigned short)hi;
        W2T[cc * 136 + 64 + r] = (unsigned short)lo;
        W2R[r * 136 + cc] = (unsigned short)hi;
        W2R[r * 136 + 64 + cc] = (unsigned short)lo;
        cvt1(loss_w[i], hi, lo);                     // [d=r][e=cc]
        LwR[r * 136 + cc] = (unsigned short)hi;
        LwR[r * 136 + 64 + cc] = (unsigned short)lo;
    }
    // zero pad rows 8..15 of the activation row-plane arrays
    for (int i = tid; i < 5 * 8 * 128; i += 256) {
        int a = i / 128, u = i % 128;
        int arr = a >> 3, row = 8 + (a & 7);
        unsigned short *base = (arr == 0) ? Kp : (arr == 1) ? Hp
                              : (arr == 2) ? Zp : (arr == 3) ? TGp : DOp;
        base[row * 136 + u] = 0;
    }
    // f32 master weights in registers (validated r7): lane (c,q) of wave w
    // owns elements (plane-row 16w+c, plane-col 16mt+4q+r) of the 3 planes.
    float w1m[16], w2m[16], w2rm[16];
#pragma unroll
    for (int mt = 0; mt < 4; ++mt) {
#pragma unroll
        for (int r = 0; r < 4; ++r) {
            int el = 16 * mt + 4 * q + r;
            int row = 16 * w + c;
            w1m[mt * 4 + r] = fw_w1[h * 4096 + el * 64 + row];
            w2m[mt * 4 + r] = fw_w2[h * 4096 + el * 64 + row];
            w2rm[mt * 4 + r] = fw_w2[h * 4096 + row * 64 + el];
        }
    }
    __syncthreads();
    // G = Lw @ Lw^T (static; fuses F3+B1 into one phase per step)
#pragma unroll 1
    for (int mt = 0; mt < 4; ++mt) {
        f32x4 g = mm64(LwR + 16 * 136 * mt, LwR, w, c, q);
#pragma unroll
        for (int r = 0; r < 4; ++r) {
            short hi, lo;
            cvt1(g[r], hi, lo);
            int dr = 16 * mt + 4 * q + r, dc = 16 * w + c;
            Gp[dr * 136 + dc] = (unsigned short)hi;
            Gp[dr * 136 + 64 + dc] = (unsigned short)lo;
        }
    }
    if (tid < 64) {
        b2_s[tid] = fw_b2[h * 64 + tid];
        lg_s[tid] = fw_lng[h * 64 + tid];
        lb_s[tid] = fw_lnb[h * 64 + tid];
        tG_s[tid] = ttt_gv[h * 64 + tid];
        tB_s[tid] = ttt_bv[h * 64 + tid];
        float c1 = 0.f;                      // c1[d] = sum_e Lb[e]*Lw[d,e]
        for (int e = 0; e < 64; ++e) c1 += loss_bv[e] * loss_w[tid * 64 + e];
        c1_s[tid] = c1;
    }

    // ---- stage token 0 (Kp/KT/TGp) and hold q(0) in registers
    float2 pk, pv, pq, q_cur;
    {
        int idx = ((bb * Sv + 0) * Hv + h) * Dv + j0;
        float2 k0 = *(const float2 *)&k_g[idx];
        float2 v0 = *(const float2 *)&v_g[idx];
        q_cur = *(const float2 *)&q_g[idx];
        unsigned khw, klw;
        cvt2(k0.x, k0.y, khw, klw);
        *(unsigned *)&Kp[bb * 136 + j0] = khw;
        *(unsigned *)&Kp[bb * 136 + 64 + j0] = klw;
        KT[j0 * 16 + bb] = (unsigned short)khw;
        KT[j0 * 16 + 8 + bb] = (unsigned short)klw;
        KT[(j0 + 1) * 16 + bb] = (unsigned short)(khw >> 16);
        KT[(j0 + 1) * 16 + 8 + bb] = (unsigned short)(klw >> 16);
        unsigned thw, tlw;
        cvt2(v0.x - k0.x, v0.y - k0.y, thw, tlw);
        *(unsigned *)&TGp[bb * 136 + j0] = thw;
        *(unsigned *)&TGp[bb * 136 + 64 + j0] = tlw;
    }
    // register-carried params (per lane, q<2 lanes meaningful)
    float b1_r = (q < 2) ? fw_b1[h * 64 + 16 * w + c] : 0.f;
    __syncthreads();
    float c1_r = c1_s[16 * w + c];
    f32x4 gd_r = {0.f, 0.f, 0.f, 0.f};
    f32x4 tgl_r = {0.f, 0.f, 0.f, 0.f};

#pragma unroll 1
    for (int t = 0; t < Sv; ++t) {
        // issue prefetch for token t+1 (consumed at F2fin staging / epilogue)
        if (t + 1 < Sv) {
            int idx2 = ((bb * Sv + t + 1) * Hv + h) * Dv + j0;
            pk = *(const float2 *)&k_g[idx2];
            pv = *(const float2 *)&v_g[idx2];
            pq = *(const float2 *)&q_g[idx2];
        }

        // ---- F1o: acc1 = k@W1 (kept in regs all token); tgl_r; Kg; gelu
        f32x4 acc1 = mm64(Kp, W1T, w, c, q);
        {
            f32x4 a2 = mm64(TGp, LwR, w, c, q);
            if (q < 2) {
#pragma unroll
                for (int r = 0; r < 4; ++r) tgl_r[r] = a2[r] - c1_r;
            }
        }
        if (w == 0) {
            // Kg = K@K^T (rows/cols >=8 are zero via Kp padding); store -LR*Kg
            f32x4 kg = mm64(Kp, Kp, 0, c, q);
            if (q < 2) {
#pragma unroll
                for (int r = 0; r < 4; ++r) {
                    short hi, lo;
                    cvt1(-LR * kg[r], hi, lo);
                    KgT[c * 16 + 4 * q + r] = (unsigned short)hi;
                    KgT[c * 16 + 8 + 4 * q + r] = (unsigned short)lo;
                }
            }
        }
        if (q < 2) {
            int col = 16 * w + c;
            float gv[4];
#pragma unroll
            for (int r = 0; r < 4; ++r) {
                float g, dg;
                gelu_both(acc1[r] + b1_r, g, dg);
                gv[r] = g;
                gd_r[r] = dg;
            }
            unsigned h01, l01, h23, l23;
            cvt2(gv[0], gv[1], h01, l01);
            cvt2(gv[2], gv[3], h23, l23);
            Hp[(4 * q + 0) * 136 + col] = (unsigned short)h01;
            Hp[(4 * q + 1) * 136 + col] = (unsigned short)(h01 >> 16);
            Hp[(4 * q + 2) * 136 + col] = (unsigned short)h23;
            Hp[(4 * q + 3) * 136 + col] = (unsigned short)(h23 >> 16);
            Hp[(4 * q + 0) * 136 + 64 + col] = (unsigned short)l01;
            Hp[(4 * q + 1) * 136 + 64 + col] = (unsigned short)(l01 >> 16);
            Hp[(4 * q + 2) * 136 + 64 + col] = (unsigned short)l23;
            Hp[(4 * q + 3) * 136 + 64 + col] = (unsigned short)(l23 >> 16);
            uint2 hh, hl;
            hh.x = h01; hh.y = h23;
            hl.x = l01; hl.y = l23;
            *(uint2 *)&HT0[col * 16 + 4 * q] = hh;
            *(uint2 *)&HT0[col * 16 + 8 + 4 * q] = hl;
        }
        __syncthreads();

#pragma unroll 1
        for (int step = 0; step < 4; ++step) {
            const unsigned short *HTr = (step & 1) ? HT1 : HT0;
            unsigned short *HTw = (step & 1) ? HT0 : HT1;
            // F2: o = h@W2 + b2
            f32x4 acc = mm64(Hp, W2T, w, c, q);
            if (q < 2) {
                float bias = b2_s[16 * w + c];
#pragma unroll
                for (int r = 0; r < 4; ++r)
                    o_s[(4 * q + r) * 68 + 16 * w + c] = acc[r] + bias;
            }
            __syncthreads();
            // LN fwd (thread-mapped, single-pass: independent S, S2 chains)
            float xh0_r, xh1_r;
            {
                float2 xv = *(const float2 *)&o_s[bb * 68 + j0];
                float s = red32(xv.x + xv.y);
                float s2 = red32(xv.x * xv.x + xv.y * xv.y);
                float mu = s * (1.f / 64.f);
                float var = s2 * (1.f / 64.f) - mu * mu;
                float rs = rsqrtf(var + 1e-5f);
                float xh0 = (xv.x - mu) * rs, xh1 = (xv.y - mu) * rs;
                float2 xw; xw.x = xh0; xw.y = xh1;
                *(float2 *)&xh_s[bb * 68 + j0] = xw;
                float z0 = xh0 * lg_s[j0] + lb_s[j0];
                float z1 = xh1 * lg_s[j0 + 1] + lb_s[j0 + 1];
                unsigned zh, zl;
                cvt2(z0, z1, zh, zl);
                *(unsigned *)&Zp[bb * 136 + j0] = zh;
                *(unsigned *)&Zp[bb * 136 + 64 + j0] = zl;
                if ((tid & 31) == 0) rstd_s[bb] = rs;
                xh0_r = xh0; xh1_r = xh1;
            }
            __syncthreads();
            // B1' (fused F3+B1): dz = SCALE * (z@G - tgl_r)
            acc = mm64(Zp, Gp, w, c, q);
            if (q < 2) {
                int col = 16 * w + c;
#pragma unroll
                for (int r = 0; r < 4; ++r)
                    o_s[(4 * q + r) * 68 + col] = (acc[r] - tgl_r[r]) * SCALE;
            }
            __syncthreads();
            // LN bwd (thread-mapped) -> do planes + doT
            {
                float2 dzv = *(const float2 *)&o_s[bb * 68 + j0];
                float dxh0 = dzv.x * lg_s[j0], dxh1 = dzv.y * lg_s[j0 + 1];
                float S1 = red32(dxh0 + dxh1) * (1.f / 64.f);
                float S2 = red32(dxh0 * xh0_r + dxh1 * xh1_r) * (1.f / 64.f);
                float rs = rstd_s[bb];
                float do0 = rs * (dxh0 - S1 - xh0_r * S2);
                float do1 = rs * (dxh1 - S1 - xh1_r * S2);
                unsigned dh, dl;
                cvt2(do0, do1, dh, dl);
                *(unsigned *)&DOp[bb * 136 + j0] = dh;
                *(unsigned *)&DOp[bb * 136 + 64 + j0] = dl;
                DOT[j0 * 16 + bb] = (unsigned short)dh;
                DOT[j0 * 16 + 8 + bb] = (unsigned short)dl;
                DOT[(j0 + 1) * 16 + bb] = (unsigned short)(dh >> 16);
                DOT[(j0 + 1) * 16 + 8 + bb] = (unsigned short)(dl >> 16);
            }
            __syncthreads();
            // B2+upd+F1' (single phase): prefetch stable operands into regs
            // (A-frags KT/HTr/DOT, B-frags DOT/HTr, KgT) so their LDS
            // latency hides under mm64; then dh=do@W2^T; da; the da
            // B-fragment is built via cross-lane SHUFFLE (no DAT LDS
            // round-trip); 3x updW3 (f32 masters); acc1 += (-LR*Kg)@da;
            // gelu (step3 instance IS the final forward h).
            bf16x8 zf8;
#pragma unroll
            for (int j = 0; j < 8; ++j) zf8[j] = 0;
            bf16x8 aK[4], aH[4], aD[4];
#pragma unroll
            for (int mt = 0; mt < 4; ++mt) {
                aK[mt] = *(const bf16x8 *)&KT[(16 * mt + c) * 16 + (q & 1) * 8];
                aH[mt] = *(const bf16x8 *)&HTr[(16 * mt + c) * 16 + (q & 1) * 8];
                aD[mt] = *(const bf16x8 *)&DOT[(16 * mt + c) * 16 + (q & 1) * 8];
            }
            bf16x8 bDO = zf8, bHT = zf8;
            if (q < 2) {
                bDO = *(const bf16x8 *)&DOT[(16 * w + c) * 16];
                bHT = *(const bf16x8 *)&HTr[(16 * w + c) * 16];
            } else if (q == 2) {
                bDO = *(const bf16x8 *)&DOT[(16 * w + c) * 16 + 8];
                bHT = *(const bf16x8 *)&HTr[(16 * w + c) * 16 + 8];
            }
            bf16x8 aKg = *(const bf16x8 *)&KgT[c * 16 + (q & 1) * 8];
            acc = mm64(DOp, W2R, w, c, q);
            {
                float b1sum = 0.f;
                uint2 th; th.x = 0u; th.y = 0u;
                uint2 tl; tl.x = 0u; tl.y = 0u;
                if (q < 2) {
                    float da0 = acc[0] * gd_r[0];
                    float da1 = acc[1] * gd_r[1];
                    float da2 = acc[2] * gd_r[2];
                    float da3 = acc[3] * gd_r[3];
                    b1sum = da0 + da1 + da2 + da3;
                    unsigned h01, l01, h23, l23;
                    cvt2(da0, da1, h01, l01);
                    cvt2(da2, da3, h23, l23);
                    th.x = h01; th.y = h23;
                    tl.x = l01; tl.y = l23;
                }
                b1sum += __shfl_xor(b1sum, 16);
                // bDA frag via shuffle: rows 0-3 from lane (c,0), rows 4-7
                // from lane (c,1). q<2 lanes need hi words, q==2 lo words.
                unsigned hx0 = (unsigned)__shfl((int)th.x, c);
                unsigned hy0 = (unsigned)__shfl((int)th.y, c);
                unsigned hx1 = (unsigned)__shfl((int)th.x, c + 16);
                unsigned hy1 = (unsigned)__shfl((int)th.y, c + 16);
                unsigned lx0 = (unsigned)__shfl((int)tl.x, c);
                unsigned ly0 = (unsigned)__shfl((int)tl.y, c);
                unsigned lx1 = (unsigned)__shfl((int)tl.x, c + 16);
                unsigned ly1 = (unsigned)__shfl((int)tl.y, c + 16);
                u32x4 Bw = {0u, 0u, 0u, 0u};
                if (q < 2) {
                    Bw[0] = hx0; Bw[1] = hy0; Bw[2] = hx1; Bw[3] = hy1;
                } else if (q == 2) {
                    Bw[0] = lx0; Bw[1] = ly0; Bw[2] = lx1; Bw[3] = ly1;
                }
                bf16x8 bDA = __builtin_bit_cast(bf16x8, Bw);
                updW3(aK, bDA, w1m, W1T, w, c, q);
                updW3(aH, bDO, w2m, W2T, w, c, q);
                updW3(aD, bHT, w2rm, W2R, w, c, q);
                if (w == 2) {
                    bf16x8 oh_ = *(const bf16x8 *)&DOT[lane * 16];
                    bf16x8 ol_ = *(const bf16x8 *)&DOT[lane * 16 + 8];
                    float db2 = 0.f;
#pragma unroll
                    for (int j = 0; j < 8; ++j)
                        db2 += bf2f(oh_[j]) + bf2f(ol_[j]);
                    b2_s[lane] -= LR * db2;
                } else if (w == 3) {
                    float dlb = 0.f, dlg = 0.f;
#pragma unroll
                    for (int b = 0; b < 8; ++b) {
                        float dzv = o_s[b * 68 + lane];
                        dlb += dzv;
                        dlg += dzv * xh_s[b * 68 + lane];
                    }
                    lb_s[lane] -= LR * dlb;
                    lg_s[lane] -= LR * dlg;
                }
                // F1': incremental pre-activation + activation for next step
                acc1 = MFMA16(aKg, bDA, acc1);
                b1_r -= LR * b1sum;
                if (q < 2) {
                    int col = 16 * w + c;
                    if (step < 3) {
                        float gv[4];
#pragma unroll
                        for (int r = 0; r < 4; ++r) {
                            float g, dg;
                            gelu_both(acc1[r] + b1_r, g, dg);
                            gv[r] = g;
                            gd_r[r] = dg;
                        }
                        unsigned h01, l01, h23, l23;
                        cvt2(gv[0], gv[1], h01, l01);
                        cvt2(gv[2], gv[3], h23, l23);
                        Hp[(4 * q + 0) * 136 + col] = (unsigned short)h01;
                        Hp[(4 * q + 1) * 136 + col] = (unsigned short)(h01 >> 16);
                        Hp[(4 * q + 2) * 136 + col] = (unsigned short)h23;
                        Hp[(4 * q + 3) * 136 + col] = (unsigned short)(h23 >> 16);
                        Hp[(4 * q + 0) * 136 + 64 + col] = (unsigned short)l01;
                        Hp[(4 * q + 1) * 136 + 64 + col] = (unsigned short)(l01 >> 16);
                        Hp[(4 * q + 2) * 136 + 64 + col] = (unsigned short)l23;
                        Hp[(4 * q + 3) * 136 + 64 + col] = (unsigned short)(l23 >> 16);
                        uint2 hh, hl;
                        hh.x = h01; hh.y = h23;
                        hl.x = l01; hl.y = l23;
                        *(uint2 *)&HTw[col * 16 + 4 * q] = hh;
                        *(uint2 *)&HTw[col * 16 + 8 + 4 * q] = hl;
                    } else {
                        // final forward h (feeds F2fin); no HT/gd needed
                        float gv[4];
#pragma unroll
                        for (int r = 0; r < 4; ++r)
                            gv[r] = gelu_f(acc1[r] + b1_r);
                        unsigned h01, l01, h23, l23;
                        cvt2(gv[0], gv[1], h01, l01);
                        cvt2(gv[2], gv[3], h23, l23);
                        Hp[(4 * q + 0) * 136 + col] = (unsigned short)h01;
                        Hp[(4 * q + 1) * 136 + col] = (unsigned short)(h01 >> 16);
                        Hp[(4 * q + 2) * 136 + col] = (unsigned short)h23;
                        Hp[(4 * q + 3) * 136 + col] = (unsigned short)(h23 >> 16);
                        Hp[(4 * q + 0) * 136 + 64 + col] = (unsigned short)l01;
                        Hp[(4 * q + 1) * 136 + 64 + col] = (unsigned short)(l01 >> 16);
                        Hp[(4 * q + 2) * 136 + 64 + col] = (unsigned short)l23;
                        Hp[(4 * q + 3) * 136 + 64 + col] = (unsigned short)(l23 >> 16);
                    }
                }
            }
            __syncthreads();
        }

        // ---- F2fin: o = h_final@W2 + b2 ; stage token t+1 (Kp/KT/TGp)
        f32x4 acc = mm64(Hp, W2T, w, c, q);
        if (q < 2) {
            float bias = b2_s[16 * w + c];
#pragma unroll
            for (int r = 0; r < 4; ++r)
                o_s[(4 * q + r) * 68 + 16 * w + c] = acc[r] + bias;
        }
        if (t + 1 < Sv) {
            unsigned khw, klw;
            cvt2(pk.x, pk.y, khw, klw);
            *(unsigned *)&Kp[bb * 136 + j0] = khw;
            *(unsigned *)&Kp[bb * 136 + 64 + j0] = klw;
            KT[j0 * 16 + bb] = (unsigned short)khw;
            KT[j0 * 16 + 8 + bb] = (unsigned short)klw;
            KT[(j0 + 1) * 16 + bb] = (unsigned short)(khw >> 16);
            KT[(j0 + 1) * 16 + 8 + bb] = (unsigned short)(klw >> 16);
            unsigned thw, tlw;
            cvt2(pv.x - pk.x, pv.y - pk.y, thw, tlw);
            *(unsigned *)&TGp[bb * 136 + j0] = thw;
            *(unsigned *)&TGp[bb * 136 + 64 + j0] = tlw;
        }
        __syncthreads();
        // epilogue: LN(lg,lb) -> LN(ttt_g,ttt_b) -> out = q + z2
        // (single-pass variance; no trailing barrier: F1o's end-barrier
        // orders the o_s reuse)
        {
            float2 xv = *(const float2 *)&o_s[bb * 68 + j0];
            float s = red32(xv.x + xv.y);
            float s2 = red32(xv.x * xv.x + xv.y * xv.y);
            float mu = s * (1.f / 64.f);
            float var = s2 * (1.f / 64.f) - mu * mu;
            float rs = rsqrtf(var + 1e-5f);
            float z0 = (xv.x - mu) * rs * lg_s[j0] + lb_s[j0];
            float z1 = (xv.y - mu) * rs * lg_s[j0 + 1] + lb_s[j0 + 1];
            float sb = red32(z0 + z1);
            float s2b = red32(z0 * z0 + z1 * z1);
            float mu2 = sb * (1.f / 64.f);
            float var2 = s2b * (1.f / 64.f) - mu2 * mu2;
            float rs2 = rsqrtf(var2 + 1e-5f);
            float z20 = (z0 - mu2) * rs2 * tG_s[j0] + tB_s[j0];
            float z21 = (z1 - mu2) * rs2 * tG_s[j0 + 1] + tB_s[j0 + 1];
            int idx = ((bb * Sv + t) * Hv + h) * Dv + j0;
            float2 ov;
            ov.x = q_cur.x + z20;
            ov.y = q_cur.y + z21;
            *(float2 *)&out_g[idx] = ov;
            q_cur = pq;
        }
    }
}

// ---------------------------------------------------------------------------
// fp32 GEMM: C[M,N] = A[M,K] @ B[K,N]; mode 1: C = gelu(acc) * gate_ln
// ---------------------------------------------------------------------------
__global__ __launch_bounds__(256) void gemm_f32(
    const float *__restrict__ A, const float *__restrict__ B,
    float *__restrict__ C, const float *__restrict__ gate_ln,
    int M, int N, int K, int mode) {
    __shared__ float As[16][68];
    __shared__ float Bs[16][64];
    const int tid = threadIdx.x;
    const int tx = tid & 15, ty = tid >> 4;
    const int bm = blockIdx.y * 64, bn = blockIdx.x * 64;

    float acc[4][4] = {};
    for (int k0 = 0; k0 < K; k0 += 16) {
        {
            int r = tid >> 2, kk = (tid & 3) * 4;
            float4 av = *(const float4 *)(A + (long)(bm + r) * K + k0 + kk);
            As[kk + 0][r] = av.x;
            As[kk + 1][r] = av.y;
            As[kk + 2][r] = av.z;
            As[kk + 3][r] = av.w;
            int rr = tid >> 4, cc = (tid & 15) * 4;
            float4 bv = *(const float4 *)(B + (long)(k0 + rr) * N + bn + cc);
            *(float4 *)&Bs[rr][cc] = bv;
        }
        __syncthreads();
#pragma unroll
        for (int kk = 0; kk < 16; ++kk) {
            float4 a4 = *(float4 *)&As[kk][ty * 4];
            float4 b4 = *(float4 *)&Bs[kk][tx * 4];
            float a[4] = {a4.x, a4.y, a4.z, a4.w};
            float b[4] = {b4.x, b4.y, b4.z, b4.w};
#pragma unroll
            for (int i = 0; i < 4; ++i)
#pragma unroll
                for (int j = 0; j < 4; ++j) acc[i][j] += a[i] * b[j];
        }
        __syncthreads();
    }
#pragma unroll
    for (int i = 0; i < 4; ++i) {
        int row = bm + ty * 4 + i;
        float4 out;
        float v[4];
#pragma unroll
        for (int j = 0; j < 4; ++j) {
            float val = acc[i][j];
            if (mode == 1) {
                int col = bn + tx * 4 + j;
                val = gelu_f(val) * gate_ln[(long)row * N + col];
            }
            v[j] = val;
        }
        out.x = v[0]; out.y = v[1]; out.z = v[2]; out.w = v[3];
        *(float4 *)(C + (long)row * N + bn + tx * 4) = out;
    }
}

// ---------------------------------------------------------------------------
// Row LayerNorm over 1024 (post-scan, pn_g / pn_b)
// ---------------------------------------------------------------------------
__global__ __launch_bounds__(256) void row_ln(const float *__restrict__ in,
                                              float *__restrict__ out,
                                              const float *__restrict__ g,
                                              const float *__restrict__ b) {
    __shared__ float sred[4], s2red[4];
    const int row = blockIdx.x;
    const int tid = threadIdx.x;
    const float *x = in + (long)row * 1024;
    float4 v = *(const float4 *)(x + tid * 4);
    float s = v.x + v.y + v.z + v.w;
    float s2 = v.x * v.x + v.y * v.y + v.z * v.z + v.w * v.w;
#pragma unroll
    for (int m = 1; m <= 32; m <<= 1) {
        s += __shfl_xor(s, m);
        s2 += __shfl_xor(s2, m);
    }
    if ((tid & 63) == 0) {
        sred[tid >> 6] = s;
        s2red[tid >> 6] = s2;
    }
    __syncthreads();
    float S = sred[0] + sred[1] + sred[2] + sred[3];
    float S2 = s2red[0] + s2red[1] + s2red[2] + s2red[3];
    float mu = S * (1.f / 1024.f);
    float var = S2 * (1.f / 1024.f) - mu * mu;
    float rs = rsqrtf(var + 1e-5f);
    float o[4] = {v.x, v.y, v.z, v.w};
    float4 ov;
    float r[4];
#pragma unroll
    for (int i = 0; i < 4; ++i) {
        int col = tid * 4 + i;
        r[i] = (o[i] - mu) * rs * g[col] + b[col];
    }
    ov.x = r[0]; ov.y = r[1]; ov.z = r[2]; ov.w = r[3];
    *(float4 *)(out + (long)row * 1024 + tid * 4) = ov;
}

// ---------------------------------------------------------------------------
// Launch
// ---------------------------------------------------------------------------
extern "C" void kernel_launch(void *const *d_in, const int *in_sizes, int n_in,
                              void *d_out, int out_size, void *d_ws,
                              size_t ws_size, hipStream_t stream) {
    const float *x = (const float *)d_in[0];
    const float *wq = (const float *)d_in[1];
    const float *wk = (const float *)d_in[2];
    const float *wv = (const float *)d_in[3];
    const float *fw_w1 = (const float *)d_in[4];
    const float *fw_b1 = (const float *)d_in[5];
    const float *fw_w2 = (const float *)d_in[6];
    const float *fw_b2 = (const float *)d_in[7];
    const float *fw_lng = (const float *)d_in[8];
    const float *fw_lnb = (const float *)d_in[9];
    const float *loss_w = (const float *)d_in[10];
    const float *loss_b = (const float *)d_in[11];
    const float *ttt_g = (const float *)d_in[12];
    const float *ttt_b = (const float *)d_in[13];
    const float *wo = (const float *)d_in[14];
    const float *wg = (const float *)d_in[15];
    const float *pn_g = (const float *)d_in[16];
    const float *pn_b = (const float *)d_in[17];

    const long MAT = 2048L * 1024L;
    float *q_ws = (float *)d_ws;
    float *k_ws = q_ws + MAT;
    float *v_ws = k_ws + MAT;
    float *out_ws = v_ws + MAT;
    float *ln_ws = k_ws;       // reuse (k dead after scan)
    float *gated_ws = v_ws;    // reuse (v dead after scan)

    dim3 gg(1024 / 64, 2048 / 64), bt(256);
    hipLaunchKernelGGL(gemm_f32, gg, bt, 0, stream, x, wq, q_ws,
                       (const float *)nullptr, 2048, 1024, 1024, 0);
    hipLaunchKernelGGL(gemm_f32, gg, bt, 0, stream, x, wk, k_ws,
                       (const float *)nullptr, 2048, 1024, 1024, 0);
    hipLaunchKernelGGL(gemm_f32, gg, bt, 0, stream, x, wv, v_ws,
                       (const float *)nullptr, 2048, 1024, 1024, 0);

    (void)hipFuncSetAttribute((const void *)ttt_scan,
                              hipFuncAttributeMaxDynamicSharedMemorySize,
                              LDS_BYTES);
    hipLaunchKernelGGL(ttt_scan, dim3(16), dim3(256), LDS_BYTES, stream,
                       q_ws, k_ws, v_ws, out_ws, fw_w1, fw_b1, fw_w2, fw_b2,
                       fw_lng, fw_lnb, loss_w, loss_b, ttt_g, ttt_b);

    hipLaunchKernelGGL(row_ln, dim3(2048), dim3(256), 0, stream, out_ws, ln_ws,
                       pn_g, pn_b);
    hipLaunchKernelGGL(gemm_f32, gg, bt, 0, stream, x, wg, gated_ws, ln_ws,
                       2048, 1024, 1024, 1);
    hipLaunchKernelGGL(gemm_f32, gg, bt, 0, stream, gated_ws, wo,
                       (float *)d_out, (const float *)nullptr, 2048, 1024,
                       1024, 0);
}

// Round 10
// 3760.219 us; speedup vs baseline: 1.2005x; 1.0426x over previous
//
#include <hip/hip_runtime.h>

// ---------------------------------------------------------------------------
// Problem constants
// ---------------------------------------------------------------------------
#define Bv 8
#define Sv 256
#define Hv 16
#define Dv 64
#define LR 0.1f
#define SCALE (2.0f / 8192.0f)   // dLoss/dpred scale: 2/(B*H*D)

using bf16x8 = __attribute__((ext_vector_type(8))) short;
using bf16x4 = __attribute__((ext_vector_type(4))) short;
using f32x4  = __attribute__((ext_vector_type(4))) float;
using u32x4  = __attribute__((ext_vector_type(4))) unsigned;
#define MFMA16(A, B, C) __builtin_amdgcn_mfma_f32_16x16x32_bf16(A, B, C, 0, 0, 0)

// ---------------------------------------------------------------------------
// LDS layout (ushort units for bf16 planes, float units for fp32 areas)
// Weight/row planes: pitch 136 ushort = 272 B (hi[64] | lo[64] | pad[8]).
// T arrays: pitch 16 ushort = 32 B (hi[8] | lo[8]).
// ---------------------------------------------------------------------------
constexpr int U_W1T = 0;          // [f][d] planes, 64x136
constexpr int U_W2T = 8704;      // [d][f]
constexpr int U_W2R = 17408;     // [f][d]
constexpr int U_G   = 26112;     // [d][d']  (symmetric, static)
constexpr int U_LwR = 34816;     // [d][e]   (static)
constexpr int U_K   = 43520;     // [b pad16][d] 16x136
constexpr int U_H   = 45696;     // [b][f]
constexpr int U_Z   = 47872;     // [b][d]
constexpr int U_TG  = 50048;     // [b pad16][e] target planes
constexpr int U_DO  = 52224;     // [b][d]
constexpr int U_KT  = 54400;     // [d][b] 64x16
constexpr int U_HT  = 55424;     // [f][b]  (buffer 0)
constexpr int U_DOT = 56448;     // [d][b]
constexpr int U_DAT = 57472;     // (unused now - DAT lives in registers/shfl)
constexpr int F_BASE = 29248;    // = 58496/2
constexpr int F_O   = F_BASE;        // o / dz shared, [8][68]
constexpr int F_XH  = F_BASE + 544;
constexpr int F_GD  = F_XH + 544;    // (unused)
constexpr int F_TGL = F_GD + 544;    // (unused)
constexpr int F_B1  = F_TGL + 544;   // (unused)
constexpr int F_B2  = F_B1 + 64;
constexpr int F_LG  = F_B2 + 64;
constexpr int F_LB  = F_LG + 64;
constexpr int F_C1  = F_LB + 64;     // Lb @ Lw^T (static)
constexpr int F_TGm = F_C1 + 64;
constexpr int F_TBm = F_TGm + 64;
constexpr int F_RSTD = F_TBm + 64;
constexpr int U_KG  = (F_RSTD + 8) * 2;   // -LR*K*K^T, [16][hi8|lo8]
constexpr int U_HT2 = U_KG + 256;         // HT buffer 1
constexpr int LDS_BYTES = (U_HT2 + 1024) * 2;   // 130080 B

// ---------------------------------------------------------------------------
// Helpers
// ---------------------------------------------------------------------------
__device__ __forceinline__ short bf_rn(float v) {
    unsigned u = __float_as_uint(v);
    unsigned r = u + 0x7fffu + ((u >> 16) & 1u);   // round-to-nearest-even
    return (short)(r >> 16);
}
__device__ __forceinline__ void cvt1(float v, short &hi, short &lo) {
    hi = bf_rn(v);
    float hf = __uint_as_float(((unsigned)(unsigned short)hi) << 16);
    lo = bf_rn(v - hf);
}
__device__ __forceinline__ float bf2f(short u) {
    return __uint_as_float(((unsigned)(unsigned short)u) << 16);
}
// Packed bf16 pair conversion: 1 instruction converts 2 floats (RTNE).
__device__ __forceinline__ unsigned cvtpk(float a, float b) {
    unsigned r;
    asm("v_cvt_pk_bf16_f32 %0, %1, %2" : "=v"(r) : "v"(a), "v"(b));
    return r;                      // lo16 = bf16(a), hi16 = bf16(b)
}
// hi/lo split of a float pair: hw = packed hi-bf16s, lw = packed lo-bf16s.
__device__ __forceinline__ void cvt2(float a, float b, unsigned &hw,
                                     unsigned &lw) {
    hw = cvtpk(a, b);
    float ra = a - __uint_as_float(hw << 16);
    float rb = b - __uint_as_float(hw & 0xffff0000u);
    lw = cvtpk(ra, rb);
}
// DPP-based 32-lane sum.
template <int CTRL>
__device__ __forceinline__ float dpp_add(float v) {
    int s = __builtin_amdgcn_update_dpp(0, __float_as_int(v), CTRL, 0xF, 0xF,
                                        true);
    return v + __int_as_float(s);
}
__device__ __forceinline__ float red32(float v) {
    v = dpp_add<0xB1>(v);    // quad_perm [1,0,3,2]  (xor 1)
    v = dpp_add<0x4E>(v);    // quad_perm [2,3,0,1]  (xor 2)
    v = dpp_add<0x124>(v);   // row_ror:4
    v = dpp_add<0x128>(v);   // row_ror:8
    v += __shfl_xor(v, 16);  // merge the two 16-rows of the 32-group
    return v;
}
__device__ __forceinline__ float fast_tanh(float u) {
    u = fminf(fmaxf(u, -10.f), 10.f);
    float e = __expf(2.0f * u);
    return (e - 1.0f) / (e + 1.0f);
}
__device__ __forceinline__ void gelu_both(float x, float &g, float &dg) {
    const float C0 = 0.7978845608028654f, A0 = 0.044715f;
    float x2 = x * x;
    float u = C0 * x * (1.0f + A0 * x2);
    float t = fast_tanh(u);
    g = 0.5f * x * (1.0f + t);
    float du = C0 * (1.0f + 3.0f * A0 * x2);
    dg = 0.5f * (1.0f + t) + 0.5f * x * (1.0f - t * t) * du;
}
__device__ __forceinline__ float gelu_f(float x) {
    const float C0 = 0.7978845608028654f, A0 = 0.044715f;
    float u = C0 * x * (1.0f + A0 * x * x);
    return 0.5f * x * (1.0f + fast_tanh(u));
}

// C[16x16 tile w] = A(16x64, row planes) @ B(64x64 via n-major planes)
// 3-term split product (hh + lh + hl; the ll term is ~2^-17 relative and
// dropped — same packing precedent as updW since round 2).
__device__ __forceinline__ f32x4 mm64(const unsigned short *Ap,
                                      const unsigned short *Bp,
                                      int w, int c, int q) {
    const unsigned short *ar = Ap + c * 136 + 8 * q;
    const unsigned short *br = Bp + (16 * w + c) * 136 + 8 * q;
    bf16x8 ah0 = *(const bf16x8 *)(ar);
    bf16x8 al0 = *(const bf16x8 *)(ar + 64);
    bf16x8 bh0 = *(const bf16x8 *)(br);
    bf16x8 bl0 = *(const bf16x8 *)(br + 64);
    bf16x8 ah1 = *(const bf16x8 *)(ar + 32);
    bf16x8 al1 = *(const bf16x8 *)(ar + 96);
    bf16x8 bh1 = *(const bf16x8 *)(br + 32);
    bf16x8 bl1 = *(const bf16x8 *)(br + 96);
    f32x4 x0 = {0.f, 0.f, 0.f, 0.f}, x1 = {0.f, 0.f, 0.f, 0.f};
    x0 = MFMA16(ah0, bh0, x0); x1 = MFMA16(ah1, bh1, x1);
    x0 = MFMA16(al0, bh0, x0); x1 = MFMA16(al1, bh1, x1);
    x0 = MFMA16(ah0, bl0, x0); x1 = MFMA16(ah1, bl1, x1);
    return x0 + x1;
}

// W update with f32 master weights in registers (validated in round 7).
// Lane (c,q) owns W elements (row 16w+c, col 16mt+4q+r) == exactly this
// lane's gradient outputs. g = X^T@Y via packed-K MFMA; master -= LR*g;
// planes = cvt2(master). No W-plane reads.
__device__ __forceinline__ void updW3(const bf16x8 *a4, bf16x8 b,
                                      float (&m)[16], unsigned short *WT,
                                      int w, int c, int q) {
    f32x4 g[4];
#pragma unroll
    for (int mt = 0; mt < 4; ++mt) {
        f32x4 z = {0.f, 0.f, 0.f, 0.f};
        g[mt] = MFMA16(a4[mt], b, z);
    }
    unsigned short *p0 = &WT[(16 * w + c) * 136 + 4 * q];
#pragma unroll
    for (int mt = 0; mt < 4; ++mt) {
        m[mt * 4 + 0] -= LR * g[mt][0];
        m[mt * 4 + 1] -= LR * g[mt][1];
        m[mt * 4 + 2] -= LR * g[mt][2];
        m[mt * 4 + 3] -= LR * g[mt][3];
        unsigned nh0, nl0, nh1, nl1;
        cvt2(m[mt * 4 + 0], m[mt * 4 + 1], nh0, nl0);
        cvt2(m[mt * 4 + 2], m[mt * 4 + 3], nh1, nl1);
        uint2 nh, nl;
        nh.x = nh0; nh.y = nh1;
        nl.x = nl0; nl.y = nl1;
        *(uint2 *)(p0 + 16 * mt) = nh;
        *(uint2 *)(p0 + 16 * mt + 64) = nl;
    }
}

// ---------------------------------------------------------------------------
// TTT scan kernel: one block (256 thr = 4 waves) per head
// (byte-identical to round 8 — 3457 us, absmax 0.0039; untouched this round)
// ---------------------------------------------------------------------------
__global__ __launch_bounds__(256) void ttt_scan(
    const float *__restrict__ q_g, const float *__restrict__ k_g,
    const float *__restrict__ v_g, float *__restrict__ out_g,
    const float *__restrict__ fw_w1, const float *__restrict__ fw_b1,
    const float *__restrict__ fw_w2, const float *__restrict__ fw_b2,
    const float *__restrict__ fw_lng, const float *__restrict__ fw_lnb,
    const float *__restrict__ loss_w, const float *__restrict__ loss_bv,
    const float *__restrict__ ttt_gv, const float *__restrict__ ttt_bv) {
    extern __shared__ char smem[];
    unsigned short *us = (unsigned short *)smem;
    float *fs = (float *)smem;

    unsigned short *W1T = us + U_W1T, *W2T = us + U_W2T, *W2R = us + U_W2R;
    unsigned short *Gp = us + U_G, *LwR = us + U_LwR;
    unsigned short *Kp = us + U_K, *Hp = us + U_H, *Zp = us + U_Z;
    unsigned short *TGp = us + U_TG, *DOp = us + U_DO;
    unsigned short *KT = us + U_KT, *HT0 = us + U_HT;
    unsigned short *DOT = us + U_DOT;
    unsigned short *KgT = us + U_KG, *HT1 = us + U_HT2;
    float *o_s = fs + F_O, *xh_s = fs + F_XH;
    float *b2_s = fs + F_B2, *lg_s = fs + F_LG;
    float *lb_s = fs + F_LB, *c1_s = fs + F_C1;
    float *tG_s = fs + F_TGm, *tB_s = fs + F_TBm, *rstd_s = fs + F_RSTD;

    const int h = blockIdx.x, tid = threadIdx.x;
    const int w = tid >> 6, lane = tid & 63, c = lane & 15, q = lane >> 4;
    const int bb = tid >> 5, j0 = (tid & 31) * 2;

    // ---- init: split weights into bf16 hi/lo planes
    for (int i = tid; i < 4096; i += 256) {
        int r = i >> 6, cc = i & 63;
        short hi, lo;
        cvt1(fw_w1[h * 4096 + i], hi, lo);           // [d=r][f=cc]
        W1T[cc * 136 + r] = (unsigned short)hi;
        W1T[cc * 136 + 64 + r] = (unsigned short)lo;
        cvt1(fw_w2[h * 4096 + i], hi, lo);           // [f=r][d=cc]
        W2T[cc * 136 + r] = (unsigned short)hi;
        W2T[cc * 136 + 64 + r] = (unsigned short)lo;
        W2R[r * 136 + cc] = (unsigned short)hi;
        W2R[r * 136 + 64 + cc] = (unsigned short)lo;
        cvt1(loss_w[i], hi, lo);                     // [d=r][e=cc]
        LwR[r * 136 + cc] = (unsigned short)hi;
        LwR[r * 136 + 64 + cc] = (unsigned short)lo;
    }
    // zero pad rows 8..15 of the activation row-plane arrays
    for (int i = tid; i < 5 * 8 * 128; i += 256) {
        int a = i / 128, u = i % 128;
        int arr = a >> 3, row = 8 + (a & 7);
        unsigned short *base = (arr == 0) ? Kp : (arr == 1) ? Hp
                              : (arr == 2) ? Zp : (arr == 3) ? TGp : DOp;
        base[row * 136 + u] = 0;
    }
    // f32 master weights in registers (validated r7): lane (c,q) of wave w
    // owns elements (plane-row 16w+c, plane-col 16mt+4q+r) of the 3 planes.
    float w1m[16], w2m[16], w2rm[16];
#pragma unroll
    for (int mt = 0; mt < 4; ++mt) {
#pragma unroll
        for (int r = 0; r < 4; ++r) {
            int el = 16 * mt + 4 * q + r;
            int row = 16 * w + c;
            w1m[mt * 4 + r] = fw_w1[h * 4096 + el * 64 + row];
            w2m[mt * 4 + r] = fw_w2[h * 4096 + el * 64 + row];
            w2rm[mt * 4 + r] = fw_w2[h * 4096 + row * 64 + el];
        }
    }
    __syncthreads();
    // G = Lw @ Lw^T (static; fuses F3+B1 into one phase per step)
#pragma unroll 1
    for (int mt = 0; mt < 4; ++mt) {
        f32x4 g = mm64(LwR + 16 * 136 * mt, LwR, w, c, q);
#pragma unroll
        for (int r = 0; r < 4; ++r) {
            short hi, lo;
            cvt1(g[r], hi, lo);
            int dr = 16 * mt + 4 * q + r, dc = 16 * w + c;
            Gp[dr * 136 + dc] = (unsigned short)hi;
            Gp[dr * 136 + 64 + dc] = (unsigned short)lo;
        }
    }
    if (tid < 64) {
        b2_s[tid] = fw_b2[h * 64 + tid];
        lg_s[tid] = fw_lng[h * 64 + tid];
        lb_s[tid] = fw_lnb[h * 64 + tid];
        tG_s[tid] = ttt_gv[h * 64 + tid];
        tB_s[tid] = ttt_bv[h * 64 + tid];
        float c1 = 0.f;                      // c1[d] = sum_e Lb[e]*Lw[d,e]
        for (int e = 0; e < 64; ++e) c1 += loss_bv[e] * loss_w[tid * 64 + e];
        c1_s[tid] = c1;
    }

    // ---- stage token 0 (Kp/KT/TGp) and hold q(0) in registers
    float2 pk, pv, pq, q_cur;
    {
        int idx = ((bb * Sv + 0) * Hv + h) * Dv + j0;
        float2 k0 = *(const float2 *)&k_g[idx];
        float2 v0 = *(const float2 *)&v_g[idx];
        q_cur = *(const float2 *)&q_g[idx];
        unsigned khw, klw;
        cvt2(k0.x, k0.y, khw, klw);
        *(unsigned *)&Kp[bb * 136 + j0] = khw;
        *(unsigned *)&Kp[bb * 136 + 64 + j0] = klw;
        KT[j0 * 16 + bb] = (unsigned short)khw;
        KT[j0 * 16 + 8 + bb] = (unsigned short)klw;
        KT[(j0 + 1) * 16 + bb] = (unsigned short)(khw >> 16);
        KT[(j0 + 1) * 16 + 8 + bb] = (unsigned short)(klw >> 16);
        unsigned thw, tlw;
        cvt2(v0.x - k0.x, v0.y - k0.y, thw, tlw);
        *(unsigned *)&TGp[bb * 136 + j0] = thw;
        *(unsigned *)&TGp[bb * 136 + 64 + j0] = tlw;
    }
    // register-carried params (per lane, q<2 lanes meaningful)
    float b1_r = (q < 2) ? fw_b1[h * 64 + 16 * w + c] : 0.f;
    __syncthreads();
    float c1_r = c1_s[16 * w + c];
    f32x4 gd_r = {0.f, 0.f, 0.f, 0.f};
    f32x4 tgl_r = {0.f, 0.f, 0.f, 0.f};

#pragma unroll 1
    for (int t = 0; t < Sv; ++t) {
        // issue prefetch for token t+1 (consumed at F2fin staging / epilogue)
        if (t + 1 < Sv) {
            int idx2 = ((bb * Sv + t + 1) * Hv + h) * Dv + j0;
            pk = *(const float2 *)&k_g[idx2];
            pv = *(const float2 *)&v_g[idx2];
            pq = *(const float2 *)&q_g[idx2];
        }

        // ---- F1o: acc1 = k@W1 (kept in regs all token); tgl_r; Kg; gelu
        f32x4 acc1 = mm64(Kp, W1T, w, c, q);
        {
            f32x4 a2 = mm64(TGp, LwR, w, c, q);
            if (q < 2) {
#pragma unroll
                for (int r = 0; r < 4; ++r) tgl_r[r] = a2[r] - c1_r;
            }
        }
        if (w == 0) {
            // Kg = K@K^T (rows/cols >=8 are zero via Kp padding); store -LR*Kg
            f32x4 kg = mm64(Kp, Kp, 0, c, q);
            if (q < 2) {
#pragma unroll
                for (int r = 0; r < 4; ++r) {
                    short hi, lo;
                    cvt1(-LR * kg[r], hi, lo);
                    KgT[c * 16 + 4 * q + r] = (unsigned short)hi;
                    KgT[c * 16 + 8 + 4 * q + r] = (unsigned short)lo;
                }
            }
        }
        if (q < 2) {
            int col = 16 * w + c;
            float gv[4];
#pragma unroll
            for (int r = 0; r < 4; ++r) {
                float g, dg;
                gelu_both(acc1[r] + b1_r, g, dg);
                gv[r] = g;
                gd_r[r] = dg;
            }
            unsigned h01, l01, h23, l23;
            cvt2(gv[0], gv[1], h01, l01);
            cvt2(gv[2], gv[3], h23, l23);
            Hp[(4 * q + 0) * 136 + col] = (unsigned short)h01;
            Hp[(4 * q + 1) * 136 + col] = (unsigned short)(h01 >> 16);
            Hp[(4 * q + 2) * 136 + col] = (unsigned short)h23;
            Hp[(4 * q + 3) * 136 + col] = (unsigned short)(h23 >> 16);
            Hp[(4 * q + 0) * 136 + 64 + col] = (unsigned short)l01;
            Hp[(4 * q + 1) * 136 + 64 + col] = (unsigned short)(l01 >> 16);
            Hp[(4 * q + 2) * 136 + 64 + col] = (unsigned short)l23;
            Hp[(4 * q + 3) * 136 + 64 + col] = (unsigned short)(l23 >> 16);
            uint2 hh, hl;
            hh.x = h01; hh.y = h23;
            hl.x = l01; hl.y = l23;
            *(uint2 *)&HT0[col * 16 + 4 * q] = hh;
            *(uint2 *)&HT0[col * 16 + 8 + 4 * q] = hl;
        }
        __syncthreads();

#pragma unroll 1
        for (int step = 0; step < 4; ++step) {
            const unsigned short *HTr = (step & 1) ? HT1 : HT0;
            unsigned short *HTw = (step & 1) ? HT0 : HT1;
            // F2: o = h@W2 + b2
            f32x4 acc = mm64(Hp, W2T, w, c, q);
            if (q < 2) {
                float bias = b2_s[16 * w + c];
#pragma unroll
                for (int r = 0; r < 4; ++r)
                    o_s[(4 * q + r) * 68 + 16 * w + c] = acc[r] + bias;
            }
            __syncthreads();
            // LN fwd (thread-mapped, single-pass: independent S, S2 chains)
            float xh0_r, xh1_r;
            {
                float2 xv = *(const float2 *)&o_s[bb * 68 + j0];
                float s = red32(xv.x + xv.y);
                float s2 = red32(xv.x * xv.x + xv.y * xv.y);
                float mu = s * (1.f / 64.f);
                float var = s2 * (1.f / 64.f) - mu * mu;
                float rs = rsqrtf(var + 1e-5f);
                float xh0 = (xv.x - mu) * rs, xh1 = (xv.y - mu) * rs;
                float2 xw; xw.x = xh0; xw.y = xh1;
                *(float2 *)&xh_s[bb * 68 + j0] = xw;
                float z0 = xh0 * lg_s[j0] + lb_s[j0];
                float z1 = xh1 * lg_s[j0 + 1] + lb_s[j0 + 1];
                unsigned zh, zl;
                cvt2(z0, z1, zh, zl);
                *(unsigned *)&Zp[bb * 136 + j0] = zh;
                *(unsigned *)&Zp[bb * 136 + 64 + j0] = zl;
                if ((tid & 31) == 0) rstd_s[bb] = rs;
                xh0_r = xh0; xh1_r = xh1;
            }
            __syncthreads();
            // B1' (fused F3+B1): dz = SCALE * (z@G - tgl_r)
            acc = mm64(Zp, Gp, w, c, q);
            if (q < 2) {
                int col = 16 * w + c;
#pragma unroll
                for (int r = 0; r < 4; ++r)
                    o_s[(4 * q + r) * 68 + col] = (acc[r] - tgl_r[r]) * SCALE;
            }
            __syncthreads();
            // LN bwd (thread-mapped) -> do planes + doT
            {
                float2 dzv = *(const float2 *)&o_s[bb * 68 + j0];
                float dxh0 = dzv.x * lg_s[j0], dxh1 = dzv.y * lg_s[j0 + 1];
                float S1 = red32(dxh0 + dxh1) * (1.f / 64.f);
                float S2 = red32(dxh0 * xh0_r + dxh1 * xh1_r) * (1.f / 64.f);
                float rs = rstd_s[bb];
                float do0 = rs * (dxh0 - S1 - xh0_r * S2);
                float do1 = rs * (dxh1 - S1 - xh1_r * S2);
                unsigned dh, dl;
                cvt2(do0, do1, dh, dl);
                *(unsigned *)&DOp[bb * 136 + j0] = dh;
                *(unsigned *)&DOp[bb * 136 + 64 + j0] = dl;
                DOT[j0 * 16 + bb] = (unsigned short)dh;
                DOT[j0 * 16 + 8 + bb] = (unsigned short)dl;
                DOT[(j0 + 1) * 16 + bb] = (unsigned short)(dh >> 16);
                DOT[(j0 + 1) * 16 + 8 + bb] = (unsigned short)(dl >> 16);
            }
            __syncthreads();
            // B2+upd+F1' (single phase): prefetch stable operands into regs
            // (A-frags KT/HTr/DOT, B-frags DOT/HTr, KgT) so their LDS
            // latency hides under mm64; then dh=do@W2^T; da; the da
            // B-fragment is built via cross-lane SHUFFLE (no DAT LDS
            // round-trip); 3x updW3 (f32 masters); acc1 += (-LR*Kg)@da;
            // gelu (step3 instance IS the final forward h).
            bf16x8 zf8;
#pragma unroll
            for (int j = 0; j < 8; ++j) zf8[j] = 0;
            bf16x8 aK[4], aH[4], aD[4];
#pragma unroll
            for (int mt = 0; mt < 4; ++mt) {
                aK[mt] = *(const bf16x8 *)&KT[(16 * mt + c) * 16 + (q & 1) * 8];
                aH[mt] = *(const bf16x8 *)&HTr[(16 * mt + c) * 16 + (q & 1) * 8];
                aD[mt] = *(const bf16x8 *)&DOT[(16 * mt + c) * 16 + (q & 1) * 8];
            }
            bf16x8 bDO = zf8, bHT = zf8;
            if (q < 2) {
                bDO = *(const bf16x8 *)&DOT[(16 * w + c) * 16];
                bHT = *(const bf16x8 *)&HTr[(16 * w + c) * 16];
            } else if (q == 2) {
                bDO = *(const bf16x8 *)&DOT[(16 * w + c) * 16 + 8];
                bHT = *(const bf16x8 *)&HTr[(16 * w + c) * 16 + 8];
            }
            bf16x8 aKg = *(const bf16x8 *)&KgT[c * 16 + (q & 1) * 8];
            acc = mm64(DOp, W2R, w, c, q);
            {
                float b1sum = 0.f;
                uint2 th; th.x = 0u; th.y = 0u;
                uint2 tl; tl.x = 0u; tl.y = 0u;
                if (q < 2) {
                    float da0 = acc[0] * gd_r[0];
                    float da1 = acc[1] * gd_r[1];
                    float da2 = acc[2] * gd_r[2];
                    float da3 = acc[3] * gd_r[3];
                    b1sum = da0 + da1 + da2 + da3;
                    unsigned h01, l01, h23, l23;
                    cvt2(da0, da1, h01, l01);
                    cvt2(da2, da3, h23, l23);
                    th.x = h01; th.y = h23;
                    tl.x = l01; tl.y = l23;
                }
                b1sum += __shfl_xor(b1sum, 16);
                // bDA frag via shuffle: rows 0-3 from lane (c,0), rows 4-7
                // from lane (c,1). q<2 lanes need hi words, q==2 lo words.
                unsigned hx0 = (unsigned)__shfl((int)th.x, c);
                unsigned hy0 = (unsigned)__shfl((int)th.y, c);
                unsigned hx1 = (unsigned)__shfl((int)th.x, c + 16);
                unsigned hy1 = (unsigned)__shfl((int)th.y, c + 16);
                unsigned lx0 = (unsigned)__shfl((int)tl.x, c);
                unsigned ly0 = (unsigned)__shfl((int)tl.y, c);
                unsigned lx1 = (unsigned)__shfl((int)tl.x, c + 16);
                unsigned ly1 = (unsigned)__shfl((int)tl.y, c + 16);
                u32x4 Bw = {0u, 0u, 0u, 0u};
                if (q < 2) {
                    Bw[0] = hx0; Bw[1] = hy0; Bw[2] = hx1; Bw[3] = hy1;
                } else if (q == 2) {
                    Bw[0] = lx0; Bw[1] = ly0; Bw[2] = lx1; Bw[3] = ly1;
                }
                bf16x8 bDA = __builtin_bit_cast(bf16x8, Bw);
                updW3(aK, bDA, w1m, W1T, w, c, q);
                updW3(aH, bDO, w2m, W2T, w, c, q);
                updW3(aD, bHT, w2rm, W2R, w, c, q);
                if (w == 2) {
                    bf16x8 oh_ = *(const bf16x8 *)&DOT[lane * 16];
                    bf16x8 ol_ = *(const bf16x8 *)&DOT[lane * 16 + 8];
                    float db2 = 0.f;
#pragma unroll
                    for (int j = 0; j < 8; ++j)
                        db2 += bf2f(oh_[j]) + bf2f(ol_[j]);
                    b2_s[lane] -= LR * db2;
                } else if (w == 3) {
                    float dlb = 0.f, dlg = 0.f;
#pragma unroll
                    for (int b = 0; b < 8; ++b) {
                        float dzv = o_s[b * 68 + lane];
                        dlb += dzv;
                        dlg += dzv * xh_s[b * 68 + lane];
                    }
                    lb_s[lane] -= LR * dlb;
                    lg_s[lane] -= LR * dlg;
                }
                // F1': incremental pre-activation + activation for next step
                acc1 = MFMA16(aKg, bDA, acc1);
                b1_r -= LR * b1sum;
                if (q < 2) {
                    int col = 16 * w + c;
                    if (step < 3) {
                        float gv[4];
#pragma unroll
                        for (int r = 0; r < 4; ++r) {
                            float g, dg;
                            gelu_both(acc1[r] + b1_r, g, dg);
                            gv[r] = g;
                            gd_r[r] = dg;
                        }
                        unsigned h01, l01, h23, l23;
                        cvt2(gv[0], gv[1], h01, l01);
                        cvt2(gv[2], gv[3], h23, l23);
                        Hp[(4 * q + 0) * 136 + col] = (unsigned short)h01;
                        Hp[(4 * q + 1) * 136 + col] = (unsigned short)(h01 >> 16);
                        Hp[(4 * q + 2) * 136 + col] = (unsigned short)h23;
                        Hp[(4 * q + 3) * 136 + col] = (unsigned short)(h23 >> 16);
                        Hp[(4 * q + 0) * 136 + 64 + col] = (unsigned short)l01;
                        Hp[(4 * q + 1) * 136 + 64 + col] = (unsigned short)(l01 >> 16);
                        Hp[(4 * q + 2) * 136 + 64 + col] = (unsigned short)l23;
                        Hp[(4 * q + 3) * 136 + 64 + col] = (unsigned short)(l23 >> 16);
                        uint2 hh, hl;
                        hh.x = h01; hh.y = h23;
                        hl.x = l01; hl.y = l23;
                        *(uint2 *)&HTw[col * 16 + 4 * q] = hh;
                        *(uint2 *)&HTw[col * 16 + 8 + 4 * q] = hl;
                    } else {
                        // final forward h (feeds F2fin); no HT/gd needed
                        float gv[4];
#pragma unroll
                        for (int r = 0; r < 4; ++r)
                            gv[r] = gelu_f(acc1[r] + b1_r);
                        unsigned h01, l01, h23, l23;
                        cvt2(gv[0], gv[1], h01, l01);
                        cvt2(gv[2], gv[3], h23, l23);
                        Hp[(4 * q + 0) * 136 + col] = (unsigned short)h01;
                        Hp[(4 * q + 1) * 136 + col] = (unsigned short)(h01 >> 16);
                        Hp[(4 * q + 2) * 136 + col] = (unsigned short)h23;
                        Hp[(4 * q + 3) * 136 + col] = (unsigned short)(h23 >> 16);
                        Hp[(4 * q + 0) * 136 + 64 + col] = (unsigned short)l01;
                        Hp[(4 * q + 1) * 136 + 64 + col] = (unsigned short)(l01 >> 16);
                        Hp[(4 * q + 2) * 136 + 64 + col] = (unsigned short)l23;
                        Hp[(4 * q + 3) * 136 + 64 + col] = (unsigned short)(l23 >> 16);
                    }
                }
            }
            __syncthreads();
        }

        // ---- F2fin: o = h_final@W2 + b2 ; stage token t+1 (Kp/KT/TGp)
        f32x4 acc = mm64(Hp, W2T, w, c, q);
        if (q < 2) {
            float bias = b2_s[16 * w + c];
#pragma unroll
            for (int r = 0; r < 4; ++r)
                o_s[(4 * q + r) * 68 + 16 * w + c] = acc[r] + bias;
        }
        if (t + 1 < Sv) {
            unsigned khw, klw;
            cvt2(pk.x, pk.y, khw, klw);
            *(unsigned *)&Kp[bb * 136 + j0] = khw;
            *(unsigned *)&Kp[bb * 136 + 64 + j0] = klw;
            KT[j0 * 16 + bb] = (unsigned short)khw;
            KT[j0 * 16 + 8 + bb] = (unsigned short)klw;
            KT[(j0 + 1) * 16 + bb] = (unsigned short)(khw >> 16);
            KT[(j0 + 1) * 16 + 8 + bb] = (unsigned short)(klw >> 16);
            unsigned thw, tlw;
            cvt2(pv.x - pk.x, pv.y - pk.y, thw, tlw);
            *(unsigned *)&TGp[bb * 136 + j0] = thw;
            *(unsigned *)&TGp[bb * 136 + 64 + j0] = tlw;
        }
        __syncthreads();
        // epilogue: LN(lg,lb) -> LN(ttt_g,ttt_b) -> out = q + z2
        // (single-pass variance; no trailing barrier: F1o's end-barrier
        // orders the o_s reuse)
        {
            float2 xv = *(const float2 *)&o_s[bb * 68 + j0];
            float s = red32(xv.x + xv.y);
            float s2 = red32(xv.x * xv.x + xv.y * xv.y);
            float mu = s * (1.f / 64.f);
            float var = s2 * (1.f / 64.f) - mu * mu;
            float rs = rsqrtf(var + 1e-5f);
            float z0 = (xv.x - mu) * rs * lg_s[j0] + lb_s[j0];
            float z1 = (xv.y - mu) * rs * lg_s[j0 + 1] + lb_s[j0 + 1];
            float sb = red32(z0 + z1);
            float s2b = red32(z0 * z0 + z1 * z1);
            float mu2 = sb * (1.f / 64.f);
            float var2 = s2b * (1.f / 64.f) - mu2 * mu2;
            float rs2 = rsqrtf(var2 + 1e-5f);
            float z20 = (z0 - mu2) * rs2 * tG_s[j0] + tB_s[j0];
            float z21 = (z1 - mu2) * rs2 * tG_s[j0 + 1] + tB_s[j0 + 1];
            int idx = ((bb * Sv + t) * Hv + h) * Dv + j0;
            float2 ov;
            ov.x = q_cur.x + z20;
            ov.y = q_cur.y + z21;
            *(float2 *)&out_g[idx] = ov;
            q_cur = pq;
        }
    }
}

// ---------------------------------------------------------------------------
// bf16 hi/lo MFMA GEMM: C[M,N] = A[M,K] @ B[K,N]; mode 1: gelu(acc)*gate_ln
// 3-term split product (hh + lh + hl), same precision policy as the scan.
// 64x64 tile / block (4 waves), K staged in 64-chunks, hi/lo bf16 in LDS.
// Fragment conventions identical to the scan's proven mm64.
// ---------------------------------------------------------------------------
__global__ __launch_bounds__(256) void gemm_bf16(
    const float *__restrict__ A, const float *__restrict__ B,
    float *__restrict__ C, const float *__restrict__ gate_ln,
    int M, int N, int K, int mode) {
    __shared__ unsigned short As[64 * 136];   // [m][k hi 0-63 | lo 64-127]
    __shared__ unsigned short Bs[64 * 136];   // [n][k hi 0-63 | lo 64-127]
    const int tid = threadIdx.x;
    const int w = tid >> 6, lane = tid & 63, c = lane & 15, q = lane >> 4;
    const int bm = blockIdx.y * 64, bn = blockIdx.x * 64;

    f32x4 acc[4] = {{0.f, 0.f, 0.f, 0.f}, {0.f, 0.f, 0.f, 0.f},
                    {0.f, 0.f, 0.f, 0.f}, {0.f, 0.f, 0.f, 0.f}};
    const int srow = tid >> 2, sseg = (tid & 3) * 16;

    for (int k0 = 0; k0 < K; k0 += 64) {
        // stage A 64x64 (row-major m, k hi/lo)
        {
            const float *src = A + (long)(bm + srow) * K + k0 + sseg;
#pragma unroll
            for (int j = 0; j < 16; j += 2) {
                float2 v = *(const float2 *)(src + j);
                unsigned hw, lw;
                cvt2(v.x, v.y, hw, lw);
                *(unsigned *)&As[srow * 136 + sseg + j] = hw;
                *(unsigned *)&As[srow * 136 + 64 + sseg + j] = lw;
            }
        }
        // stage B 64(k)x64(n), transposed to n-major
        {
            const float *bsrc = B + (long)(k0 + srow) * N + bn + sseg;
#pragma unroll
            for (int j = 0; j < 16; j += 4) {
                float4 v = *(const float4 *)(bsrc + j);
                short hi, lo;
                cvt1(v.x, hi, lo);
                Bs[(sseg + j + 0) * 136 + srow] = (unsigned short)hi;
                Bs[(sseg + j + 0) * 136 + 64 + srow] = (unsigned short)lo;
                cvt1(v.y, hi, lo);
                Bs[(sseg + j + 1) * 136 + srow] = (unsigned short)hi;
                Bs[(sseg + j + 1) * 136 + 64 + srow] = (unsigned short)lo;
                cvt1(v.z, hi, lo);
                Bs[(sseg + j + 2) * 136 + srow] = (unsigned short)hi;
                Bs[(sseg + j + 2) * 136 + 64 + srow] = (unsigned short)lo;
                cvt1(v.w, hi, lo);
                Bs[(sseg + j + 3) * 136 + srow] = (unsigned short)hi;
                Bs[(sseg + j + 3) * 136 + 64 + srow] = (unsigned short)lo;
            }
        }
        __syncthreads();
#pragma unroll
        for (int kc = 0; kc < 2; ++kc) {
            const unsigned short *br =
                &Bs[(16 * w + c) * 136 + kc * 32 + 8 * q];
            bf16x8 bh = *(const bf16x8 *)(br);
            bf16x8 bl = *(const bf16x8 *)(br + 64);
#pragma unroll
            for (int mt = 0; mt < 4; ++mt) {
                const unsigned short *ar =
                    &As[(16 * mt + c) * 136 + kc * 32 + 8 * q];
                bf16x8 ah = *(const bf16x8 *)(ar);
                bf16x8 al = *(const bf16x8 *)(ar + 64);
                acc[mt] = MFMA16(ah, bh, acc[mt]);
                acc[mt] = MFMA16(al, bh, acc[mt]);
                acc[mt] = MFMA16(ah, bl, acc[mt]);
            }
        }
        __syncthreads();
    }
#pragma unroll
    for (int mt = 0; mt < 4; ++mt) {
#pragma unroll
        for (int r = 0; r < 4; ++r) {
            int row = bm + 16 * mt + 4 * q + r;
            int col = bn + 16 * w + c;
            float val = acc[mt][r];
            if (mode == 1)
                val = gelu_f(val) * gate_ln[(long)row * N + col];
            C[(long)row * N + col] = val;
        }
    }
}

// ---------------------------------------------------------------------------
// Row LayerNorm over 1024 (post-scan, pn_g / pn_b)
// ---------------------------------------------------------------------------
__global__ __launch_bounds__(256) void row_ln(const float *__restrict__ in,
                                              float *__restrict__ out,
                                              const float *__restrict__ g,
                                              const float *__restrict__ b) {
    __shared__ float sred[4], s2red[4];
    const int row = blockIdx.x;
    const int tid = threadIdx.x;
    const float *x = in + (long)row * 1024;
    float4 v = *(const float4 *)(x + tid * 4);
    float s = v.x + v.y + v.z + v.w;
    float s2 = v.x * v.x + v.y * v.y + v.z * v.z + v.w * v.w;
#pragma unroll
    for (int m = 1; m <= 32; m <<= 1) {
        s += __shfl_xor(s, m);
        s2 += __shfl_xor(s2, m);
    }
    if ((tid & 63) == 0) {
        sred[tid >> 6] = s;
        s2red[tid >> 6] = s2;
    }
    __syncthreads();
    float S = sred[0] + sred[1] + sred[2] + sred[3];
    float S2 = s2red[0] + s2red[1] + s2red[2] + s2red[3];
    float mu = S * (1.f / 1024.f);
    float var = S2 * (1.f / 1024.f) - mu * mu;
    float rs = rsqrtf(var + 1e-5f);
    float o[4] = {v.x, v.y, v.z, v.w};
    float4 ov;
    float r[4];
#pragma unroll
    for (int i = 0; i < 4; ++i) {
        int col = tid * 4 + i;
        r[i] = (o[i] - mu) * rs * g[col] + b[col];
    }
    ov.x = r[0]; ov.y = r[1]; ov.z = r[2]; ov.w = r[3];
    *(float4 *)(out + (long)row * 1024 + tid * 4) = ov;
}

// ---------------------------------------------------------------------------
// Launch
// ---------------------------------------------------------------------------
extern "C" void kernel_launch(void *const *d_in, const int *in_sizes, int n_in,
                              void *d_out, int out_size, void *d_ws,
                              size_t ws_size, hipStream_t stream) {
    const float *x = (const float *)d_in[0];
    const float *wq = (const float *)d_in[1];
    const float *wk = (const float *)d_in[2];
    const float *wv = (const float *)d_in[3];
    const float *fw_w1 = (const float *)d_in[4];
    const float *fw_b1 = (const float *)d_in[5];
    const float *fw_w2 = (const float *)d_in[6];
    const float *fw_b2 = (const float *)d_in[7];
    const float *fw_lng = (const float *)d_in[8];
    const float *fw_lnb = (const float *)d_in[9];
    const float *loss_w = (const float *)d_in[10];
    const float *loss_b = (const float *)d_in[11];
    const float *ttt_g = (const float *)d_in[12];
    const float *ttt_b = (const float *)d_in[13];
    const float *wo = (const float *)d_in[14];
    const float *wg = (const float *)d_in[15];
    const float *pn_g = (const float *)d_in[16];
    const float *pn_b = (const float *)d_in[17];

    const long MAT = 2048L * 1024L;
    float *q_ws = (float *)d_ws;
    float *k_ws = q_ws + MAT;
    float *v_ws = k_ws + MAT;
    float *out_ws = v_ws + MAT;
    float *ln_ws = k_ws;       // reuse (k dead after scan)
    float *gated_ws = v_ws;    // reuse (v dead after scan)

    dim3 gg(1024 / 64, 2048 / 64), bt(256);
    hipLaunchKernelGGL(gemm_bf16, gg, bt, 0, stream, x, wq, q_ws,
                       (const float *)nullptr, 2048, 1024, 1024, 0);
    hipLaunchKernelGGL(gemm_bf16, gg, bt, 0, stream, x, wk, k_ws,
                       (const float *)nullptr, 2048, 1024, 1024, 0);
    hipLaunchKernelGGL(gemm_bf16, gg, bt, 0, stream, x, wv, v_ws,
                       (const float *)nullptr, 2048, 1024, 1024, 0);

    (void)hipFuncSetAttribute((const void *)ttt_scan,
                              hipFuncAttributeMaxDynamicSharedMemorySize,
                              LDS_BYTES);
    hipLaunchKernelGGL(ttt_scan, dim3(16), dim3(256), LDS_BYTES, stream,
                       q_ws, k_ws, v_ws, out_ws, fw_w1, fw_b1, fw_w2, fw_b2,
                       fw_lng, fw_lnb, loss_w, loss_b, ttt_g, ttt_b);

    hipLaunchKernelGGL(row_ln, dim3(2048), dim3(256), 0, stream, out_ws, ln_ws,
                       pn_g, pn_b);
    hipLaunchKernelGGL(gemm_bf16, gg, bt, 0, stream, x, wg, gated_ws, ln_ws,
                       2048, 1024, 1024, 1);
    hipLaunchKernelGGL(gemm_bf16, gg, bt, 0, stream, gated_ws, wo,
                       (float *)d_out, (const float *)nullptr, 2048, 1024,
                       1024, 0);
}

// Round 12
// 3701.525 us; speedup vs baseline: 1.2195x; 1.0159x over previous
//
#include <hip/hip_runtime.h>

// ---------------------------------------------------------------------------
// Problem constants
// ---------------------------------------------------------------------------
#define Bv 8
#define Sv 256
#define Hv 16
#define Dv 64
#define LR 0.1f
#define SCALE (2.0f / 8192.0f)   // dLoss/dpred scale: 2/(B*H*D)

using bf16x8 = __attribute__((ext_vector_type(8))) short;
using bf16x4 = __attribute__((ext_vector_type(4))) short;
using f32x4  = __attribute__((ext_vector_type(4))) float;
using u32x4  = __attribute__((ext_vector_type(4))) unsigned;
#define MFMA16(A, B, C) __builtin_amdgcn_mfma_f32_16x16x32_bf16(A, B, C, 0, 0, 0)

// ---------------------------------------------------------------------------
// LDS layout (ushort units for bf16 planes, float units for fp32 areas)
// Weight/row planes: pitch 136 ushort = 272 B (hi[64] | lo[64] | pad[8]).
// T arrays: pitch 16 ushort = 32 B (hi[8] | lo[8]).
// ---------------------------------------------------------------------------
constexpr int U_W1T = 0;          // [f][d] planes, 64x136
constexpr int U_W2T = 8704;      // [d][f]
constexpr int U_W2R = 17408;     // [f][d]
constexpr int U_G   = 26112;     // [d][d']  (symmetric, static)
constexpr int U_LwR = 34816;     // [d][e]   (static)
constexpr int U_K   = 43520;     // [b pad16][d] 16x136
constexpr int U_H   = 45696;     // [b][f]
constexpr int U_Z   = 47872;     // [b][d]
constexpr int U_TG  = 50048;     // [b pad16][e] target planes
constexpr int U_DO  = 52224;     // [b][d]
constexpr int U_KT  = 54400;     // [d][b] 64x16
constexpr int U_HT  = 55424;     // [f][b]  (buffer 0)
constexpr int U_DOT = 56448;     // [d][b]
constexpr int U_DAT = 57472;     // (unused now - DAT lives in registers/shfl)
constexpr int F_BASE = 29248;    // = 58496/2
constexpr int F_O   = F_BASE;        // o / dz shared, [8][68]
constexpr int F_XH  = F_BASE + 544;
constexpr int F_GD  = F_XH + 544;    // (unused)
constexpr int F_TGL = F_GD + 544;    // (unused)
constexpr int F_B1  = F_TGL + 544;   // (unused)
constexpr int F_B2  = F_B1 + 64;
constexpr int F_LG  = F_B2 + 64;
constexpr int F_LB  = F_LG + 64;
constexpr int F_C1  = F_LB + 64;     // Lb @ Lw^T (static)
constexpr int F_TGm = F_C1 + 64;
constexpr int F_TBm = F_TGm + 64;
constexpr int F_RSTD = F_TBm + 64;
constexpr int U_KG  = (F_RSTD + 8) * 2;   // -LR*K*K^T, [16][hi8|lo8]
constexpr int U_HT2 = U_KG + 256;         // HT buffer 1
constexpr int LDS_BYTES = (U_HT2 + 1024) * 2;   // 130080 B

// ---------------------------------------------------------------------------
// Helpers
// ---------------------------------------------------------------------------
__device__ __forceinline__ short bf_rn(float v) {
    unsigned u = __float_as_uint(v);
    unsigned r = u + 0x7fffu + ((u >> 16) & 1u);   // round-to-nearest-even
    return (short)(r >> 16);
}
__device__ __forceinline__ void cvt1(float v, short &hi, short &lo) {
    hi = bf_rn(v);
    float hf = __uint_as_float(((unsigned)(unsigned short)hi) << 16);
    lo = bf_rn(v - hf);
}
__device__ __forceinline__ float bf2f(short u) {
    return __uint_as_float(((unsigned)(unsigned short)u) << 16);
}
// Packed bf16 pair conversion: 1 instruction converts 2 floats (RTNE).
__device__ __forceinline__ unsigned cvtpk(float a, float b) {
    unsigned r;
    asm("v_cvt_pk_bf16_f32 %0, %1, %2" : "=v"(r) : "v"(a), "v"(b));
    return r;                      // lo16 = bf16(a), hi16 = bf16(b)
}
// hi/lo split of a float pair: hw = packed hi-bf16s, lw = packed lo-bf16s.
__device__ __forceinline__ void cvt2(float a, float b, unsigned &hw,
                                     unsigned &lw) {
    hw = cvtpk(a, b);
    float ra = a - __uint_as_float(hw << 16);
    float rb = b - __uint_as_float(hw & 0xffff0000u);
    lw = cvtpk(ra, rb);
}
// DPP-based 32-lane sum.
template <int CTRL>
__device__ __forceinline__ float dpp_add(float v) {
    int s = __builtin_amdgcn_update_dpp(0, __float_as_int(v), CTRL, 0xF, 0xF,
                                        true);
    return v + __int_as_float(s);
}
__device__ __forceinline__ float red32(float v) {
    v = dpp_add<0xB1>(v);    // quad_perm [1,0,3,2]  (xor 1)
    v = dpp_add<0x4E>(v);    // quad_perm [2,3,0,1]  (xor 2)
    v = dpp_add<0x124>(v);   // row_ror:4
    v = dpp_add<0x128>(v);   // row_ror:8
    v += __shfl_xor(v, 16);  // merge the two 16-rows of the 32-group
    return v;
}
__device__ __forceinline__ float fast_tanh(float u) {
    u = fminf(fmaxf(u, -10.f), 10.f);
    float e = __expf(2.0f * u);
    return (e - 1.0f) / (e + 1.0f);
}
__device__ __forceinline__ void gelu_both(float x, float &g, float &dg) {
    const float C0 = 0.7978845608028654f, A0 = 0.044715f;
    float x2 = x * x;
    float u = C0 * x * (1.0f + A0 * x2);
    float t = fast_tanh(u);
    g = 0.5f * x * (1.0f + t);
    float du = C0 * (1.0f + 3.0f * A0 * x2);
    dg = 0.5f * (1.0f + t) + 0.5f * x * (1.0f - t * t) * du;
}
__device__ __forceinline__ float gelu_f(float x) {
    const float C0 = 0.7978845608028654f, A0 = 0.044715f;
    float u = C0 * x * (1.0f + A0 * x * x);
    return 0.5f * x * (1.0f + fast_tanh(u));
}

// C[16x16 tile w] = A(16x64, row planes) @ B(64x64 via n-major planes)
// 3-term split product (hh + lh + hl; the ll term is ~2^-17 relative and
// dropped — same packing precedent as updW since round 2).
__device__ __forceinline__ f32x4 mm64(const unsigned short *Ap,
                                      const unsigned short *Bp,
                                      int w, int c, int q) {
    const unsigned short *ar = Ap + c * 136 + 8 * q;
    const unsigned short *br = Bp + (16 * w + c) * 136 + 8 * q;
    bf16x8 ah0 = *(const bf16x8 *)(ar);
    bf16x8 al0 = *(const bf16x8 *)(ar + 64);
    bf16x8 bh0 = *(const bf16x8 *)(br);
    bf16x8 bl0 = *(const bf16x8 *)(br + 64);
    bf16x8 ah1 = *(const bf16x8 *)(ar + 32);
    bf16x8 al1 = *(const bf16x8 *)(ar + 96);
    bf16x8 bh1 = *(const bf16x8 *)(br + 32);
    bf16x8 bl1 = *(const bf16x8 *)(br + 96);
    f32x4 x0 = {0.f, 0.f, 0.f, 0.f}, x1 = {0.f, 0.f, 0.f, 0.f};
    x0 = MFMA16(ah0, bh0, x0); x1 = MFMA16(ah1, bh1, x1);
    x0 = MFMA16(al0, bh0, x0); x1 = MFMA16(al1, bh1, x1);
    x0 = MFMA16(ah0, bl0, x0); x1 = MFMA16(ah1, bl1, x1);
    return x0 + x1;
}

// W update with f32 master weights in registers (validated in round 7).
// Lane (c,q) owns W elements (row 16w+c, col 16mt+4q+r) == exactly this
// lane's gradient outputs. g = X^T@Y via packed-K MFMA; master -= LR*g;
// planes = cvt2(master). No W-plane reads.
__device__ __forceinline__ void updW3(const bf16x8 *a4, bf16x8 b,
                                      float (&m)[16], unsigned short *WT,
                                      int w, int c, int q) {
    f32x4 g[4];
#pragma unroll
    for (int mt = 0; mt < 4; ++mt) {
        f32x4 z = {0.f, 0.f, 0.f, 0.f};
        g[mt] = MFMA16(a4[mt], b, z);
    }
    unsigned short *p0 = &WT[(16 * w + c) * 136 + 4 * q];
#pragma unroll
    for (int mt = 0; mt < 4; ++mt) {
        m[mt * 4 + 0] -= LR * g[mt][0];
        m[mt * 4 + 1] -= LR * g[mt][1];
        m[mt * 4 + 2] -= LR * g[mt][2];
        m[mt * 4 + 3] -= LR * g[mt][3];
        unsigned nh0, nl0, nh1, nl1;
        cvt2(m[mt * 4 + 0], m[mt * 4 + 1], nh0, nl0);
        cvt2(m[mt * 4 + 2], m[mt * 4 + 3], nh1, nl1);
        uint2 nh, nl;
        nh.x = nh0; nh.y = nh1;
        nl.x = nl0; nl.y = nl1;
        *(uint2 *)(p0 + 16 * mt) = nh;
        *(uint2 *)(p0 + 16 * mt + 64) = nl;
    }
}

// ---------------------------------------------------------------------------
// TTT scan kernel: one block (256 thr = 4 waves) per head
// (byte-identical to round 8 — 3457 us, absmax 0.0039; untouched this round)
// ---------------------------------------------------------------------------
__global__ __launch_bounds__(256) void ttt_scan(
    const float *__restrict__ q_g, const float *__restrict__ k_g,
    const float *__restrict__ v_g, float *__restrict__ out_g,
    const float *__restrict__ fw_w1, const float *__restrict__ fw_b1,
    const float *__restrict__ fw_w2, const float *__restrict__ fw_b2,
    const float *__restrict__ fw_lng, const float *__restrict__ fw_lnb,
    const float *__restrict__ loss_w, const float *__restrict__ loss_bv,
    const float *__restrict__ ttt_gv, const float *__restrict__ ttt_bv) {
    extern __shared__ char smem[];
    unsigned short *us = (unsigned short *)smem;
    float *fs = (float *)smem;

    unsigned short *W1T = us + U_W1T, *W2T = us + U_W2T, *W2R = us + U_W2R;
    unsigned short *Gp = us + U_G, *LwR = us + U_LwR;
    unsigned short *Kp = us + U_K, *Hp = us + U_H, *Zp = us + U_Z;
    unsigned short *TGp = us + U_TG, *DOp = us + U_DO;
    unsigned short *KT = us + U_KT, *HT0 = us + U_HT;
    unsigned short *DOT = us + U_DOT;
    unsigned short *KgT = us + U_KG, *HT1 = us + U_HT2;
    float *o_s = fs + F_O, *xh_s = fs + F_XH;
    float *b2_s = fs + F_B2, *lg_s = fs + F_LG;
    float *lb_s = fs + F_LB, *c1_s = fs + F_C1;
    float *tG_s = fs + F_TGm, *tB_s = fs + F_TBm, *rstd_s = fs + F_RSTD;

    const int h = blockIdx.x, tid = threadIdx.x;
    const int w = tid >> 6, lane = tid & 63, c = lane & 15, q = lane >> 4;
    const int bb = tid >> 5, j0 = (tid & 31) * 2;

    // ---- init: split weights into bf16 hi/lo planes
    for (int i = tid; i < 4096; i += 256) {
        int r = i >> 6, cc = i & 63;
        short hi, lo;
        cvt1(fw_w1[h * 4096 + i], hi, lo);           // [d=r][f=cc]
        W1T[cc * 136 + r] = (unsigned short)hi;
        W1T[cc * 136 + 64 + r] = (unsigned short)lo;
        cvt1(fw_w2[h * 4096 + i], hi, lo);           // [f=r][d=cc]
        W2T[cc * 136 + r] = (unsigned short)hi;
        W2T[cc * 136 + 64 + r] = (unsigned short)lo;
        W2R[r * 136 + cc] = (unsigned short)hi;
        W2R[r * 136 + 64 + cc] = (unsigned short)lo;
        cvt1(loss_w[i], hi, lo);                     // [d=r][e=cc]
        LwR[r * 136 + cc] = (unsigned short)hi;
        LwR[r * 136 + 64 + cc] = (unsigned short)lo;
    }
    // zero pad rows 8..15 of the activation row-plane arrays
    for (int i = tid; i < 5 * 8 * 128; i += 256) {
        int a = i / 128, u = i % 128;
        int arr = a >> 3, row = 8 + (a & 7);
        unsigned short *base = (arr == 0) ? Kp : (arr == 1) ? Hp
                              : (arr == 2) ? Zp : (arr == 3) ? TGp : DOp;
        base[row * 136 + u] = 0;
    }
    // f32 master weights in registers (validated r7): lane (c,q) of wave w
    // owns elements (plane-row 16w+c, plane-col 16mt+4q+r) of the 3 planes.
    float w1m[16], w2m[16], w2rm[16];
#pragma unroll
    for (int mt = 0; mt < 4; ++mt) {
#pragma unroll
        for (int r = 0; r < 4; ++r) {
            int el = 16 * mt + 4 * q + r;
            int row = 16 * w + c;
            w1m[mt * 4 + r] = fw_w1[h * 4096 + el * 64 + row];
            w2m[mt * 4 + r] = fw_w2[h * 4096 + el * 64 + row];
            w2rm[mt * 4 + r] = fw_w2[h * 4096 + row * 64 + el];
        }
    }
    __syncthreads();
    // G = Lw @ Lw^T (static; fuses F3+B1 into one phase per step)
#pragma unroll 1
    for (int mt = 0; mt < 4; ++mt) {
        f32x4 g = mm64(LwR + 16 * 136 * mt, LwR, w, c, q);
#pragma unroll
        for (int r = 0; r < 4; ++r) {
            short hi, lo;
            cvt1(g[r], hi, lo);
            int dr = 16 * mt + 4 * q + r, dc = 16 * w + c;
            Gp[dr * 136 + dc] = (unsigned short)hi;
            Gp[dr * 136 + 64 + dc] = (unsigned short)lo;
        }
    }
    if (tid < 64) {
        b2_s[tid] = fw_b2[h * 64 + tid];
        lg_s[tid] = fw_lng[h * 64 + tid];
        lb_s[tid] = fw_lnb[h * 64 + tid];
        tG_s[tid] = ttt_gv[h * 64 + tid];
        tB_s[tid] = ttt_bv[h * 64 + tid];
        float c1 = 0.f;                      // c1[d] = sum_e Lb[e]*Lw[d,e]
        for (int e = 0; e < 64; ++e) c1 += loss_bv[e] * loss_w[tid * 64 + e];
        c1_s[tid] = c1;
    }

    // ---- stage token 0 (Kp/KT/TGp) and hold q(0) in registers
    float2 pk, pv, pq, q_cur;
    {
        int idx = ((bb * Sv + 0) * Hv + h) * Dv + j0;
        float2 k0 = *(const float2 *)&k_g[idx];
        float2 v0 = *(const float2 *)&v_g[idx];
        q_cur = *(const float2 *)&q_g[idx];
        unsigned khw, klw;
        cvt2(k0.x, k0.y, khw, klw);
        *(unsigned *)&Kp[bb * 136 + j0] = khw;
        *(unsigned *)&Kp[bb * 136 + 64 + j0] = klw;
        KT[j0 * 16 + bb] = (unsigned short)khw;
        KT[j0 * 16 + 8 + bb] = (unsigned short)klw;
        KT[(j0 + 1) * 16 + bb] = (unsigned short)(khw >> 16);
        KT[(j0 + 1) * 16 + 8 + bb] = (unsigned short)(klw >> 16);
        unsigned thw, tlw;
        cvt2(v0.x - k0.x, v0.y - k0.y, thw, tlw);
        *(unsigned *)&TGp[bb * 136 + j0] = thw;
        *(unsigned *)&TGp[bb * 136 + 64 + j0] = tlw;
    }
    // register-carried params (per lane, q<2 lanes meaningful)
    float b1_r = (q < 2) ? fw_b1[h * 64 + 16 * w + c] : 0.f;
    __syncthreads();
    float c1_r = c1_s[16 * w + c];
    f32x4 gd_r = {0.f, 0.f, 0.f, 0.f};
    f32x4 tgl_r = {0.f, 0.f, 0.f, 0.f};

#pragma unroll 1
    for (int t = 0; t < Sv; ++t) {
        // issue prefetch for token t+1 (consumed at F2fin staging / epilogue)
        if (t + 1 < Sv) {
            int idx2 = ((bb * Sv + t + 1) * Hv + h) * Dv + j0;
            pk = *(const float2 *)&k_g[idx2];
            pv = *(const float2 *)&v_g[idx2];
            pq = *(const float2 *)&q_g[idx2];
        }

        // ---- F1o: acc1 = k@W1 (kept in regs all token); tgl_r; Kg; gelu
        f32x4 acc1 = mm64(Kp, W1T, w, c, q);
        {
            f32x4 a2 = mm64(TGp, LwR, w, c, q);
            if (q < 2) {
#pragma unroll
                for (int r = 0; r < 4; ++r) tgl_r[r] = a2[r] - c1_r;
            }
        }
        if (w == 0) {
            // Kg = K@K^T (rows/cols >=8 are zero via Kp padding); store -LR*Kg
            f32x4 kg = mm64(Kp, Kp, 0, c, q);
            if (q < 2) {
#pragma unroll
                for (int r = 0; r < 4; ++r) {
                    short hi, lo;
                    cvt1(-LR * kg[r], hi, lo);
                    KgT[c * 16 + 4 * q + r] = (unsigned short)hi;
                    KgT[c * 16 + 8 + 4 * q + r] = (unsigned short)lo;
                }
            }
        }
        if (q < 2) {
            int col = 16 * w + c;
            float gv[4];
#pragma unroll
            for (int r = 0; r < 4; ++r) {
                float g, dg;
                gelu_both(acc1[r] + b1_r, g, dg);
                gv[r] = g;
                gd_r[r] = dg;
            }
            unsigned h01, l01, h23, l23;
            cvt2(gv[0], gv[1], h01, l01);
            cvt2(gv[2], gv[3], h23, l23);
            Hp[(4 * q + 0) * 136 + col] = (unsigned short)h01;
            Hp[(4 * q + 1) * 136 + col] = (unsigned short)(h01 >> 16);
            Hp[(4 * q + 2) * 136 + col] = (unsigned short)h23;
            Hp[(4 * q + 3) * 136 + col] = (unsigned short)(h23 >> 16);
            Hp[(4 * q + 0) * 136 + 64 + col] = (unsigned short)l01;
            Hp[(4 * q + 1) * 136 + 64 + col] = (unsigned short)(l01 >> 16);
            Hp[(4 * q + 2) * 136 + 64 + col] = (unsigned short)l23;
            Hp[(4 * q + 3) * 136 + 64 + col] = (unsigned short)(l23 >> 16);
            uint2 hh, hl;
            hh.x = h01; hh.y = h23;
            hl.x = l01; hl.y = l23;
            *(uint2 *)&HT0[col * 16 + 4 * q] = hh;
            *(uint2 *)&HT0[col * 16 + 8 + 4 * q] = hl;
        }
        __syncthreads();

#pragma unroll 1
        for (int step = 0; step < 4; ++step) {
            const unsigned short *HTr = (step & 1) ? HT1 : HT0;
            unsigned short *HTw = (step & 1) ? HT0 : HT1;
            // F2: o = h@W2 + b2
            f32x4 acc = mm64(Hp, W2T, w, c, q);
            if (q < 2) {
                float bias = b2_s[16 * w + c];
#pragma unroll
                for (int r = 0; r < 4; ++r)
                    o_s[(4 * q + r) * 68 + 16 * w + c] = acc[r] + bias;
            }
            __syncthreads();
            // LN fwd (thread-mapped, single-pass: independent S, S2 chains)
            float xh0_r, xh1_r;
            {
                float2 xv = *(const float2 *)&o_s[bb * 68 + j0];
                float s = red32(xv.x + xv.y);
                float s2 = red32(xv.x * xv.x + xv.y * xv.y);
                float mu = s * (1.f / 64.f);
                float var = s2 * (1.f / 64.f) - mu * mu;
                float rs = rsqrtf(var + 1e-5f);
                float xh0 = (xv.x - mu) * rs, xh1 = (xv.y - mu) * rs;
                float2 xw; xw.x = xh0; xw.y = xh1;
                *(float2 *)&xh_s[bb * 68 + j0] = xw;
                float z0 = xh0 * lg_s[j0] + lb_s[j0];
                float z1 = xh1 * lg_s[j0 + 1] + lb_s[j0 + 1];
                unsigned zh, zl;
                cvt2(z0, z1, zh, zl);
                *(unsigned *)&Zp[bb * 136 + j0] = zh;
                *(unsigned *)&Zp[bb * 136 + 64 + j0] = zl;
                if ((tid & 31) == 0) rstd_s[bb] = rs;
                xh0_r = xh0; xh1_r = xh1;
            }
            __syncthreads();
            // B1' (fused F3+B1): dz = SCALE * (z@G - tgl_r)
            acc = mm64(Zp, Gp, w, c, q);
            if (q < 2) {
                int col = 16 * w + c;
#pragma unroll
                for (int r = 0; r < 4; ++r)
                    o_s[(4 * q + r) * 68 + col] = (acc[r] - tgl_r[r]) * SCALE;
            }
            __syncthreads();
            // LN bwd (thread-mapped) -> do planes + doT
            {
                float2 dzv = *(const float2 *)&o_s[bb * 68 + j0];
                float dxh0 = dzv.x * lg_s[j0], dxh1 = dzv.y * lg_s[j0 + 1];
                float S1 = red32(dxh0 + dxh1) * (1.f / 64.f);
                float S2 = red32(dxh0 * xh0_r + dxh1 * xh1_r) * (1.f / 64.f);
                float rs = rstd_s[bb];
                float do0 = rs * (dxh0 - S1 - xh0_r * S2);
                float do1 = rs * (dxh1 - S1 - xh1_r * S2);
                unsigned dh, dl;
                cvt2(do0, do1, dh, dl);
                *(unsigned *)&DOp[bb * 136 + j0] = dh;
                *(unsigned *)&DOp[bb * 136 + 64 + j0] = dl;
                DOT[j0 * 16 + bb] = (unsigned short)dh;
                DOT[j0 * 16 + 8 + bb] = (unsigned short)dl;
                DOT[(j0 + 1) * 16 + bb] = (unsigned short)(dh >> 16);
                DOT[(j0 + 1) * 16 + 8 + bb] = (unsigned short)(dl >> 16);
            }
            __syncthreads();
            // B2+upd+F1' (single phase): prefetch stable operands into regs
            // (A-frags KT/HTr/DOT, B-frags DOT/HTr, KgT) so their LDS
            // latency hides under mm64; then dh=do@W2^T; da; the da
            // B-fragment is built via cross-lane SHUFFLE (no DAT LDS
            // round-trip); 3x updW3 (f32 masters); acc1 += (-LR*Kg)@da;
            // gelu (step3 instance IS the final forward h).
            bf16x8 zf8;
#pragma unroll
            for (int j = 0; j < 8; ++j) zf8[j] = 0;
            bf16x8 aK[4], aH[4], aD[4];
#pragma unroll
            for (int mt = 0; mt < 4; ++mt) {
                aK[mt] = *(const bf16x8 *)&KT[(16 * mt + c) * 16 + (q & 1) * 8];
                aH[mt] = *(const bf16x8 *)&HTr[(16 * mt + c) * 16 + (q & 1) * 8];
                aD[mt] = *(const bf16x8 *)&DOT[(16 * mt + c) * 16 + (q & 1) * 8];
            }
            bf16x8 bDO = zf8, bHT = zf8;
            if (q < 2) {
                bDO = *(const bf16x8 *)&DOT[(16 * w + c) * 16];
                bHT = *(const bf16x8 *)&HTr[(16 * w + c) * 16];
            } else if (q == 2) {
                bDO = *(const bf16x8 *)&DOT[(16 * w + c) * 16 + 8];
                bHT = *(const bf16x8 *)&HTr[(16 * w + c) * 16 + 8];
            }
            bf16x8 aKg = *(const bf16x8 *)&KgT[c * 16 + (q & 1) * 8];
            acc = mm64(DOp, W2R, w, c, q);
            {
                float b1sum = 0.f;
                uint2 th; th.x = 0u; th.y = 0u;
                uint2 tl; tl.x = 0u; tl.y = 0u;
                if (q < 2) {
                    float da0 = acc[0] * gd_r[0];
                    float da1 = acc[1] * gd_r[1];
                    float da2 = acc[2] * gd_r[2];
                    float da3 = acc[3] * gd_r[3];
                    b1sum = da0 + da1 + da2 + da3;
                    unsigned h01, l01, h23, l23;
                    cvt2(da0, da1, h01, l01);
                    cvt2(da2, da3, h23, l23);
                    th.x = h01; th.y = h23;
                    tl.x = l01; tl.y = l23;
                }
                b1sum += __shfl_xor(b1sum, 16);
                // bDA frag via shuffle: rows 0-3 from lane (c,0), rows 4-7
                // from lane (c,1). q<2 lanes need hi words, q==2 lo words.
                unsigned hx0 = (unsigned)__shfl((int)th.x, c);
                unsigned hy0 = (unsigned)__shfl((int)th.y, c);
                unsigned hx1 = (unsigned)__shfl((int)th.x, c + 16);
                unsigned hy1 = (unsigned)__shfl((int)th.y, c + 16);
                unsigned lx0 = (unsigned)__shfl((int)tl.x, c);
                unsigned ly0 = (unsigned)__shfl((int)tl.y, c);
                unsigned lx1 = (unsigned)__shfl((int)tl.x, c + 16);
                unsigned ly1 = (unsigned)__shfl((int)tl.y, c + 16);
                u32x4 Bw = {0u, 0u, 0u, 0u};
                if (q < 2) {
                    Bw[0] = hx0; Bw[1] = hy0; Bw[2] = hx1; Bw[3] = hy1;
                } else if (q == 2) {
                    Bw[0] = lx0; Bw[1] = ly0; Bw[2] = lx1; Bw[3] = ly1;
                }
                bf16x8 bDA = __builtin_bit_cast(bf16x8, Bw);
                updW3(aK, bDA, w1m, W1T, w, c, q);
                updW3(aH, bDO, w2m, W2T, w, c, q);
                updW3(aD, bHT, w2rm, W2R, w, c, q);
                if (w == 2) {
                    bf16x8 oh_ = *(const bf16x8 *)&DOT[lane * 16];
                    bf16x8 ol_ = *(const bf16x8 *)&DOT[lane * 16 + 8];
                    float db2 = 0.f;
#pragma unroll
                    for (int j = 0; j < 8; ++j)
                        db2 += bf2f(oh_[j]) + bf2f(ol_[j]);
                    b2_s[lane] -= LR * db2;
                } else if (w == 3) {
                    float dlb = 0.f, dlg = 0.f;
#pragma unroll
                    for (int b = 0; b < 8; ++b) {
                        float dzv = o_s[b * 68 + lane];
                        dlb += dzv;
                        dlg += dzv * xh_s[b * 68 + lane];
                    }
                    lb_s[lane] -= LR * dlb;
                    lg_s[lane] -= LR * dlg;
                }
                // F1': incremental pre-activation + activation for next step
                acc1 = MFMA16(aKg, bDA, acc1);
                b1_r -= LR * b1sum;
                if (q < 2) {
                    int col = 16 * w + c;
                    if (step < 3) {
                        float gv[4];
#pragma unroll
                        for (int r = 0; r < 4; ++r) {
                            float g, dg;
                            gelu_both(acc1[r] + b1_r, g, dg);
                            gv[r] = g;
                            gd_r[r] = dg;
                        }
                        unsigned h01, l01, h23, l23;
                        cvt2(gv[0], gv[1], h01, l01);
                        cvt2(gv[2], gv[3], h23, l23);
                        Hp[(4 * q + 0) * 136 + col] = (unsigned short)h01;
                        Hp[(4 * q + 1) * 136 + col] = (unsigned short)(h01 >> 16);
                        Hp[(4 * q + 2) * 136 + col] = (unsigned short)h23;
                        Hp[(4 * q + 3) * 136 + col] = (unsigned short)(h23 >> 16);
                        Hp[(4 * q + 0) * 136 + 64 + col] = (unsigned short)l01;
                        Hp[(4 * q + 1) * 136 + 64 + col] = (unsigned short)(l01 >> 16);
                        Hp[(4 * q + 2) * 136 + 64 + col] = (unsigned short)l23;
                        Hp[(4 * q + 3) * 136 + 64 + col] = (unsigned short)(l23 >> 16);
                        uint2 hh, hl;
                        hh.x = h01; hh.y = h23;
                        hl.x = l01; hl.y = l23;
                        *(uint2 *)&HTw[col * 16 + 4 * q] = hh;
                        *(uint2 *)&HTw[col * 16 + 8 + 4 * q] = hl;
                    } else {
                        // final forward h (feeds F2fin); no HT/gd needed
                        float gv[4];
#pragma unroll
                        for (int r = 0; r < 4; ++r)
                            gv[r] = gelu_f(acc1[r] + b1_r);
                        unsigned h01, l01, h23, l23;
                        cvt2(gv[0], gv[1], h01, l01);
                        cvt2(gv[2], gv[3], h23, l23);
                        Hp[(4 * q + 0) * 136 + col] = (unsigned short)h01;
                        Hp[(4 * q + 1) * 136 + col] = (unsigned short)(h01 >> 16);
                        Hp[(4 * q + 2) * 136 + col] = (unsigned short)h23;
                        Hp[(4 * q + 3) * 136 + col] = (unsigned short)(h23 >> 16);
                        Hp[(4 * q + 0) * 136 + 64 + col] = (unsigned short)l01;
                        Hp[(4 * q + 1) * 136 + 64 + col] = (unsigned short)(l01 >> 16);
                        Hp[(4 * q + 2) * 136 + 64 + col] = (unsigned short)l23;
                        Hp[(4 * q + 3) * 136 + 64 + col] = (unsigned short)(l23 >> 16);
                    }
                }
            }
            __syncthreads();
        }

        // ---- F2fin: o = h_final@W2 + b2 ; stage token t+1 (Kp/KT/TGp)
        f32x4 acc = mm64(Hp, W2T, w, c, q);
        if (q < 2) {
            float bias = b2_s[16 * w + c];
#pragma unroll
            for (int r = 0; r < 4; ++r)
                o_s[(4 * q + r) * 68 + 16 * w + c] = acc[r] + bias;
        }
        if (t + 1 < Sv) {
            unsigned khw, klw;
            cvt2(pk.x, pk.y, khw, klw);
            *(unsigned *)&Kp[bb * 136 + j0] = khw;
            *(unsigned *)&Kp[bb * 136 + 64 + j0] = klw;
            KT[j0 * 16 + bb] = (unsigned short)khw;
            KT[j0 * 16 + 8 + bb] = (unsigned short)klw;
            KT[(j0 + 1) * 16 + bb] = (unsigned short)(khw >> 16);
            KT[(j0 + 1) * 16 + 8 + bb] = (unsigned short)(klw >> 16);
            unsigned thw, tlw;
            cvt2(pv.x - pk.x, pv.y - pk.y, thw, tlw);
            *(unsigned *)&TGp[bb * 136 + j0] = thw;
            *(unsigned *)&TGp[bb * 136 + 64 + j0] = tlw;
        }
        __syncthreads();
        // epilogue: LN(lg,lb) -> LN(ttt_g,ttt_b) -> out = q + z2
        // (single-pass variance; no trailing barrier: F1o's end-barrier
        // orders the o_s reuse)
        {
            float2 xv = *(const float2 *)&o_s[bb * 68 + j0];
            float s = red32(xv.x + xv.y);
            float s2 = red32(xv.x * xv.x + xv.y * xv.y);
            float mu = s * (1.f / 64.f);
            float var = s2 * (1.f / 64.f) - mu * mu;
            float rs = rsqrtf(var + 1e-5f);
            float z0 = (xv.x - mu) * rs * lg_s[j0] + lb_s[j0];
            float z1 = (xv.y - mu) * rs * lg_s[j0 + 1] + lb_s[j0 + 1];
            float sb = red32(z0 + z1);
            float s2b = red32(z0 * z0 + z1 * z1);
            float mu2 = sb * (1.f / 64.f);
            float var2 = s2b * (1.f / 64.f) - mu2 * mu2;
            float rs2 = rsqrtf(var2 + 1e-5f);
            float z20 = (z0 - mu2) * rs2 * tG_s[j0] + tB_s[j0];
            float z21 = (z1 - mu2) * rs2 * tG_s[j0 + 1] + tB_s[j0 + 1];
            int idx = ((bb * Sv + t) * Hv + h) * Dv + j0;
            float2 ov;
            ov.x = q_cur.x + z20;
            ov.y = q_cur.y + z21;
            *(float2 *)&out_g[idx] = ov;
            q_cur = pq;
        }
    }
}

// ---------------------------------------------------------------------------
// bf16 hi/lo MFMA GEMM body: C[64x64 tile] = A@B (+ optional gated epilogue).
// B staged via k-pair packing: coalesced dword loads along n, one cvt2 per
// k-pair, packed 4B stores (was 16 cvt1 + 32 scalar ushort stores).
// ---------------------------------------------------------------------------
__device__ __forceinline__ void gemm_body(
    const float *__restrict__ A, const float *__restrict__ B,
    float *__restrict__ C, const float *__restrict__ gate_ln,
    int N, int K, int mode, int bm, int bn,
    unsigned short *As, unsigned short *Bs, int tid) {
    const int w = tid >> 6, lane = tid & 63, c = lane & 15, q = lane >> 4;

    f32x4 acc[4] = {{0.f, 0.f, 0.f, 0.f}, {0.f, 0.f, 0.f, 0.f},
                    {0.f, 0.f, 0.f, 0.f}, {0.f, 0.f, 0.f, 0.f}};
    const int srow = tid >> 2, sseg = (tid & 3) * 16;
    const int nB = tid & 63, kb = (tid >> 6) * 16;

    for (int k0 = 0; k0 < K; k0 += 64) {
        // stage A 64x64 (row-major m, k hi/lo)
        {
            const float *src = A + (long)(bm + srow) * K + k0 + sseg;
#pragma unroll
            for (int j = 0; j < 16; j += 2) {
                float2 v = *(const float2 *)(src + j);
                unsigned hw, lw;
                cvt2(v.x, v.y, hw, lw);
                *(unsigned *)&As[srow * 136 + sseg + j] = hw;
                *(unsigned *)&As[srow * 136 + 64 + sseg + j] = lw;
            }
        }
        // stage B 64(k)x64(n) -> n-major planes via k-pair packing
        {
            const float *bsrc = B + (long)(k0 + kb) * N + bn + nB;
#pragma unroll
            for (int j = 0; j < 16; j += 2) {
                float f0 = bsrc[(long)j * N];
                float f1 = bsrc[(long)(j + 1) * N];
                unsigned hw, lw;
                cvt2(f0, f1, hw, lw);
                *(unsigned *)&Bs[nB * 136 + kb + j] = hw;
                *(unsigned *)&Bs[nB * 136 + 64 + kb + j] = lw;
            }
        }
        __syncthreads();
#pragma unroll
        for (int kc = 0; kc < 2; ++kc) {
            const unsigned short *br =
                &Bs[(16 * w + c) * 136 + kc * 32 + 8 * q];
            bf16x8 bh = *(const bf16x8 *)(br);
            bf16x8 bl = *(const bf16x8 *)(br + 64);
#pragma unroll
            for (int mt = 0; mt < 4; ++mt) {
                const unsigned short *ar =
                    &As[(16 * mt + c) * 136 + kc * 32 + 8 * q];
                bf16x8 ah = *(const bf16x8 *)(ar);
                bf16x8 al = *(const bf16x8 *)(ar + 64);
                acc[mt] = MFMA16(ah, bh, acc[mt]);
                acc[mt] = MFMA16(al, bh, acc[mt]);
                acc[mt] = MFMA16(ah, bl, acc[mt]);
            }
        }
        __syncthreads();
    }
#pragma unroll
    for (int mt = 0; mt < 4; ++mt) {
#pragma unroll
        for (int r = 0; r < 4; ++r) {
            int row = bm + 16 * mt + 4 * q + r;
            int col = bn + 16 * w + c;
            float val = acc[mt][r];
            if (mode == 1)
                val = gelu_f(val) * gate_ln[(long)row * N + col];
            C[(long)row * N + col] = val;
        }
    }
}

__global__ __launch_bounds__(256) void gemm_bf16(
    const float *__restrict__ A, const float *__restrict__ B,
    float *__restrict__ C, const float *__restrict__ gate_ln,
    int M, int N, int K, int mode) {
    __shared__ unsigned short As[64 * 136];
    __shared__ unsigned short Bs[64 * 136];
    gemm_body(A, B, C, gate_ln, N, K, mode, blockIdx.y * 64, blockIdx.x * 64,
              As, Bs, threadIdx.x);
}

// Fused q/k/v projection: the three gemms share A=x; blockIdx.x selects the
// weight/output pair (saves 2 launch/drain gaps). NOTE: parameter names must
// avoid the Bv/Sv/Hv/Dv problem-constant macros (round-11 compile failure).
__global__ __launch_bounds__(256) void gemm_qkv(
    const float *__restrict__ A, const float *__restrict__ Wq_,
    const float *__restrict__ Wk_, const float *__restrict__ Wv_,
    float *__restrict__ Cq, float *__restrict__ Ck, float *__restrict__ Cv_,
    int N, int K) {
    __shared__ unsigned short As[64 * 136];
    __shared__ unsigned short Bs[64 * 136];
    const int mat = blockIdx.x >> 4;
    const int bn = (blockIdx.x & 15) * 64;
    const float *Bmat = (mat == 0) ? Wq_ : (mat == 1) ? Wk_ : Wv_;
    float *Cmat = (mat == 0) ? Cq : (mat == 1) ? Ck : Cv_;
    gemm_body(A, Bmat, Cmat, nullptr, N, K, 0, blockIdx.y * 64, bn, As, Bs,
              threadIdx.x);
}

// ---------------------------------------------------------------------------
// Row LayerNorm over 1024 (post-scan, pn_g / pn_b)
// ---------------------------------------------------------------------------
__global__ __launch_bounds__(256) void row_ln(const float *__restrict__ in,
                                              float *__restrict__ out,
                                              const float *__restrict__ g,
                                              const float *__restrict__ b) {
    __shared__ float sred[4], s2red[4];
    const int row = blockIdx.x;
    const int tid = threadIdx.x;
    const float *x = in + (long)row * 1024;
    float4 v = *(const float4 *)(x + tid * 4);
    float s = v.x + v.y + v.z + v.w;
    float s2 = v.x * v.x + v.y * v.y + v.z * v.z + v.w * v.w;
#pragma unroll
    for (int m = 1; m <= 32; m <<= 1) {
        s += __shfl_xor(s, m);
        s2 += __shfl_xor(s2, m);
    }
    if ((tid & 63) == 0) {
        sred[tid >> 6] = s;
        s2red[tid >> 6] = s2;
    }
    __syncthreads();
    float S = sred[0] + sred[1] + sred[2] + sred[3];
    float S2 = s2red[0] + s2red[1] + s2red[2] + s2red[3];
    float mu = S * (1.f / 1024.f);
    float var = S2 * (1.f / 1024.f) - mu * mu;
    float rs = rsqrtf(var + 1e-5f);
    float o[4] = {v.x, v.y, v.z, v.w};
    float4 ov;
    float r[4];
#pragma unroll
    for (int i = 0; i < 4; ++i) {
        int col = tid * 4 + i;
        r[i] = (o[i] - mu) * rs * g[col] + b[col];
    }
    ov.x = r[0]; ov.y = r[1]; ov.z = r[2]; ov.w = r[3];
    *(float4 *)(out + (long)row * 1024 + tid * 4) = ov;
}

// ---------------------------------------------------------------------------
// Launch
// ---------------------------------------------------------------------------
extern "C" void kernel_launch(void *const *d_in, const int *in_sizes, int n_in,
                              void *d_out, int out_size, void *d_ws,
                              size_t ws_size, hipStream_t stream) {
    const float *x = (const float *)d_in[0];
    const float *wq = (const float *)d_in[1];
    const float *wk = (const float *)d_in[2];
    const float *wv = (const float *)d_in[3];
    const float *fw_w1 = (const float *)d_in[4];
    const float *fw_b1 = (const float *)d_in[5];
    const float *fw_w2 = (const float *)d_in[6];
    const float *fw_b2 = (const float *)d_in[7];
    const float *fw_lng = (const float *)d_in[8];
    const float *fw_lnb = (const float *)d_in[9];
    const float *loss_w = (const float *)d_in[10];
    const float *loss_b = (const float *)d_in[11];
    const float *ttt_g = (const float *)d_in[12];
    const float *ttt_b = (const float *)d_in[13];
    const float *wo = (const float *)d_in[14];
    const float *wg = (const float *)d_in[15];
    const float *pn_g = (const float *)d_in[16];
    const float *pn_b = (const float *)d_in[17];

    const long MAT = 2048L * 1024L;
    float *q_ws = (float *)d_ws;
    float *k_ws = q_ws + MAT;
    float *v_ws = k_ws + MAT;
    float *out_ws = v_ws + MAT;
    float *ln_ws = k_ws;       // reuse (k dead after scan)
    float *gated_ws = v_ws;    // reuse (v dead after scan)

    dim3 gq(16 * 3, 2048 / 64), gg(1024 / 64, 2048 / 64), bt(256);
    hipLaunchKernelGGL(gemm_qkv, gq, bt, 0, stream, x, wq, wk, wv,
                       q_ws, k_ws, v_ws, 1024, 1024);

    (void)hipFuncSetAttribute((const void *)ttt_scan,
                              hipFuncAttributeMaxDynamicSharedMemorySize,
                              LDS_BYTES);
    hipLaunchKernelGGL(ttt_scan, dim3(16), dim3(256), LDS_BYTES, stream,
                       q_ws, k_ws, v_ws, out_ws, fw_w1, fw_b1, fw_w2, fw_b2,
                       fw_lng, fw_lnb, loss_w, loss_b, ttt_g, ttt_b);

    hipLaunchKernelGGL(row_ln, dim3(2048), dim3(256), 0, stream, out_ws, ln_ws,
                       pn_g, pn_b);
    hipLaunchKernelGGL(gemm_bf16, gg, bt, 0, stream, x, wg, gated_ws, ln_ws,
                       2048, 1024, 1024, 1);
    hipLaunchKernelGGL(gemm_bf16, gg, bt, 0, stream, gated_ws, wo,
                       (float *)d_out, (const float *)nullptr, 2048, 1024,
                       1024, 0);
}

// Round 13
// 3699.696 us; speedup vs baseline: 1.2201x; 1.0005x over previous
//
#include <hip/hip_runtime.h>

// ---------------------------------------------------------------------------
// Problem constants
// ---------------------------------------------------------------------------
#define Bv 8
#define Sv 256
#define Hv 16
#define Dv 64
#define LR 0.1f
#define SCALE (2.0f / 8192.0f)   // dLoss/dpred scale: 2/(B*H*D)

using bf16x8 = __attribute__((ext_vector_type(8))) short;
using bf16x4 = __attribute__((ext_vector_type(4))) short;
using f32x4  = __attribute__((ext_vector_type(4))) float;
using u32x4  = __attribute__((ext_vector_type(4))) unsigned;
#define MFMA16(A, B, C) __builtin_amdgcn_mfma_f32_16x16x32_bf16(A, B, C, 0, 0, 0)

// ---------------------------------------------------------------------------
// LDS layout (ushort units for bf16 planes, float units for fp32 areas)
// Weight/row planes: pitch 136 ushort = 272 B (hi[64] | lo[64] | pad[8]).
// T arrays: pitch 16 ushort = 32 B (hi[8] | lo[8]).
// ---------------------------------------------------------------------------
constexpr int U_W1T = 0;          // [f][d] planes, 64x136
constexpr int U_W2T = 8704;      // [d][f]
constexpr int U_W2R = 17408;     // [f][d]
constexpr int U_G   = 26112;     // [d][d']  (symmetric, static)
constexpr int U_LwR = 34816;     // [d][e]   (static)
constexpr int U_K   = 43520;     // [b pad16][d] 16x136
constexpr int U_H   = 45696;     // [b][f]
constexpr int U_Z   = 47872;     // [b][d]
constexpr int U_TG  = 50048;     // [b pad16][e] target planes
constexpr int U_DO  = 52224;     // [b][d]
constexpr int U_KT  = 54400;     // [d][b] 64x16
constexpr int U_HT  = 55424;     // [f][b]  (buffer 0)
constexpr int U_DOT = 56448;     // [d][b]
constexpr int U_DAT = 57472;     // (unused now - DAT lives in registers/shfl)
constexpr int F_BASE = 29248;    // = 58496/2
constexpr int F_O   = F_BASE;        // o / dz shared, [8][68]
constexpr int F_XH  = F_BASE + 544;
constexpr int F_GD  = F_XH + 544;    // (unused)
constexpr int F_TGL = F_GD + 544;    // (unused)
constexpr int F_B1  = F_TGL + 544;   // (unused)
constexpr int F_B2  = F_B1 + 64;
constexpr int F_LG  = F_B2 + 64;
constexpr int F_LB  = F_LG + 64;
constexpr int F_C1  = F_LB + 64;     // Lb @ Lw^T (static)
constexpr int F_TGm = F_C1 + 64;
constexpr int F_TBm = F_TGm + 64;
constexpr int F_RSTD = F_TBm + 64;
constexpr int U_KG  = (F_RSTD + 8) * 2;   // -LR*K*K^T, [16][hi8|lo8]
constexpr int U_HT2 = U_KG + 256;         // HT buffer 1
constexpr int LDS_BYTES = (U_HT2 + 1024) * 2;   // 130080 B

// ---------------------------------------------------------------------------
// Helpers
// ---------------------------------------------------------------------------
__device__ __forceinline__ short bf_rn(float v) {
    unsigned u = __float_as_uint(v);
    unsigned r = u + 0x7fffu + ((u >> 16) & 1u);   // round-to-nearest-even
    return (short)(r >> 16);
}
__device__ __forceinline__ void cvt1(float v, short &hi, short &lo) {
    hi = bf_rn(v);
    float hf = __uint_as_float(((unsigned)(unsigned short)hi) << 16);
    lo = bf_rn(v - hf);
}
__device__ __forceinline__ float bf2f(short u) {
    return __uint_as_float(((unsigned)(unsigned short)u) << 16);
}
// Packed bf16 pair conversion: 1 instruction converts 2 floats (RTNE).
__device__ __forceinline__ unsigned cvtpk(float a, float b) {
    unsigned r;
    asm("v_cvt_pk_bf16_f32 %0, %1, %2" : "=v"(r) : "v"(a), "v"(b));
    return r;                      // lo16 = bf16(a), hi16 = bf16(b)
}
// hi/lo split of a float pair: hw = packed hi-bf16s, lw = packed lo-bf16s.
__device__ __forceinline__ void cvt2(float a, float b, unsigned &hw,
                                     unsigned &lw) {
    hw = cvtpk(a, b);
    float ra = a - __uint_as_float(hw << 16);
    float rb = b - __uint_as_float(hw & 0xffff0000u);
    lw = cvtpk(ra, rb);
}
// DPP-based 32-lane sum.
template <int CTRL>
__device__ __forceinline__ float dpp_add(float v) {
    int s = __builtin_amdgcn_update_dpp(0, __float_as_int(v), CTRL, 0xF, 0xF,
                                        true);
    return v + __int_as_float(s);
}
__device__ __forceinline__ float red32(float v) {
    v = dpp_add<0xB1>(v);    // quad_perm [1,0,3,2]  (xor 1)
    v = dpp_add<0x4E>(v);    // quad_perm [2,3,0,1]  (xor 2)
    v = dpp_add<0x124>(v);   // row_ror:4
    v = dpp_add<0x128>(v);   // row_ror:8
    v += __shfl_xor(v, 16);  // merge the two 16-rows of the 32-group
    return v;
}
__device__ __forceinline__ float fast_tanh(float u) {
    u = fminf(fmaxf(u, -10.f), 10.f);
    float e = __expf(2.0f * u);
    return (e - 1.0f) / (e + 1.0f);
}
__device__ __forceinline__ void gelu_both(float x, float &g, float &dg) {
    const float C0 = 0.7978845608028654f, A0 = 0.044715f;
    float x2 = x * x;
    float u = C0 * x * (1.0f + A0 * x2);
    float t = fast_tanh(u);
    g = 0.5f * x * (1.0f + t);
    float du = C0 * (1.0f + 3.0f * A0 * x2);
    dg = 0.5f * (1.0f + t) + 0.5f * x * (1.0f - t * t) * du;
}
__device__ __forceinline__ float gelu_f(float x) {
    const float C0 = 0.7978845608028654f, A0 = 0.044715f;
    float u = C0 * x * (1.0f + A0 * x * x);
    return 0.5f * x * (1.0f + fast_tanh(u));
}

// C[16x16 tile w] = A(16x64, row planes) @ B(64x64 via n-major planes)
// 3-term split product (hh + lh + hl; the ll term is ~2^-17 relative and
// dropped — same packing precedent as updW since round 2).
__device__ __forceinline__ f32x4 mm64(const unsigned short *Ap,
                                      const unsigned short *Bp,
                                      int w, int c, int q) {
    const unsigned short *ar = Ap + c * 136 + 8 * q;
    const unsigned short *br = Bp + (16 * w + c) * 136 + 8 * q;
    bf16x8 ah0 = *(const bf16x8 *)(ar);
    bf16x8 al0 = *(const bf16x8 *)(ar + 64);
    bf16x8 bh0 = *(const bf16x8 *)(br);
    bf16x8 bl0 = *(const bf16x8 *)(br + 64);
    bf16x8 ah1 = *(const bf16x8 *)(ar + 32);
    bf16x8 al1 = *(const bf16x8 *)(ar + 96);
    bf16x8 bh1 = *(const bf16x8 *)(br + 32);
    bf16x8 bl1 = *(const bf16x8 *)(br + 96);
    f32x4 x0 = {0.f, 0.f, 0.f, 0.f}, x1 = {0.f, 0.f, 0.f, 0.f};
    x0 = MFMA16(ah0, bh0, x0); x1 = MFMA16(ah1, bh1, x1);
    x0 = MFMA16(al0, bh0, x0); x1 = MFMA16(al1, bh1, x1);
    x0 = MFMA16(ah0, bl0, x0); x1 = MFMA16(ah1, bl1, x1);
    return x0 + x1;
}

// W update with f32 master weights in registers (validated in round 7).
// Lane (c,q) owns W elements (row 16w+c, col 16mt+4q+r) == exactly this
// lane's gradient outputs. g = X^T@Y via packed-K MFMA; master -= LR*g;
// planes = cvt2(master). No W-plane reads.
__device__ __forceinline__ void updW3(const bf16x8 *a4, bf16x8 b,
                                      float (&m)[16], unsigned short *WT,
                                      int w, int c, int q) {
    f32x4 g[4];
#pragma unroll
    for (int mt = 0; mt < 4; ++mt) {
        f32x4 z = {0.f, 0.f, 0.f, 0.f};
        g[mt] = MFMA16(a4[mt], b, z);
    }
    unsigned short *p0 = &WT[(16 * w + c) * 136 + 4 * q];
#pragma unroll
    for (int mt = 0; mt < 4; ++mt) {
        m[mt * 4 + 0] -= LR * g[mt][0];
        m[mt * 4 + 1] -= LR * g[mt][1];
        m[mt * 4 + 2] -= LR * g[mt][2];
        m[mt * 4 + 3] -= LR * g[mt][3];
        unsigned nh0, nl0, nh1, nl1;
        cvt2(m[mt * 4 + 0], m[mt * 4 + 1], nh0, nl0);
        cvt2(m[mt * 4 + 2], m[mt * 4 + 3], nh1, nl1);
        uint2 nh, nl;
        nh.x = nh0; nh.y = nh1;
        nl.x = nl0; nl.y = nl1;
        *(uint2 *)(p0 + 16 * mt) = nh;
        *(uint2 *)(p0 + 16 * mt + 64) = nl;
    }
}

// ---------------------------------------------------------------------------
// bf16 hi/lo MFMA GEMM body: C[64x64 tile] = A@B (+ optional epilogue).
// mode 0: raw; mode 1: gelu(acc)*gate_ln; mode 3: gelu(acc) only.
// B staged via k-pair packing (coalesced dword loads along n, one cvt2 per
// k-pair, packed 4B stores).
// ---------------------------------------------------------------------------
__device__ __forceinline__ void gemm_body(
    const float *__restrict__ A, const float *__restrict__ B,
    float *__restrict__ C, const float *__restrict__ gate_ln,
    int N, int K, int mode, int bm, int bn,
    unsigned short *As, unsigned short *Bs, int tid) {
    const int w = tid >> 6, lane = tid & 63, c = lane & 15, q = lane >> 4;

    f32x4 acc[4] = {{0.f, 0.f, 0.f, 0.f}, {0.f, 0.f, 0.f, 0.f},
                    {0.f, 0.f, 0.f, 0.f}, {0.f, 0.f, 0.f, 0.f}};
    const int srow = tid >> 2, sseg = (tid & 3) * 16;
    const int nB = tid & 63, kb = (tid >> 6) * 16;

    for (int k0 = 0; k0 < K; k0 += 64) {
        // stage A 64x64 (row-major m, k hi/lo)
        {
            const float *src = A + (long)(bm + srow) * K + k0 + sseg;
#pragma unroll
            for (int j = 0; j < 16; j += 2) {
                float2 v = *(const float2 *)(src + j);
                unsigned hw, lw;
                cvt2(v.x, v.y, hw, lw);
                *(unsigned *)&As[srow * 136 + sseg + j] = hw;
                *(unsigned *)&As[srow * 136 + 64 + sseg + j] = lw;
            }
        }
        // stage B 64(k)x64(n) -> n-major planes via k-pair packing
        {
            const float *bsrc = B + (long)(k0 + kb) * N + bn + nB;
#pragma unroll
            for (int j = 0; j < 16; j += 2) {
                float f0 = bsrc[(long)j * N];
                float f1 = bsrc[(long)(j + 1) * N];
                unsigned hw, lw;
                cvt2(f0, f1, hw, lw);
                *(unsigned *)&Bs[nB * 136 + kb + j] = hw;
                *(unsigned *)&Bs[nB * 136 + 64 + kb + j] = lw;
            }
        }
        __syncthreads();
#pragma unroll
        for (int kc = 0; kc < 2; ++kc) {
            const unsigned short *br =
                &Bs[(16 * w + c) * 136 + kc * 32 + 8 * q];
            bf16x8 bh = *(const bf16x8 *)(br);
            bf16x8 bl = *(const bf16x8 *)(br + 64);
#pragma unroll
            for (int mt = 0; mt < 4; ++mt) {
                const unsigned short *ar =
                    &As[(16 * mt + c) * 136 + kc * 32 + 8 * q];
                bf16x8 ah = *(const bf16x8 *)(ar);
                bf16x8 al = *(const bf16x8 *)(ar + 64);
                acc[mt] = MFMA16(ah, bh, acc[mt]);
                acc[mt] = MFMA16(al, bh, acc[mt]);
                acc[mt] = MFMA16(ah, bl, acc[mt]);
            }
        }
        __syncthreads();
    }
#pragma unroll
    for (int mt = 0; mt < 4; ++mt) {
#pragma unroll
        for (int r = 0; r < 4; ++r) {
            int row = bm + 16 * mt + 4 * q + r;
            int col = bn + 16 * w + c;
            float val = acc[mt][r];
            if (mode == 1)
                val = gelu_f(val) * gate_ln[(long)row * N + col];
            else if (mode == 3)
                val = gelu_f(val);
            C[(long)row * N + col] = val;
        }
    }
}

// ---------------------------------------------------------------------------
// TTT scan kernel: blocks 0..15 = one per head (scan, byte-identical logic
// to round 8's 3457 us version); blocks 16..527 = gate projection
// ggo = gelu(x @ wg) — independent of the scan, runs on the ~240 idle CUs
// and is fully hidden under the 3.46 ms scan (130 KB LDS -> 1 block/CU, so
// gate blocks never share a CU with a scan block).
// ---------------------------------------------------------------------------
__global__ __launch_bounds__(256) void ttt_scan(
    const float *__restrict__ q_g, const float *__restrict__ k_g,
    const float *__restrict__ v_g, float *__restrict__ out_g,
    const float *__restrict__ fw_w1, const float *__restrict__ fw_b1,
    const float *__restrict__ fw_w2, const float *__restrict__ fw_b2,
    const float *__restrict__ fw_lng, const float *__restrict__ fw_lnb,
    const float *__restrict__ loss_w, const float *__restrict__ loss_bv,
    const float *__restrict__ ttt_gv, const float *__restrict__ ttt_bv,
    const float *__restrict__ gx, const float *__restrict__ gwg,
    float *__restrict__ ggo) {
    extern __shared__ char smem[];
    unsigned short *us = (unsigned short *)smem;
    float *fs = (float *)smem;
    const int tid = threadIdx.x;

    if (blockIdx.x >= Hv) {
        // ---- gate path: ggo = gelu(gx @ gwg), 64x64 tile per block
        int bid = blockIdx.x - Hv;
        gemm_body(gx, gwg, ggo, nullptr, 1024, 1024, 3,
                  (bid >> 4) * 64, (bid & 15) * 64, us, us + 64 * 136, tid);
        return;
    }

    unsigned short *W1T = us + U_W1T, *W2T = us + U_W2T, *W2R = us + U_W2R;
    unsigned short *Gp = us + U_G, *LwR = us + U_LwR;
    unsigned short *Kp = us + U_K, *Hp = us + U_H, *Zp = us + U_Z;
    unsigned short *TGp = us + U_TG, *DOp = us + U_DO;
    unsigned short *KT = us + U_KT, *HT0 = us + U_HT;
    unsigned short *DOT = us + U_DOT;
    unsigned short *KgT = us + U_KG, *HT1 = us + U_HT2;
    float *o_s = fs + F_O, *xh_s = fs + F_XH;
    float *b2_s = fs + F_B2, *lg_s = fs + F_LG;
    float *lb_s = fs + F_LB, *c1_s = fs + F_C1;
    float *tG_s = fs + F_TGm, *tB_s = fs + F_TBm, *rstd_s = fs + F_RSTD;

    const int h = blockIdx.x;
    const int w = tid >> 6, lane = tid & 63, c = lane & 15, q = lane >> 4;
    const int bb = tid >> 5, j0 = (tid & 31) * 2;

    // ---- init: split weights into bf16 hi/lo planes
    for (int i = tid; i < 4096; i += 256) {
        int r = i >> 6, cc = i & 63;
        short hi, lo;
        cvt1(fw_w1[h * 4096 + i], hi, lo);           // [d=r][f=cc]
        W1T[cc * 136 + r] = (unsigned short)hi;
        W1T[cc * 136 + 64 + r] = (unsigned short)lo;
        cvt1(fw_w2[h * 4096 + i], hi, lo);           // [f=r][d=cc]
        W2T[cc * 136 + r] = (unsigned short)hi;
        W2T[cc * 136 + 64 + r] = (unsigned short)lo;
        W2R[r * 136 + cc] = (unsigned short)hi;
        W2R[r * 136 + 64 + cc] = (unsigned short)lo;
        cvt1(loss_w[i], hi, lo);                     // [d=r][e=cc]
        LwR[r * 136 + cc] = (unsigned short)hi;
        LwR[r * 136 + 64 + cc] = (unsigned short)lo;
    }
    // zero pad rows 8..15 of the activation row-plane arrays
    for (int i = tid; i < 5 * 8 * 128; i += 256) {
        int a = i / 128, u = i % 128;
        int arr = a >> 3, row = 8 + (a & 7);
        unsigned short *base = (arr == 0) ? Kp : (arr == 1) ? Hp
                              : (arr == 2) ? Zp : (arr == 3) ? TGp : DOp;
        base[row * 136 + u] = 0;
    }
    // f32 master weights in registers (validated r7): lane (c,q) of wave w
    // owns elements (plane-row 16w+c, plane-col 16mt+4q+r) of the 3 planes.
    float w1m[16], w2m[16], w2rm[16];
#pragma unroll
    for (int mt = 0; mt < 4; ++mt) {
#pragma unroll
        for (int r = 0; r < 4; ++r) {
            int el = 16 * mt + 4 * q + r;
            int row = 16 * w + c;
            w1m[mt * 4 + r] = fw_w1[h * 4096 + el * 64 + row];
            w2m[mt * 4 + r] = fw_w2[h * 4096 + el * 64 + row];
            w2rm[mt * 4 + r] = fw_w2[h * 4096 + row * 64 + el];
        }
    }
    __syncthreads();
    // G = Lw @ Lw^T (static; fuses F3+B1 into one phase per step)
#pragma unroll 1
    for (int mt = 0; mt < 4; ++mt) {
        f32x4 g = mm64(LwR + 16 * 136 * mt, LwR, w, c, q);
#pragma unroll
        for (int r = 0; r < 4; ++r) {
            short hi, lo;
            cvt1(g[r], hi, lo);
            int dr = 16 * mt + 4 * q + r, dc = 16 * w + c;
            Gp[dr * 136 + dc] = (unsigned short)hi;
            Gp[dr * 136 + 64 + dc] = (unsigned short)lo;
        }
    }
    if (tid < 64) {
        b2_s[tid] = fw_b2[h * 64 + tid];
        lg_s[tid] = fw_lng[h * 64 + tid];
        lb_s[tid] = fw_lnb[h * 64 + tid];
        tG_s[tid] = ttt_gv[h * 64 + tid];
        tB_s[tid] = ttt_bv[h * 64 + tid];
        float c1 = 0.f;                      // c1[d] = sum_e Lb[e]*Lw[d,e]
        for (int e = 0; e < 64; ++e) c1 += loss_bv[e] * loss_w[tid * 64 + e];
        c1_s[tid] = c1;
    }

    // ---- stage token 0 (Kp/KT/TGp) and hold q(0) in registers
    float2 pk, pv, pq, q_cur;
    {
        int idx = ((bb * Sv + 0) * Hv + h) * Dv + j0;
        float2 k0 = *(const float2 *)&k_g[idx];
        float2 v0 = *(const float2 *)&v_g[idx];
        q_cur = *(const float2 *)&q_g[idx];
        unsigned khw, klw;
        cvt2(k0.x, k0.y, khw, klw);
        *(unsigned *)&Kp[bb * 136 + j0] = khw;
        *(unsigned *)&Kp[bb * 136 + 64 + j0] = klw;
        KT[j0 * 16 + bb] = (unsigned short)khw;
        KT[j0 * 16 + 8 + bb] = (unsigned short)klw;
        KT[(j0 + 1) * 16 + bb] = (unsigned short)(khw >> 16);
        KT[(j0 + 1) * 16 + 8 + bb] = (unsigned short)(klw >> 16);
        unsigned thw, tlw;
        cvt2(v0.x - k0.x, v0.y - k0.y, thw, tlw);
        *(unsigned *)&TGp[bb * 136 + j0] = thw;
        *(unsigned *)&TGp[bb * 136 + 64 + j0] = tlw;
    }
    // register-carried params (per lane, q<2 lanes meaningful)
    float b1_r = (q < 2) ? fw_b1[h * 64 + 16 * w + c] : 0.f;
    __syncthreads();
    float c1_r = c1_s[16 * w + c];
    f32x4 gd_r = {0.f, 0.f, 0.f, 0.f};
    f32x4 tgl_r = {0.f, 0.f, 0.f, 0.f};

#pragma unroll 1
    for (int t = 0; t < Sv; ++t) {
        // issue prefetch for token t+1 (consumed at F2fin staging / epilogue)
        if (t + 1 < Sv) {
            int idx2 = ((bb * Sv + t + 1) * Hv + h) * Dv + j0;
            pk = *(const float2 *)&k_g[idx2];
            pv = *(const float2 *)&v_g[idx2];
            pq = *(const float2 *)&q_g[idx2];
        }

        // ---- F1o: acc1 = k@W1 (kept in regs all token); tgl_r; Kg; gelu
        f32x4 acc1 = mm64(Kp, W1T, w, c, q);
        {
            f32x4 a2 = mm64(TGp, LwR, w, c, q);
            if (q < 2) {
#pragma unroll
                for (int r = 0; r < 4; ++r) tgl_r[r] = a2[r] - c1_r;
            }
        }
        if (w == 0) {
            // Kg = K@K^T (rows/cols >=8 are zero via Kp padding); store -LR*Kg
            f32x4 kg = mm64(Kp, Kp, 0, c, q);
            if (q < 2) {
#pragma unroll
                for (int r = 0; r < 4; ++r) {
                    short hi, lo;
                    cvt1(-LR * kg[r], hi, lo);
                    KgT[c * 16 + 4 * q + r] = (unsigned short)hi;
                    KgT[c * 16 + 8 + 4 * q + r] = (unsigned short)lo;
                }
            }
        }
        if (q < 2) {
            int col = 16 * w + c;
            float gv[4];
#pragma unroll
            for (int r = 0; r < 4; ++r) {
                float g, dg;
                gelu_both(acc1[r] + b1_r, g, dg);
                gv[r] = g;
                gd_r[r] = dg;
            }
            unsigned h01, l01, h23, l23;
            cvt2(gv[0], gv[1], h01, l01);
            cvt2(gv[2], gv[3], h23, l23);
            Hp[(4 * q + 0) * 136 + col] = (unsigned short)h01;
            Hp[(4 * q + 1) * 136 + col] = (unsigned short)(h01 >> 16);
            Hp[(4 * q + 2) * 136 + col] = (unsigned short)h23;
            Hp[(4 * q + 3) * 136 + col] = (unsigned short)(h23 >> 16);
            Hp[(4 * q + 0) * 136 + 64 + col] = (unsigned short)l01;
            Hp[(4 * q + 1) * 136 + 64 + col] = (unsigned short)(l01 >> 16);
            Hp[(4 * q + 2) * 136 + 64 + col] = (unsigned short)l23;
            Hp[(4 * q + 3) * 136 + 64 + col] = (unsigned short)(l23 >> 16);
            uint2 hh, hl;
            hh.x = h01; hh.y = h23;
            hl.x = l01; hl.y = l23;
            *(uint2 *)&HT0[col * 16 + 4 * q] = hh;
            *(uint2 *)&HT0[col * 16 + 8 + 4 * q] = hl;
        }
        __syncthreads();

#pragma unroll 1
        for (int step = 0; step < 4; ++step) {
            const unsigned short *HTr = (step & 1) ? HT1 : HT0;
            unsigned short *HTw = (step & 1) ? HT0 : HT1;
            // F2: o = h@W2 + b2
            f32x4 acc = mm64(Hp, W2T, w, c, q);
            if (q < 2) {
                float bias = b2_s[16 * w + c];
#pragma unroll
                for (int r = 0; r < 4; ++r)
                    o_s[(4 * q + r) * 68 + 16 * w + c] = acc[r] + bias;
            }
            __syncthreads();
            // LN fwd (thread-mapped, single-pass: independent S, S2 chains)
            float xh0_r, xh1_r;
            {
                float2 xv = *(const float2 *)&o_s[bb * 68 + j0];
                float s = red32(xv.x + xv.y);
                float s2 = red32(xv.x * xv.x + xv.y * xv.y);
                float mu = s * (1.f / 64.f);
                float var = s2 * (1.f / 64.f) - mu * mu;
                float rs = rsqrtf(var + 1e-5f);
                float xh0 = (xv.x - mu) * rs, xh1 = (xv.y - mu) * rs;
                float2 xw; xw.x = xh0; xw.y = xh1;
                *(float2 *)&xh_s[bb * 68 + j0] = xw;
                float z0 = xh0 * lg_s[j0] + lb_s[j0];
                float z1 = xh1 * lg_s[j0 + 1] + lb_s[j0 + 1];
                unsigned zh, zl;
                cvt2(z0, z1, zh, zl);
                *(unsigned *)&Zp[bb * 136 + j0] = zh;
                *(unsigned *)&Zp[bb * 136 + 64 + j0] = zl;
                if ((tid & 31) == 0) rstd_s[bb] = rs;
                xh0_r = xh0; xh1_r = xh1;
            }
            __syncthreads();
            // B1' (fused F3+B1): dz = SCALE * (z@G - tgl_r)
            acc = mm64(Zp, Gp, w, c, q);
            if (q < 2) {
                int col = 16 * w + c;
#pragma unroll
                for (int r = 0; r < 4; ++r)
                    o_s[(4 * q + r) * 68 + col] = (acc[r] - tgl_r[r]) * SCALE;
            }
            __syncthreads();
            // LN bwd (thread-mapped) -> do planes + doT
            {
                float2 dzv = *(const float2 *)&o_s[bb * 68 + j0];
                float dxh0 = dzv.x * lg_s[j0], dxh1 = dzv.y * lg_s[j0 + 1];
                float S1 = red32(dxh0 + dxh1) * (1.f / 64.f);
                float S2 = red32(dxh0 * xh0_r + dxh1 * xh1_r) * (1.f / 64.f);
                float rs = rstd_s[bb];
                float do0 = rs * (dxh0 - S1 - xh0_r * S2);
                float do1 = rs * (dxh1 - S1 - xh1_r * S2);
                unsigned dh, dl;
                cvt2(do0, do1, dh, dl);
                *(unsigned *)&DOp[bb * 136 + j0] = dh;
                *(unsigned *)&DOp[bb * 136 + 64 + j0] = dl;
                DOT[j0 * 16 + bb] = (unsigned short)dh;
                DOT[j0 * 16 + 8 + bb] = (unsigned short)dl;
                DOT[(j0 + 1) * 16 + bb] = (unsigned short)(dh >> 16);
                DOT[(j0 + 1) * 16 + 8 + bb] = (unsigned short)(dl >> 16);
            }
            __syncthreads();
            // B2+upd+F1' (single phase): prefetch stable operands into regs
            // (A-frags KT/HTr/DOT, B-frags DOT/HTr, KgT) so their LDS
            // latency hides under mm64; then dh=do@W2^T; da; the da
            // B-fragment is built via cross-lane SHUFFLE (no DAT LDS
            // round-trip); 3x updW3 (f32 masters); acc1 += (-LR*Kg)@da;
            // gelu (step3 instance IS the final forward h).
            bf16x8 zf8;
#pragma unroll
            for (int j = 0; j < 8; ++j) zf8[j] = 0;
            bf16x8 aK[4], aH[4], aD[4];
#pragma unroll
            for (int mt = 0; mt < 4; ++mt) {
                aK[mt] = *(const bf16x8 *)&KT[(16 * mt + c) * 16 + (q & 1) * 8];
                aH[mt] = *(const bf16x8 *)&HTr[(16 * mt + c) * 16 + (q & 1) * 8];
                aD[mt] = *(const bf16x8 *)&DOT[(16 * mt + c) * 16 + (q & 1) * 8];
            }
            bf16x8 bDO = zf8, bHT = zf8;
            if (q < 2) {
                bDO = *(const bf16x8 *)&DOT[(16 * w + c) * 16];
                bHT = *(const bf16x8 *)&HTr[(16 * w + c) * 16];
            } else if (q == 2) {
                bDO = *(const bf16x8 *)&DOT[(16 * w + c) * 16 + 8];
                bHT = *(const bf16x8 *)&HTr[(16 * w + c) * 16 + 8];
            }
            bf16x8 aKg = *(const bf16x8 *)&KgT[c * 16 + (q & 1) * 8];
            acc = mm64(DOp, W2R, w, c, q);
            {
                float b1sum = 0.f;
                uint2 th; th.x = 0u; th.y = 0u;
                uint2 tl; tl.x = 0u; tl.y = 0u;
                if (q < 2) {
                    float da0 = acc[0] * gd_r[0];
                    float da1 = acc[1] * gd_r[1];
                    float da2 = acc[2] * gd_r[2];
                    float da3 = acc[3] * gd_r[3];
                    b1sum = da0 + da1 + da2 + da3;
                    unsigned h01, l01, h23, l23;
                    cvt2(da0, da1, h01, l01);
                    cvt2(da2, da3, h23, l23);
                    th.x = h01; th.y = h23;
                    tl.x = l01; tl.y = l23;
                }
                b1sum += __shfl_xor(b1sum, 16);
                // bDA frag via shuffle: rows 0-3 from lane (c,0), rows 4-7
                // from lane (c,1). q<2 lanes need hi words, q==2 lo words.
                unsigned hx0 = (unsigned)__shfl((int)th.x, c);
                unsigned hy0 = (unsigned)__shfl((int)th.y, c);
                unsigned hx1 = (unsigned)__shfl((int)th.x, c + 16);
                unsigned hy1 = (unsigned)__shfl((int)th.y, c + 16);
                unsigned lx0 = (unsigned)__shfl((int)tl.x, c);
                unsigned ly0 = (unsigned)__shfl((int)tl.y, c);
                unsigned lx1 = (unsigned)__shfl((int)tl.x, c + 16);
                unsigned ly1 = (unsigned)__shfl((int)tl.y, c + 16);
                u32x4 Bw = {0u, 0u, 0u, 0u};
                if (q < 2) {
                    Bw[0] = hx0; Bw[1] = hy0; Bw[2] = hx1; Bw[3] = hy1;
                } else if (q == 2) {
                    Bw[0] = lx0; Bw[1] = ly0; Bw[2] = lx1; Bw[3] = ly1;
                }
                bf16x8 bDA = __builtin_bit_cast(bf16x8, Bw);
                updW3(aK, bDA, w1m, W1T, w, c, q);
                updW3(aH, bDO, w2m, W2T, w, c, q);
                updW3(aD, bHT, w2rm, W2R, w, c, q);
                if (w == 2) {
                    bf16x8 oh_ = *(const bf16x8 *)&DOT[lane * 16];
                    bf16x8 ol_ = *(const bf16x8 *)&DOT[lane * 16 + 8];
                    float db2 = 0.f;
#pragma unroll
                    for (int j = 0; j < 8; ++j)
                        db2 += bf2f(oh_[j]) + bf2f(ol_[j]);
                    b2_s[lane] -= LR * db2;
                } else if (w == 3) {
                    float dlb = 0.f, dlg = 0.f;
#pragma unroll
                    for (int b = 0; b < 8; ++b) {
                        float dzv = o_s[b * 68 + lane];
                        dlb += dzv;
                        dlg += dzv * xh_s[b * 68 + lane];
                    }
                    lb_s[lane] -= LR * dlb;
                    lg_s[lane] -= LR * dlg;
                }
                // F1': incremental pre-activation + activation for next step
                acc1 = MFMA16(aKg, bDA, acc1);
                b1_r -= LR * b1sum;
                if (q < 2) {
                    int col = 16 * w + c;
                    if (step < 3) {
                        float gv[4];
#pragma unroll
                        for (int r = 0; r < 4; ++r) {
                            float g, dg;
                            gelu_both(acc1[r] + b1_r, g, dg);
                            gv[r] = g;
                            gd_r[r] = dg;
                        }
                        unsigned h01, l01, h23, l23;
                        cvt2(gv[0], gv[1], h01, l01);
                        cvt2(gv[2], gv[3], h23, l23);
                        Hp[(4 * q + 0) * 136 + col] = (unsigned short)h01;
                        Hp[(4 * q + 1) * 136 + col] = (unsigned short)(h01 >> 16);
                        Hp[(4 * q + 2) * 136 + col] = (unsigned short)h23;
                        Hp[(4 * q + 3) * 136 + col] = (unsigned short)(h23 >> 16);
                        Hp[(4 * q + 0) * 136 + 64 + col] = (unsigned short)l01;
                        Hp[(4 * q + 1) * 136 + 64 + col] = (unsigned short)(l01 >> 16);
                        Hp[(4 * q + 2) * 136 + 64 + col] = (unsigned short)l23;
                        Hp[(4 * q + 3) * 136 + 64 + col] = (unsigned short)(l23 >> 16);
                        uint2 hh, hl;
                        hh.x = h01; hh.y = h23;
                        hl.x = l01; hl.y = l23;
                        *(uint2 *)&HTw[col * 16 + 4 * q] = hh;
                        *(uint2 *)&HTw[col * 16 + 8 + 4 * q] = hl;
                    } else {
                        // final forward h (feeds F2fin); no HT/gd needed
                        float gv[4];
#pragma unroll
                        for (int r = 0; r < 4; ++r)
                            gv[r] = gelu_f(acc1[r] + b1_r);
                        unsigned h01, l01, h23, l23;
                        cvt2(gv[0], gv[1], h01, l01);
                        cvt2(gv[2], gv[3], h23, l23);
                        Hp[(4 * q + 0) * 136 + col] = (unsigned short)h01;
                        Hp[(4 * q + 1) * 136 + col] = (unsigned short)(h01 >> 16);
                        Hp[(4 * q + 2) * 136 + col] = (unsigned short)h23;
                        Hp[(4 * q + 3) * 136 + col] = (unsigned short)(h23 >> 16);
                        Hp[(4 * q + 0) * 136 + 64 + col] = (unsigned short)l01;
                        Hp[(4 * q + 1) * 136 + 64 + col] = (unsigned short)(l01 >> 16);
                        Hp[(4 * q + 2) * 136 + 64 + col] = (unsigned short)l23;
                        Hp[(4 * q + 3) * 136 + 64 + col] = (unsigned short)(l23 >> 16);
                    }
                }
            }
            __syncthreads();
        }

        // ---- F2fin: o = h_final@W2 + b2 ; stage token t+1 (Kp/KT/TGp)
        f32x4 acc = mm64(Hp, W2T, w, c, q);
        if (q < 2) {
            float bias = b2_s[16 * w + c];
#pragma unroll
            for (int r = 0; r < 4; ++r)
                o_s[(4 * q + r) * 68 + 16 * w + c] = acc[r] + bias;
        }
        if (t + 1 < Sv) {
            unsigned khw, klw;
            cvt2(pk.x, pk.y, khw, klw);
            *(unsigned *)&Kp[bb * 136 + j0] = khw;
            *(unsigned *)&Kp[bb * 136 + 64 + j0] = klw;
            KT[j0 * 16 + bb] = (unsigned short)khw;
            KT[j0 * 16 + 8 + bb] = (unsigned short)klw;
            KT[(j0 + 1) * 16 + bb] = (unsigned short)(khw >> 16);
            KT[(j0 + 1) * 16 + 8 + bb] = (unsigned short)(klw >> 16);
            unsigned thw, tlw;
            cvt2(pv.x - pk.x, pv.y - pk.y, thw, tlw);
            *(unsigned *)&TGp[bb * 136 + j0] = thw;
            *(unsigned *)&TGp[bb * 136 + 64 + j0] = tlw;
        }
        __syncthreads();
        // epilogue: LN(lg,lb) -> LN(ttt_g,ttt_b) -> out = q + z2
        // (single-pass variance; no trailing barrier: F1o's end-barrier
        // orders the o_s reuse)
        {
            float2 xv = *(const float2 *)&o_s[bb * 68 + j0];
            float s = red32(xv.x + xv.y);
            float s2 = red32(xv.x * xv.x + xv.y * xv.y);
            float mu = s * (1.f / 64.f);
            float var = s2 * (1.f / 64.f) - mu * mu;
            float rs = rsqrtf(var + 1e-5f);
            float z0 = (xv.x - mu) * rs * lg_s[j0] + lb_s[j0];
            float z1 = (xv.y - mu) * rs * lg_s[j0 + 1] + lb_s[j0 + 1];
            float sb = red32(z0 + z1);
            float s2b = red32(z0 * z0 + z1 * z1);
            float mu2 = sb * (1.f / 64.f);
            float var2 = s2b * (1.f / 64.f) - mu2 * mu2;
            float rs2 = rsqrtf(var2 + 1e-5f);
            float z20 = (z0 - mu2) * rs2 * tG_s[j0] + tB_s[j0];
            float z21 = (z1 - mu2) * rs2 * tG_s[j0 + 1] + tB_s[j0 + 1];
            int idx = ((bb * Sv + t) * Hv + h) * Dv + j0;
            float2 ov;
            ov.x = q_cur.x + z20;
            ov.y = q_cur.y + z21;
            *(float2 *)&out_g[idx] = ov;
            q_cur = pq;
        }
    }
}

__global__ __launch_bounds__(256) void gemm_bf16(
    const float *__restrict__ A, const float *__restrict__ B,
    float *__restrict__ C, const float *__restrict__ gate_ln,
    int M, int N, int K, int mode) {
    __shared__ unsigned short As[64 * 136];
    __shared__ unsigned short Bs[64 * 136];
    gemm_body(A, B, C, gate_ln, N, K, mode, blockIdx.y * 64, blockIdx.x * 64,
              As, Bs, threadIdx.x);
}

// Fused q/k/v projection: the three gemms share A=x; blockIdx.x selects the
// weight/output pair. NOTE: parameter names must avoid the Bv/Sv/Hv/Dv
// problem-constant macros (round-11 compile failure).
__global__ __launch_bounds__(256) void gemm_qkv(
    const float *__restrict__ A, const float *__restrict__ Wq_,
    const float *__restrict__ Wk_, const float *__restrict__ Wv_,
    float *__restrict__ Cq, float *__restrict__ Ck, float *__restrict__ Cv_,
    int N, int K) {
    __shared__ unsigned short As[64 * 136];
    __shared__ unsigned short Bs[64 * 136];
    const int mat = blockIdx.x >> 4;
    const int bn = (blockIdx.x & 15) * 64;
    const float *Bmat = (mat == 0) ? Wq_ : (mat == 1) ? Wk_ : Wv_;
    float *Cmat = (mat == 0) ? Cq : (mat == 1) ? Ck : Cv_;
    gemm_body(A, Bmat, Cmat, nullptr, N, K, 0, blockIdx.y * 64, bn, As, Bs,
              threadIdx.x);
}

// gated = ggr * ln (elementwise, float4)
__global__ __launch_bounds__(256) void mul_gate(
    const float *__restrict__ a, const float *__restrict__ g2,
    float *__restrict__ o2) {
    long i = ((long)blockIdx.x * 256 + threadIdx.x) * 4;
    float4 va = *(const float4 *)&a[i];
    float4 vb = *(const float4 *)&g2[i];
    float4 vo;
    vo.x = va.x * vb.x;
    vo.y = va.y * vb.y;
    vo.z = va.z * vb.z;
    vo.w = va.w * vb.w;
    *(float4 *)&o2[i] = vo;
}

// ---------------------------------------------------------------------------
// Row LayerNorm over 1024 (post-scan, pn_g / pn_b)
// ---------------------------------------------------------------------------
__global__ __launch_bounds__(256) void row_ln(const float *__restrict__ in,
                                              float *__restrict__ out,
                                              const float *__restrict__ g,
                                              const float *__restrict__ b) {
    __shared__ float sred[4], s2red[4];
    const int row = blockIdx.x;
    const int tid = threadIdx.x;
    const float *x = in + (long)row * 1024;
    float4 v = *(const float4 *)(x + tid * 4);
    float s = v.x + v.y + v.z + v.w;
    float s2 = v.x * v.x + v.y * v.y + v.z * v.z + v.w * v.w;
#pragma unroll
    for (int m = 1; m <= 32; m <<= 1) {
        s += __shfl_xor(s, m);
        s2 += __shfl_xor(s2, m);
    }
    if ((tid & 63) == 0) {
        sred[tid >> 6] = s;
        s2red[tid >> 6] = s2;
    }
    __syncthreads();
    float S = sred[0] + sred[1] + sred[2] + sred[3];
    float S2 = s2red[0] + s2red[1] + s2red[2] + s2red[3];
    float mu = S * (1.f / 1024.f);
    float var = S2 * (1.f / 1024.f) - mu * mu;
    float rs = rsqrtf(var + 1e-5f);
    float o[4] = {v.x, v.y, v.z, v.w};
    float4 ov;
    float r[4];
#pragma unroll
    for (int i = 0; i < 4; ++i) {
        int col = tid * 4 + i;
        r[i] = (o[i] - mu) * rs * g[col] + b[col];
    }
    ov.x = r[0]; ov.y = r[1]; ov.z = r[2]; ov.w = r[3];
    *(float4 *)(out + (long)row * 1024 + tid * 4) = ov;
}

// ---------------------------------------------------------------------------
// Launch
// ---------------------------------------------------------------------------
extern "C" void kernel_launch(void *const *d_in, const int *in_sizes, int n_in,
                              void *d_out, int out_size, void *d_ws,
                              size_t ws_size, hipStream_t stream) {
    const float *x = (const float *)d_in[0];
    const float *wq = (const float *)d_in[1];
    const float *wk = (const float *)d_in[2];
    const float *wv = (const float *)d_in[3];
    const float *fw_w1 = (const float *)d_in[4];
    const float *fw_b1 = (const float *)d_in[5];
    const float *fw_w2 = (const float *)d_in[6];
    const float *fw_b2 = (const float *)d_in[7];
    const float *fw_lng = (const float *)d_in[8];
    const float *fw_lnb = (const float *)d_in[9];
    const float *loss_w = (const float *)d_in[10];
    const float *loss_b = (const float *)d_in[11];
    const float *ttt_g = (const float *)d_in[12];
    const float *ttt_b = (const float *)d_in[13];
    const float *wo = (const float *)d_in[14];
    const float *wg = (const float *)d_in[15];
    const float *pn_g = (const float *)d_in[16];
    const float *pn_b = (const float *)d_in[17];

    const long MAT = 2048L * 1024L;
    float *q_ws = (float *)d_ws;
    float *k_ws = q_ws + MAT;
    float *v_ws = k_ws + MAT;
    float *out_ws = v_ws + MAT;
    float *ln_ws = k_ws;       // reuse (k dead after scan)
    float *gated_ws = v_ws;    // reuse (v dead after scan)
    float *ggr = (float *)d_out;   // gate raw output lives in d_out until
                                   // mul_gate consumes it (final gemm then
                                   // overwrites d_out)

    dim3 gq(16 * 3, 2048 / 64), gg(1024 / 64, 2048 / 64), bt(256);
    hipLaunchKernelGGL(gemm_qkv, gq, bt, 0, stream, x, wq, wk, wv,
                       q_ws, k_ws, v_ws, 1024, 1024);

    (void)hipFuncSetAttribute((const void *)ttt_scan,
                              hipFuncAttributeMaxDynamicSharedMemorySize,
                              LDS_BYTES);
    // blocks 0..15: per-head scan; blocks 16..527: gate gemm (hidden)
    hipLaunchKernelGGL(ttt_scan, dim3(16 + 512), dim3(256), LDS_BYTES, stream,
                       q_ws, k_ws, v_ws, out_ws, fw_w1, fw_b1, fw_w2, fw_b2,
                       fw_lng, fw_lnb, loss_w, loss_b, ttt_g, ttt_b,
                       x, wg, ggr);

    hipLaunchKernelGGL(row_ln, dim3(2048), dim3(256), 0, stream, out_ws, ln_ws,
                       pn_g, pn_b);
    hipLaunchKernelGGL(mul_gate, dim3(2048), bt, 0, stream,
                       (const float *)ggr, ln_ws, gated_ws);
    hipLaunchKernelGGL(gemm_bf16, gg, bt, 0, stream, gated_ws, wo,
                       (float *)d_out, (const float *)nullptr, 2048, 1024,
                       1024, 0);
}